// Round 1
// baseline (6554.568 us; speedup 1.0000x reference)
//
#include <hip/hip_runtime.h>
#include <cstddef>
#include <math.h>

#define T_TOK 2048
#define F_DIM 512
#define H_DIM 1024
#define V_DIM 32000
#define NVC   10
#define VCH   3200
#define LN_EPS 1e-5f

__device__ inline float wave_sum(float x) {
#pragma unroll
  for (int off = 32; off > 0; off >>= 1) x += __shfl_xor(x, off, 64);
  return x;
}

// ---------------- zero ----------------
__global__ void zero_kernel(float* __restrict__ p, int n) {
  int i = blockIdx.x * 256 + threadIdx.x;
  if (i < n) p[i] = 0.f;
}

// ---------------- GEMM NT: C[M,N] = (A ⊙ A2)[M,K] * B[N,K]^T (+bias,relu) ----
__global__ __launch_bounds__(256) void gemm_nt_kernel(
    const float* __restrict__ A, const float* __restrict__ A2,
    const float* __restrict__ B, float* __restrict__ C,
    int M, int N, int K,
    const float* __restrict__ bias1, const float* __restrict__ bias2, int relu)
{
  __shared__ float As[16][68];
  __shared__ float Bs[16][68];
  const int tid = threadIdx.x;
  const int m0 = blockIdx.y * 64, n0 = blockIdx.x * 64;
  const int ty = tid >> 4, tx = tid & 15;
  const int lrow = tid >> 2, lkq = (tid & 3) * 4;
  float acc[4][4] = {};
  for (int k0 = 0; k0 < K; k0 += 16) {
    float4 a4 = *(const float4*)(A + (size_t)(m0 + lrow) * K + k0 + lkq);
    if (A2) {
      float4 u4 = *(const float4*)(A2 + (size_t)(m0 + lrow) * K + k0 + lkq);
      a4.x *= u4.x; a4.y *= u4.y; a4.z *= u4.z; a4.w *= u4.w;
    }
    float4 b4 = *(const float4*)(B + (size_t)(n0 + lrow) * K + k0 + lkq);
    As[lkq+0][lrow] = a4.x; As[lkq+1][lrow] = a4.y; As[lkq+2][lrow] = a4.z; As[lkq+3][lrow] = a4.w;
    Bs[lkq+0][lrow] = b4.x; Bs[lkq+1][lrow] = b4.y; Bs[lkq+2][lrow] = b4.z; Bs[lkq+3][lrow] = b4.w;
    __syncthreads();
#pragma unroll
    for (int k = 0; k < 16; ++k) {
      float4 a = *(const float4*)&As[k][ty*4];
      float4 b = *(const float4*)&Bs[k][tx*4];
      float ar[4] = {a.x,a.y,a.z,a.w}, br[4] = {b.x,b.y,b.z,b.w};
#pragma unroll
      for (int i = 0; i < 4; ++i)
#pragma unroll
        for (int j = 0; j < 4; ++j) acc[i][j] = fmaf(ar[i], br[j], acc[i][j]);
    }
    __syncthreads();
  }
#pragma unroll
  for (int i = 0; i < 4; ++i) {
    const int m = m0 + ty*4 + i;
    float cr[4];
#pragma unroll
    for (int j = 0; j < 4; ++j) {
      const int n = n0 + tx*4 + j;
      float v = acc[i][j];
      if (bias1) v += bias1[n];
      if (bias2) v += bias2[n];
      if (relu) v = fmaxf(v, 0.f);
      cr[j] = v;
    }
    float4 c; c.x = cr[0]; c.y = cr[1]; c.z = cr[2]; c.w = cr[3];
    *(float4*)(C + (size_t)m * N + n0 + tx*4) = c;
  }
}

// ---------------- GEMM NN: C[M,N] = A[M,K] * B[K,N], optional relu-mask ------
__global__ __launch_bounds__(256) void gemm_nn_kernel(
    const float* __restrict__ A, const float* __restrict__ B,
    float* __restrict__ C, int M, int N, int K,
    const float* __restrict__ maskgt)
{
  __shared__ float As[16][68];
  __shared__ float Bs[16][68];
  const int tid = threadIdx.x;
  const int m0 = blockIdx.y * 64, n0 = blockIdx.x * 64;
  const int ty = tid >> 4, tx = tid & 15;
  const int arow = tid >> 2, akq = (tid & 3) * 4;
  const int brow = tid >> 4, bcq = (tid & 15) * 4;
  float acc[4][4] = {};
  for (int k0 = 0; k0 < K; k0 += 16) {
    float4 a4 = *(const float4*)(A + (size_t)(m0 + arow) * K + k0 + akq);
    float4 b4 = *(const float4*)(B + (size_t)(k0 + brow) * N + n0 + bcq);
    As[akq+0][arow] = a4.x; As[akq+1][arow] = a4.y; As[akq+2][arow] = a4.z; As[akq+3][arow] = a4.w;
    *(float4*)&Bs[brow][bcq] = b4;
    __syncthreads();
#pragma unroll
    for (int k = 0; k < 16; ++k) {
      float4 a = *(const float4*)&As[k][ty*4];
      float4 b = *(const float4*)&Bs[k][tx*4];
      float ar[4] = {a.x,a.y,a.z,a.w}, br[4] = {b.x,b.y,b.z,b.w};
#pragma unroll
      for (int i = 0; i < 4; ++i)
#pragma unroll
        for (int j = 0; j < 4; ++j) acc[i][j] = fmaf(ar[i], br[j], acc[i][j]);
    }
    __syncthreads();
  }
#pragma unroll
  for (int i = 0; i < 4; ++i) {
    const int m = m0 + ty*4 + i;
    float cr[4];
    float4 mk;
    if (maskgt) mk = *(const float4*)(maskgt + (size_t)m * N + n0 + tx*4);
#pragma unroll
    for (int j = 0; j < 4; ++j) cr[j] = acc[i][j];
    if (maskgt) {
      if (!(mk.x > 0.f)) cr[0] = 0.f;
      if (!(mk.y > 0.f)) cr[1] = 0.f;
      if (!(mk.z > 0.f)) cr[2] = 0.f;
      if (!(mk.w > 0.f)) cr[3] = 0.f;
    }
    float4 c; c.x = cr[0]; c.y = cr[1]; c.z = cr[2]; c.w = cr[3];
    *(float4*)(C + (size_t)m * N + n0 + tx*4) = c;
  }
}

// ---------------- GEMM TN: C[M,N] = A[K,M]^T * B[K,N] ------------------------
__global__ __launch_bounds__(256) void gemm_tn_kernel(
    const float* __restrict__ A, const float* __restrict__ B,
    float* __restrict__ C, int M, int N, int K)
{
  __shared__ float As[16][68];
  __shared__ float Bs[16][68];
  const int tid = threadIdx.x;
  const int m0 = blockIdx.y * 64, n0 = blockIdx.x * 64;
  const int ty = tid >> 4, tx = tid & 15;
  const int row = tid >> 4, cq = (tid & 15) * 4;
  float acc[4][4] = {};
  for (int k0 = 0; k0 < K; k0 += 16) {
    float4 a4 = *(const float4*)(A + (size_t)(k0 + row) * M + m0 + cq);
    float4 b4 = *(const float4*)(B + (size_t)(k0 + row) * N + n0 + cq);
    *(float4*)&As[row][cq] = a4;
    *(float4*)&Bs[row][cq] = b4;
    __syncthreads();
#pragma unroll
    for (int k = 0; k < 16; ++k) {
      float4 a = *(const float4*)&As[k][ty*4];
      float4 b = *(const float4*)&Bs[k][tx*4];
      float ar[4] = {a.x,a.y,a.z,a.w}, br[4] = {b.x,b.y,b.z,b.w};
#pragma unroll
      for (int i = 0; i < 4; ++i)
#pragma unroll
        for (int j = 0; j < 4; ++j) acc[i][j] = fmaf(ar[i], br[j], acc[i][j]);
    }
    __syncthreads();
  }
#pragma unroll
  for (int i = 0; i < 4; ++i) {
    const int m = m0 + ty*4 + i;
    float4 c; c.x = acc[i][0]; c.y = acc[i][1]; c.z = acc[i][2]; c.w = acc[i][3];
    *(float4*)(C + (size_t)m * N + n0 + tx*4) = c;
  }
}

// ---------------- LayerNorm forward (wave per token) --------------------------
// fastmode: x = p - v*(tmat + stepb*sdot[t]);  else x = p
__global__ __launch_bounds__(256) void ln_fwd_kernel(
    const float* __restrict__ p, const float* __restrict__ v,
    const float* __restrict__ tmat, const float* __restrict__ stepb,
    const float* __restrict__ sdot, const float* __restrict__ gamma,
    const float* __restrict__ beta, float* __restrict__ o,
    float* __restrict__ mu_out, float* __restrict__ rstd_out, int fastmode)
{
  const int t = blockIdx.x * 4 + (threadIdx.x >> 6);
  const int lane = threadIdx.x & 63;
  const int f0 = lane * 4, f1 = 256 + lane * 4;
  const float* pr = p + (size_t)t * F_DIM;
  float4 x0 = *(const float4*)(pr + f0);
  float4 x1 = *(const float4*)(pr + f1);
  if (fastmode) {
    const float* vr = v + (size_t)t * F_DIM;
    const float* tr = tmat + (size_t)t * F_DIM;
    const float sdt = sdot[t];
    float4 v0 = *(const float4*)(vr + f0), v1 = *(const float4*)(vr + f1);
    float4 t0 = *(const float4*)(tr + f0), t1 = *(const float4*)(tr + f1);
    float4 s0 = *(const float4*)(stepb + f0), s1 = *(const float4*)(stepb + f1);
    x0.x -= v0.x * (t0.x + s0.x * sdt);
    x0.y -= v0.y * (t0.y + s0.y * sdt);
    x0.z -= v0.z * (t0.z + s0.z * sdt);
    x0.w -= v0.w * (t0.w + s0.w * sdt);
    x1.x -= v1.x * (t1.x + s1.x * sdt);
    x1.y -= v1.y * (t1.y + s1.y * sdt);
    x1.z -= v1.z * (t1.z + s1.z * sdt);
    x1.w -= v1.w * (t1.w + s1.w * sdt);
  }
  float s  = x0.x + x0.y + x0.z + x0.w + x1.x + x1.y + x1.z + x1.w;
  float ss = x0.x*x0.x + x0.y*x0.y + x0.z*x0.z + x0.w*x0.w
           + x1.x*x1.x + x1.y*x1.y + x1.z*x1.z + x1.w*x1.w;
  s = wave_sum(s); ss = wave_sum(ss);
  const float mu = s * (1.f / F_DIM);
  const float var = ss * (1.f / F_DIM) - mu * mu;
  const float rstd = rsqrtf(var + LN_EPS);
  float4 g0 = *(const float4*)(gamma + f0), g1 = *(const float4*)(gamma + f1);
  float4 b0 = *(const float4*)(beta + f0),  b1 = *(const float4*)(beta + f1);
  float4 y0, y1;
  y0.x = (x0.x - mu) * rstd * g0.x + b0.x;
  y0.y = (x0.y - mu) * rstd * g0.y + b0.y;
  y0.z = (x0.z - mu) * rstd * g0.z + b0.z;
  y0.w = (x0.w - mu) * rstd * g0.w + b0.w;
  y1.x = (x1.x - mu) * rstd * g1.x + b1.x;
  y1.y = (x1.y - mu) * rstd * g1.y + b1.y;
  y1.z = (x1.z - mu) * rstd * g1.z + b1.z;
  y1.w = (x1.w - mu) * rstd * g1.w + b1.w;
  *(float4*)(o + (size_t)t * F_DIM + f0) = y0;
  *(float4*)(o + (size_t)t * F_DIM + f1) = y1;
  if (!fastmode && lane == 0) { mu_out[t] = mu; rstd_out[t] = rstd; }
}

// ---------------- LayerNorm backward (wave per token) -------------------------
// true do = dO_acc - E[label]; dp = rstd*(dh - mean(dh) - xhat*mean(dh*xhat))
__global__ __launch_bounds__(256) void ln_bwd_kernel(
    const float* __restrict__ dO, const float* __restrict__ E,
    const int* __restrict__ labels, const float* __restrict__ gamma,
    const float* __restrict__ p, const float* __restrict__ mu_,
    const float* __restrict__ rstd_, float* __restrict__ dp)
{
  const int t = blockIdx.x * 4 + (threadIdx.x >> 6);
  const int lane = threadIdx.x & 63;
  const int f0 = lane * 4, f1 = 256 + lane * 4;
  const int lab = labels[t];
  const float mu = mu_[t], rstd = rstd_[t];
  const float* dor = dO + (size_t)t * F_DIM;
  const float* er  = E + (size_t)lab * F_DIM;
  const float* pr  = p + (size_t)t * F_DIM;
  alignas(16) float d[8], e[8], g[8], x[8];
  *(float4*)&d[0] = *(const float4*)(dor + f0); *(float4*)&d[4] = *(const float4*)(dor + f1);
  *(float4*)&e[0] = *(const float4*)(er + f0);  *(float4*)&e[4] = *(const float4*)(er + f1);
  *(float4*)&g[0] = *(const float4*)(gamma + f0); *(float4*)&g[4] = *(const float4*)(gamma + f1);
  *(float4*)&x[0] = *(const float4*)(pr + f0);  *(float4*)&x[4] = *(const float4*)(pr + f1);
  float dh[8], xh[8];
  float s1 = 0.f, s2 = 0.f;
#pragma unroll
  for (int i = 0; i < 8; ++i) {
    dh[i] = (d[i] - e[i]) * g[i];
    xh[i] = (x[i] - mu) * rstd;
    s1 += dh[i];
    s2 += dh[i] * xh[i];
  }
  s1 = wave_sum(s1); s2 = wave_sum(s2);
  const float c1 = s1 * (1.f / F_DIM), c2 = s2 * (1.f / F_DIM);
  alignas(16) float outv[8];
#pragma unroll
  for (int i = 0; i < 8; ++i) outv[i] = rstd * (dh[i] - c1 - xh[i] * c2);
  *(float4*)(dp + (size_t)t * F_DIM + f0) = *(float4*)&outv[0];
  *(float4*)(dp + (size_t)t * F_DIM + f1) = *(float4*)&outv[4];
}

// ---------------- column sum with atomics -------------------------------------
__global__ __launch_bounds__(256) void colsum_kernel(
    const float* __restrict__ X, float* __restrict__ out)
{
  const int f = blockIdx.x * 256 + threadIdx.x;      // F=512 -> grid.x = 2
  const int t0 = blockIdx.y * 128;                   // grid.y = 16
  float s = 0.f;
  for (int r = 0; r < 128; ++r) s += X[(size_t)(t0 + r) * F_DIM + f];
  atomicAdd(out + f, s);
}

// ---------------- sdot[t] = dot(v[t,:], gbp) ----------------------------------
__global__ __launch_bounds__(256) void sdot_kernel(
    const float* __restrict__ v, const float* __restrict__ gbp,
    float* __restrict__ sd)
{
  const int t = blockIdx.x * 4 + (threadIdx.x >> 6);
  const int lane = threadIdx.x & 63;
  const int f0 = lane * 4, f1 = 256 + lane * 4;
  const float* vr = v + (size_t)t * F_DIM;
  float4 a0 = *(const float4*)(vr + f0), a1 = *(const float4*)(vr + f1);
  float4 b0 = *(const float4*)(gbp + f0), b1 = *(const float4*)(gbp + f1);
  float s = a0.x*b0.x + a0.y*b0.y + a0.z*b0.z + a0.w*b0.w
          + a1.x*b1.x + a1.y*b1.y + a1.z*b1.z + a1.w*b1.w;
  s = wave_sum(s);
  if (lane == 0) sd[t] = s;
}

// ---------------- softmax stats over a V-chunk (online, 64-token tile) --------
__global__ __launch_bounds__(256) void softmax_stats_kernel(
    const float* __restrict__ o, const float* __restrict__ E,
    const float* __restrict__ ob, float* __restrict__ mpart,
    float* __restrict__ zpart)
{
  __shared__ float As[16][68];
  __shared__ float Bs[16][68];
  __shared__ float red[64][17];
  __shared__ float rm[64], rz[64], nm[64];
  const int tid = threadIdx.x;
  const int m0 = blockIdx.y * 64;
  const int vbase = blockIdx.x * VCH;
  if (tid < 64) { rm[tid] = -1e30f; rz[tid] = 0.f; }
  const int ty = tid >> 4, tx = tid & 15;
  const int lrow = tid >> 2, lkq = (tid & 3) * 4;
  __syncthreads();
  for (int vt = 0; vt < VCH / 64; ++vt) {
    const int v0 = vbase + vt * 64;
    float acc[4][4] = {};
    for (int k0 = 0; k0 < F_DIM; k0 += 16) {
      float4 a4 = *(const float4*)(o + (size_t)(m0 + lrow) * F_DIM + k0 + lkq);
      float4 b4 = *(const float4*)(E + (size_t)(v0 + lrow) * F_DIM + k0 + lkq);
      As[lkq+0][lrow] = a4.x; As[lkq+1][lrow] = a4.y; As[lkq+2][lrow] = a4.z; As[lkq+3][lrow] = a4.w;
      Bs[lkq+0][lrow] = b4.x; Bs[lkq+1][lrow] = b4.y; Bs[lkq+2][lrow] = b4.z; Bs[lkq+3][lrow] = b4.w;
      __syncthreads();
#pragma unroll
      for (int k = 0; k < 16; ++k) {
        float4 a = *(const float4*)&As[k][ty*4];
        float4 b = *(const float4*)&Bs[k][tx*4];
        float ar[4] = {a.x,a.y,a.z,a.w}, br[4] = {b.x,b.y,b.z,b.w};
#pragma unroll
        for (int i = 0; i < 4; ++i)
#pragma unroll
          for (int j = 0; j < 4; ++j) acc[i][j] = fmaf(ar[i], br[j], acc[i][j]);
      }
      __syncthreads();
    }
#pragma unroll
    for (int j = 0; j < 4; ++j) {
      const float obv = ob[v0 + tx*4 + j];
#pragma unroll
      for (int i = 0; i < 4; ++i) acc[i][j] += obv;
    }
#pragma unroll
    for (int i = 0; i < 4; ++i) {
      float mx = fmaxf(fmaxf(acc[i][0], acc[i][1]), fmaxf(acc[i][2], acc[i][3]));
      red[ty*4 + i][tx] = mx;
    }
    __syncthreads();
    if (tid < 64) {
      float mx = rm[tid];
#pragma unroll
      for (int q = 0; q < 16; ++q) mx = fmaxf(mx, red[tid][q]);
      nm[tid] = mx;
    }
    __syncthreads();
#pragma unroll
    for (int i = 0; i < 4; ++i) {
      const float nmv = nm[ty*4 + i];
      float sv = __expf(acc[i][0]-nmv) + __expf(acc[i][1]-nmv)
               + __expf(acc[i][2]-nmv) + __expf(acc[i][3]-nmv);
      red[ty*4 + i][tx] = sv;
    }
    __syncthreads();
    if (tid < 64) {
      float sv = 0.f;
#pragma unroll
      for (int q = 0; q < 16; ++q) sv += red[tid][q];
      rz[tid] = rz[tid] * __expf(rm[tid] - nm[tid]) + sv;
      rm[tid] = nm[tid];
    }
    __syncthreads();
  }
  if (tid < 64) {
    mpart[(size_t)(m0 + tid) * NVC + blockIdx.x] = rm[tid];
    zpart[(size_t)(m0 + tid) * NVC + blockIdx.x] = rz[tid];
  }
}

// ---------------- combine partial stats ---------------------------------------
__global__ void combine_kernel(const float* __restrict__ mpart,
                               const float* __restrict__ zpart,
                               float* __restrict__ m, float* __restrict__ z)
{
  const int t = blockIdx.x * 256 + threadIdx.x;
  if (t >= T_TOK) return;
  float mm = -1e30f;
  for (int c = 0; c < NVC; ++c) mm = fmaxf(mm, mpart[(size_t)t * NVC + c]);
  float zz = 0.f;
  for (int c = 0; c < NVC; ++c)
    zz += zpart[(size_t)t * NVC + c] * __expf(mpart[(size_t)t * NVC + c] - mm);
  m[t] = mm; z[t] = zz;
}

// ---------------- dO += softmax(logits) @ E over a V-chunk (flash-style) ------
__global__ __launch_bounds__(256) void do_accum_kernel(
    const float* __restrict__ o, const float* __restrict__ E,
    const float* __restrict__ ob, const float* __restrict__ ms,
    const float* __restrict__ zs, float* __restrict__ dO)
{
  __shared__ float o_s[16][516];
  __shared__ float Es[16][68];
  __shared__ float P_s[16][68];
  __shared__ float mzm[16], mzr[16];
  const int tid = threadIdx.x;
  const int t0 = blockIdx.y * 16;
  const int vbase = blockIdx.x * VCH;
#pragma unroll
  for (int i = 0; i < 8; ++i) {
    const int idx = tid + i * 256;
    const int r = idx >> 7, c = (idx & 127) * 4;
    *(float4*)&o_s[r][c] = *(const float4*)(o + (size_t)(t0 + r) * F_DIM + c);
  }
  if (tid < 16) { mzm[tid] = ms[t0 + tid]; mzr[tid] = 1.f / zs[t0 + tid]; }
  __syncthreads();
  const int tL = tid & 15, vg = tid >> 4;   // phase A mapping (logits)
  const int fg = tid & 63, tg = tid >> 6;   // phase B mapping (P @ E)
  const int evrow = tid >> 2, ekq = (tid & 3) * 4;
  float acc[4][8] = {};
  for (int vt = 0; vt < VCH / 64; ++vt) {
    const int v0 = vbase + vt * 64;
    float lacc[4] = {0.f, 0.f, 0.f, 0.f};
    for (int kt = 0; kt < F_DIM; kt += 16) {
      float4 e4 = *(const float4*)(E + (size_t)(v0 + evrow) * F_DIM + kt + ekq);
      Es[ekq+0][evrow] = e4.x; Es[ekq+1][evrow] = e4.y; Es[ekq+2][evrow] = e4.z; Es[ekq+3][evrow] = e4.w;
      __syncthreads();
#pragma unroll
      for (int k = 0; k < 16; ++k) {
        const float a = o_s[tL][kt + k];
#pragma unroll
        for (int j = 0; j < 4; ++j) lacc[j] = fmaf(a, Es[k][vg*4 + j], lacc[j]);
      }
      __syncthreads();
    }
#pragma unroll
    for (int j = 0; j < 4; ++j) {
      const int v = v0 + vg*4 + j;
      const float l = lacc[j] + ob[v];
      P_s[tL][vg*4 + j] = __expf(l - mzm[tL]) * mzr[tL];
    }
    __syncthreads();
    for (int vv = 0; vv < 64; ++vv) {
      const float* er = E + (size_t)(v0 + vv) * F_DIM + fg * 8;
      float4 e0 = *(const float4*)er;
      float4 e1 = *(const float4*)(er + 4);
#pragma unroll
      for (int i = 0; i < 4; ++i) {
        const float pv = P_s[tg*4 + i][vv];
        acc[i][0] = fmaf(pv, e0.x, acc[i][0]); acc[i][1] = fmaf(pv, e0.y, acc[i][1]);
        acc[i][2] = fmaf(pv, e0.z, acc[i][2]); acc[i][3] = fmaf(pv, e0.w, acc[i][3]);
        acc[i][4] = fmaf(pv, e1.x, acc[i][4]); acc[i][5] = fmaf(pv, e1.y, acc[i][5]);
        acc[i][6] = fmaf(pv, e1.z, acc[i][6]); acc[i][7] = fmaf(pv, e1.w, acc[i][7]);
      }
    }
    __syncthreads();
  }
#pragma unroll
  for (int i = 0; i < 4; ++i) {
    float* dst = dO + (size_t)(t0 + tg*4 + i) * F_DIM + fg * 8;
#pragma unroll
    for (int q = 0; q < 8; ++q) atomicAdd(dst + q, acc[i][q]);
  }
}

// ---------------- fast loss: m + log z - (logit at label) ---------------------
__global__ __launch_bounds__(256) void fast_loss_kernel(
    const float* __restrict__ of, const float* __restrict__ E,
    const float* __restrict__ ob, const int* __restrict__ labels,
    const float* __restrict__ mf, const float* __restrict__ zf,
    float* __restrict__ out)
{
  const int t = blockIdx.x * 4 + (threadIdx.x >> 6);
  const int lane = threadIdx.x & 63;
  const int f0 = lane * 4, f1 = 256 + lane * 4;
  const int lab = labels[t];
  const float* orow = of + (size_t)t * F_DIM;
  const float* er = E + (size_t)lab * F_DIM;
  float4 a0 = *(const float4*)(orow + f0), a1 = *(const float4*)(orow + f1);
  float4 b0 = *(const float4*)(er + f0),   b1 = *(const float4*)(er + f1);
  float s = a0.x*b0.x + a0.y*b0.y + a0.z*b0.z + a0.w*b0.w
          + a1.x*b1.x + a1.y*b1.y + a1.z*b1.z + a1.w*b1.w;
  s = wave_sum(s);
  if (lane == 0) out[t] = mf[t] + logf(zf[t]) - (s + ob[lab]);
}

// ==============================================================================
extern "C" void kernel_launch(void* const* d_in, const int* in_sizes, int n_in,
                              void* d_out, int out_size, void* d_ws, size_t ws_size,
                              hipStream_t stream)
{
  const float* h      = (const float*)d_in[0];
  const float* E      = (const float*)d_in[1];
  const float* ob     = (const float*)d_in[2];
  const int*   labels = (const int*)d_in[3];
  const float* Wh     = (const float*)d_in[4];
  const float* bh     = (const float*)d_in[5];
  const float* hb     = (const float*)d_in[6];
  const float* Wp     = (const float*)d_in[7];
  const float* bp     = (const float*)d_in[8];
  const float* gamma  = (const float*)d_in[9];
  const float* beta   = (const float*)d_in[10];
  const float* stepW  = (const float*)d_in[11];
  const float* stepb  = (const float*)d_in[12];

  float* out_loss = (float*)d_out;                 // [2048]
  float* out_gWh  = out_loss + T_TOK;              // [512,1024]
  float* out_ghb  = out_gWh + F_DIM * H_DIM;       // [512]
  float* out_gWp  = out_ghb + F_DIM;               // [512,512]
  float* out_gbp  = out_gWp + F_DIM * F_DIM;       // [512]

  float* ws = (float*)d_ws;
  const size_t TF = (size_t)T_TOK * F_DIM;
  float* v_   = ws;
  float* p_   = ws + TF;
  float* o_   = ws + 2 * TF;
  float* dO_  = ws + 3 * TF;
  float* dp_  = ws + 4 * TF;
  float* dv_  = ws + 5 * TF;
  float* u_   = ws + 6 * TF;
  float* tm_  = ws + 7 * TF;
  float* of_  = ws + 8 * TF;
  float* sm   = ws + 9 * TF;
  float* mu_    = sm;
  float* rstd_  = sm + 2048;
  float* ms_    = sm + 4096;
  float* zs_    = sm + 6144;
  float* mf_    = sm + 8192;
  float* zf_    = sm + 10240;
  float* sd_    = sm + 12288;
  float* mpart  = sm + 14336;
  float* zpart  = sm + 14336 + T_TOK * NVC;

  // zero atomic accumulators
  zero_kernel<<<(int)((TF + 255) / 256), 256, 0, stream>>>(dO_, (int)TF);
  zero_kernel<<<2, 256, 0, stream>>>(out_ghb, F_DIM);
  zero_kernel<<<2, 256, 0, stream>>>(out_gbp, F_DIM);

  // v = relu(h @ Wh^T + bh + hb)
  gemm_nt_kernel<<<dim3(F_DIM/64, T_TOK/64), 256, 0, stream>>>(
      h, nullptr, Wh, v_, T_TOK, F_DIM, H_DIM, bh, hb, 1);
  // p = v @ Wp^T + bp
  gemm_nt_kernel<<<dim3(8, 32), 256, 0, stream>>>(
      v_, nullptr, Wp, p_, T_TOK, F_DIM, F_DIM, bp, nullptr, 0);
  // o = LN(p)
  ln_fwd_kernel<<<512, 256, 0, stream>>>(
      p_, nullptr, nullptr, nullptr, nullptr, gamma, beta, o_, mu_, rstd_, 0);
  // slow softmax stats
  softmax_stats_kernel<<<dim3(NVC, T_TOK/64), 256, 0, stream>>>(o_, E, ob, mpart, zpart);
  combine_kernel<<<8, 256, 0, stream>>>(mpart, zpart, ms_, zs_);
  // dO = softmax @ E
  do_accum_kernel<<<dim3(NVC, T_TOK/16), 256, 0, stream>>>(o_, E, ob, ms_, zs_, dO_);
  // dp = LN backward(dO - E[label])
  ln_bwd_kernel<<<512, 256, 0, stream>>>(dO_, E, labels, gamma, p_, mu_, rstd_, dp_);
  // gbp = colsum(dp)
  colsum_kernel<<<dim3(2, 16), 256, 0, stream>>>(dp_, out_gbp);
  // gWp = dp^T @ v
  gemm_tn_kernel<<<dim3(8, 8), 256, 0, stream>>>(dp_, v_, out_gWp, F_DIM, F_DIM, T_TOK);
  // dv = (dp @ Wp) * (v > 0)
  gemm_nn_kernel<<<dim3(8, 32), 256, 0, stream>>>(dp_, Wp, dv_, T_TOK, F_DIM, F_DIM, v_);
  // ghb = colsum(dv)
  colsum_kernel<<<dim3(2, 16), 256, 0, stream>>>(dv_, out_ghb);
  // gWh = dv^T @ h
  gemm_tn_kernel<<<dim3(16, 8), 256, 0, stream>>>(dv_, h, out_gWh, F_DIM, H_DIM, T_TOK);
  // u = v @ gWp
  gemm_nn_kernel<<<dim3(8, 32), 256, 0, stream>>>(v_, out_gWp, u_, T_TOK, F_DIM, F_DIM, nullptr);
  // sdot = v . gbp
  sdot_kernel<<<512, 256, 0, stream>>>(v_, out_gbp, sd_);
  // tmat = (v*u) @ stepW^T
  gemm_nt_kernel<<<dim3(8, 32), 256, 0, stream>>>(
      v_, u_, stepW, tm_, T_TOK, F_DIM, F_DIM, nullptr, nullptr, 0);
  // o_fast = LN(p - v*(tmat + stepb*sdot))
  ln_fwd_kernel<<<512, 256, 0, stream>>>(
      p_, v_, tm_, stepb, sd_, gamma, beta, of_, nullptr, nullptr, 1);
  // fast softmax stats
  softmax_stats_kernel<<<dim3(NVC, T_TOK/64), 256, 0, stream>>>(of_, E, ob, mpart, zpart);
  combine_kernel<<<8, 256, 0, stream>>>(mpart, zpart, mf_, zf_);
  // fast_loss
  fast_loss_kernel<<<512, 256, 0, stream>>>(of_, E, ob, labels, mf_, zf_, out_loss);
}

// Round 2
// 1470.252 us; speedup vs baseline: 4.4581x; 4.4581x over previous
//
#include <hip/hip_runtime.h>
#include <cstddef>
#include <math.h>

#define T_TOK 2048
#define F_DIM 512
#define H_DIM 1024
#define V_DIM 32000
#define NVC_S 25
#define VCH_S 1280
#define NVC_P 20
#define VCH_P 1600
#define NPART (NVC_S*4)
#define LN_EPS 1e-5f

typedef __attribute__((ext_vector_type(8))) short bf16x8;
typedef __attribute__((ext_vector_type(4))) float f32x4;

__device__ __forceinline__ unsigned short f2bf(float x) {
  unsigned int u = __float_as_uint(x);
  u += 0x7fffu + ((u >> 16) & 1u);
  return (unsigned short)(u >> 16);
}

// async global->LDS, 16B per lane; LDS dest = wave-uniform base + lane*16
__device__ __forceinline__ void gld16(const unsigned short* gsrc, unsigned short* ldst) {
  __builtin_amdgcn_global_load_lds(
      (const __attribute__((address_space(1))) unsigned int*)gsrc,
      (__attribute__((address_space(3))) unsigned int*)ldst, 16, 0, 0);
}

__device__ inline float wave_sum(float x) {
#pragma unroll
  for (int off = 32; off > 0; off >>= 1) x += __shfl_xor(x, off, 64);
  return x;
}

// ---------------- zero ----------------
__global__ void zero_kernel(float* __restrict__ p, int n) {
  int i = blockIdx.x * 256 + threadIdx.x;
  if (i < n) p[i] = 0.f;
}

// ---------------- convert E to bf16 (row-major) + bf16 transposed ------------
__global__ __launch_bounds__(256) void convertE_kernel(
    const float* __restrict__ E, unsigned short* __restrict__ Ebf,
    unsigned short* __restrict__ Etbf)
{
  __shared__ float tile[64][65];
  const int tid = threadIdx.x;
  const int v0 = blockIdx.x * 64, f0 = blockIdx.y * 64;
  const int r = tid >> 4, cq = (tid & 15) * 4;
#pragma unroll
  for (int ps = 0; ps < 4; ++ps) {
    const int row = ps * 16 + r;
    float4 x = *(const float4*)&E[(size_t)(v0 + row) * F_DIM + f0 + cq];
    tile[row][cq + 0] = x.x; tile[row][cq + 1] = x.y;
    tile[row][cq + 2] = x.z; tile[row][cq + 3] = x.w;
    ushort4 u; u.x = f2bf(x.x); u.y = f2bf(x.y); u.z = f2bf(x.z); u.w = f2bf(x.w);
    *(ushort4*)&Ebf[(size_t)(v0 + row) * F_DIM + f0 + cq] = u;
  }
  __syncthreads();
#pragma unroll
  for (int ps = 0; ps < 4; ++ps) {
    const int frow = ps * 16 + r;
    ushort4 u;
    u.x = f2bf(tile[cq + 0][frow]); u.y = f2bf(tile[cq + 1][frow]);
    u.z = f2bf(tile[cq + 2][frow]); u.w = f2bf(tile[cq + 3][frow]);
    *(ushort4*)&Etbf[(size_t)(f0 + frow) * V_DIM + v0 + cq] = u;
  }
}

// ---------------- GEMM NT: C[M,N] = (A ⊙ A2)[M,K] * B[N,K]^T (+bias,relu) ----
__global__ __launch_bounds__(256) void gemm_nt_kernel(
    const float* __restrict__ A, const float* __restrict__ A2,
    const float* __restrict__ B, float* __restrict__ C,
    int M, int N, int K,
    const float* __restrict__ bias1, const float* __restrict__ bias2, int relu)
{
  __shared__ float As[16][68];
  __shared__ float Bs[16][68];
  const int tid = threadIdx.x;
  const int m0 = blockIdx.y * 64, n0 = blockIdx.x * 64;
  const int ty = tid >> 4, tx = tid & 15;
  const int lrow = tid >> 2, lkq = (tid & 3) * 4;
  float acc[4][4] = {};
  for (int k0 = 0; k0 < K; k0 += 16) {
    float4 a4 = *(const float4*)(A + (size_t)(m0 + lrow) * K + k0 + lkq);
    if (A2) {
      float4 u4 = *(const float4*)(A2 + (size_t)(m0 + lrow) * K + k0 + lkq);
      a4.x *= u4.x; a4.y *= u4.y; a4.z *= u4.z; a4.w *= u4.w;
    }
    float4 b4 = *(const float4*)(B + (size_t)(n0 + lrow) * K + k0 + lkq);
    As[lkq+0][lrow] = a4.x; As[lkq+1][lrow] = a4.y; As[lkq+2][lrow] = a4.z; As[lkq+3][lrow] = a4.w;
    Bs[lkq+0][lrow] = b4.x; Bs[lkq+1][lrow] = b4.y; Bs[lkq+2][lrow] = b4.z; Bs[lkq+3][lrow] = b4.w;
    __syncthreads();
#pragma unroll
    for (int k = 0; k < 16; ++k) {
      float4 a = *(const float4*)&As[k][ty*4];
      float4 b = *(const float4*)&Bs[k][tx*4];
      float ar[4] = {a.x,a.y,a.z,a.w}, br[4] = {b.x,b.y,b.z,b.w};
#pragma unroll
      for (int i = 0; i < 4; ++i)
#pragma unroll
        for (int j = 0; j < 4; ++j) acc[i][j] = fmaf(ar[i], br[j], acc[i][j]);
    }
    __syncthreads();
  }
#pragma unroll
  for (int i = 0; i < 4; ++i) {
    const int m = m0 + ty*4 + i;
    float cr[4];
#pragma unroll
    for (int j = 0; j < 4; ++j) {
      const int n = n0 + tx*4 + j;
      float v = acc[i][j];
      if (bias1) v += bias1[n];
      if (bias2) v += bias2[n];
      if (relu) v = fmaxf(v, 0.f);
      cr[j] = v;
    }
    float4 c; c.x = cr[0]; c.y = cr[1]; c.z = cr[2]; c.w = cr[3];
    *(float4*)(C + (size_t)m * N + n0 + tx*4) = c;
  }
}

// ---------------- GEMM NN: C[M,N] = A[M,K] * B[K,N], optional relu-mask ------
__global__ __launch_bounds__(256) void gemm_nn_kernel(
    const float* __restrict__ A, const float* __restrict__ B,
    float* __restrict__ C, int M, int N, int K,
    const float* __restrict__ maskgt)
{
  __shared__ float As[16][68];
  __shared__ float Bs[16][68];
  const int tid = threadIdx.x;
  const int m0 = blockIdx.y * 64, n0 = blockIdx.x * 64;
  const int ty = tid >> 4, tx = tid & 15;
  const int arow = tid >> 2, akq = (tid & 3) * 4;
  const int brow = tid >> 4, bcq = (tid & 15) * 4;
  float acc[4][4] = {};
  for (int k0 = 0; k0 < K; k0 += 16) {
    float4 a4 = *(const float4*)(A + (size_t)(m0 + arow) * K + k0 + akq);
    float4 b4 = *(const float4*)(B + (size_t)(k0 + brow) * N + n0 + bcq);
    As[akq+0][arow] = a4.x; As[akq+1][arow] = a4.y; As[akq+2][arow] = a4.z; As[akq+3][arow] = a4.w;
    *(float4*)&Bs[brow][bcq] = b4;
    __syncthreads();
#pragma unroll
    for (int k = 0; k < 16; ++k) {
      float4 a = *(const float4*)&As[k][ty*4];
      float4 b = *(const float4*)&Bs[k][tx*4];
      float ar[4] = {a.x,a.y,a.z,a.w}, br[4] = {b.x,b.y,b.z,b.w};
#pragma unroll
      for (int i = 0; i < 4; ++i)
#pragma unroll
        for (int j = 0; j < 4; ++j) acc[i][j] = fmaf(ar[i], br[j], acc[i][j]);
    }
    __syncthreads();
  }
#pragma unroll
  for (int i = 0; i < 4; ++i) {
    const int m = m0 + ty*4 + i;
    float cr[4];
    float4 mk;
    if (maskgt) mk = *(const float4*)(maskgt + (size_t)m * N + n0 + tx*4);
#pragma unroll
    for (int j = 0; j < 4; ++j) cr[j] = acc[i][j];
    if (maskgt) {
      if (!(mk.x > 0.f)) cr[0] = 0.f;
      if (!(mk.y > 0.f)) cr[1] = 0.f;
      if (!(mk.z > 0.f)) cr[2] = 0.f;
      if (!(mk.w > 0.f)) cr[3] = 0.f;
    }
    float4 c; c.x = cr[0]; c.y = cr[1]; c.z = cr[2]; c.w = cr[3];
    *(float4*)(C + (size_t)m * N + n0 + tx*4) = c;
  }
}

// ---------------- GEMM TN: C[M,N] = A[K,M]^T * B[K,N] ------------------------
__global__ __launch_bounds__(256) void gemm_tn_kernel(
    const float* __restrict__ A, const float* __restrict__ B,
    float* __restrict__ C, int M, int N, int K)
{
  __shared__ float As[16][68];
  __shared__ float Bs[16][68];
  const int tid = threadIdx.x;
  const int m0 = blockIdx.y * 64, n0 = blockIdx.x * 64;
  const int ty = tid >> 4, tx = tid & 15;
  const int row = tid >> 4, cq = (tid & 15) * 4;
  float acc[4][4] = {};
  for (int k0 = 0; k0 < K; k0 += 16) {
    float4 a4 = *(const float4*)(A + (size_t)(k0 + row) * M + m0 + cq);
    float4 b4 = *(const float4*)(B + (size_t)(k0 + row) * N + n0 + cq);
    *(float4*)&As[row][cq] = a4;
    *(float4*)&Bs[row][cq] = b4;
    __syncthreads();
#pragma unroll
    for (int k = 0; k < 16; ++k) {
      float4 a = *(const float4*)&As[k][ty*4];
      float4 b = *(const float4*)&Bs[k][tx*4];
      float ar[4] = {a.x,a.y,a.z,a.w}, br[4] = {b.x,b.y,b.z,b.w};
#pragma unroll
      for (int i = 0; i < 4; ++i)
#pragma unroll
        for (int j = 0; j < 4; ++j) acc[i][j] = fmaf(ar[i], br[j], acc[i][j]);
    }
    __syncthreads();
  }
#pragma unroll
  for (int i = 0; i < 4; ++i) {
    const int m = m0 + ty*4 + i;
    float4 c; c.x = acc[i][0]; c.y = acc[i][1]; c.z = acc[i][2]; c.w = acc[i][3];
    *(float4*)(C + (size_t)m * N + n0 + tx*4) = c;
  }
}

// ---------------- LayerNorm forward (wave per token), emits fp32 + bf16 -------
__global__ __launch_bounds__(256) void ln_fwd_kernel(
    const float* __restrict__ p, const float* __restrict__ v,
    const float* __restrict__ tmat, const float* __restrict__ stepb,
    const float* __restrict__ sdot, const float* __restrict__ gamma,
    const float* __restrict__ beta, float* __restrict__ o,
    unsigned short* __restrict__ obf,
    float* __restrict__ mu_out, float* __restrict__ rstd_out, int fastmode)
{
  const int t = blockIdx.x * 4 + (threadIdx.x >> 6);
  const int lane = threadIdx.x & 63;
  const int f0 = lane * 4, f1 = 256 + lane * 4;
  const float* pr = p + (size_t)t * F_DIM;
  float4 x0 = *(const float4*)(pr + f0);
  float4 x1 = *(const float4*)(pr + f1);
  if (fastmode) {
    const float* vr = v + (size_t)t * F_DIM;
    const float* tr = tmat + (size_t)t * F_DIM;
    const float sdt = sdot[t];
    float4 v0 = *(const float4*)(vr + f0), v1 = *(const float4*)(vr + f1);
    float4 t0 = *(const float4*)(tr + f0), t1 = *(const float4*)(tr + f1);
    float4 s0 = *(const float4*)(stepb + f0), s1 = *(const float4*)(stepb + f1);
    x0.x -= v0.x * (t0.x + s0.x * sdt);
    x0.y -= v0.y * (t0.y + s0.y * sdt);
    x0.z -= v0.z * (t0.z + s0.z * sdt);
    x0.w -= v0.w * (t0.w + s0.w * sdt);
    x1.x -= v1.x * (t1.x + s1.x * sdt);
    x1.y -= v1.y * (t1.y + s1.y * sdt);
    x1.z -= v1.z * (t1.z + s1.z * sdt);
    x1.w -= v1.w * (t1.w + s1.w * sdt);
  }
  float s  = x0.x + x0.y + x0.z + x0.w + x1.x + x1.y + x1.z + x1.w;
  float ss = x0.x*x0.x + x0.y*x0.y + x0.z*x0.z + x0.w*x0.w
           + x1.x*x1.x + x1.y*x1.y + x1.z*x1.z + x1.w*x1.w;
  s = wave_sum(s); ss = wave_sum(ss);
  const float mu = s * (1.f / F_DIM);
  const float var = ss * (1.f / F_DIM) - mu * mu;
  const float rstd = rsqrtf(var + LN_EPS);
  float4 g0 = *(const float4*)(gamma + f0), g1 = *(const float4*)(gamma + f1);
  float4 b0 = *(const float4*)(beta + f0),  b1 = *(const float4*)(beta + f1);
  float4 y0, y1;
  y0.x = (x0.x - mu) * rstd * g0.x + b0.x;
  y0.y = (x0.y - mu) * rstd * g0.y + b0.y;
  y0.z = (x0.z - mu) * rstd * g0.z + b0.z;
  y0.w = (x0.w - mu) * rstd * g0.w + b0.w;
  y1.x = (x1.x - mu) * rstd * g1.x + b1.x;
  y1.y = (x1.y - mu) * rstd * g1.y + b1.y;
  y1.z = (x1.z - mu) * rstd * g1.z + b1.z;
  y1.w = (x1.w - mu) * rstd * g1.w + b1.w;
  *(float4*)(o + (size_t)t * F_DIM + f0) = y0;
  *(float4*)(o + (size_t)t * F_DIM + f1) = y1;
  ushort4 u0, u1;
  u0.x = f2bf(y0.x); u0.y = f2bf(y0.y); u0.z = f2bf(y0.z); u0.w = f2bf(y0.w);
  u1.x = f2bf(y1.x); u1.y = f2bf(y1.y); u1.z = f2bf(y1.z); u1.w = f2bf(y1.w);
  *(ushort4*)(obf + (size_t)t * F_DIM + f0) = u0;
  *(ushort4*)(obf + (size_t)t * F_DIM + f1) = u1;
  if (!fastmode && lane == 0) { mu_out[t] = mu; rstd_out[t] = rstd; }
}

// ---------------- LayerNorm backward (wave per token) -------------------------
__global__ __launch_bounds__(256) void ln_bwd_kernel(
    const float* __restrict__ dO, const float* __restrict__ E,
    const int* __restrict__ labels, const float* __restrict__ gamma,
    const float* __restrict__ p, const float* __restrict__ mu_,
    const float* __restrict__ rstd_, float* __restrict__ dp)
{
  const int t = blockIdx.x * 4 + (threadIdx.x >> 6);
  const int lane = threadIdx.x & 63;
  const int f0 = lane * 4, f1 = 256 + lane * 4;
  const int lab = labels[t];
  const float mu = mu_[t], rstd = rstd_[t];
  const float* dor = dO + (size_t)t * F_DIM;
  const float* er  = E + (size_t)lab * F_DIM;
  const float* pr  = p + (size_t)t * F_DIM;
  alignas(16) float d[8], e[8], g[8], x[8];
  *(float4*)&d[0] = *(const float4*)(dor + f0); *(float4*)&d[4] = *(const float4*)(dor + f1);
  *(float4*)&e[0] = *(const float4*)(er + f0);  *(float4*)&e[4] = *(const float4*)(er + f1);
  *(float4*)&g[0] = *(const float4*)(gamma + f0); *(float4*)&g[4] = *(const float4*)(gamma + f1);
  *(float4*)&x[0] = *(const float4*)(pr + f0);  *(float4*)&x[4] = *(const float4*)(pr + f1);
  float dh[8], xh[8];
  float s1 = 0.f, s2 = 0.f;
#pragma unroll
  for (int i = 0; i < 8; ++i) {
    dh[i] = (d[i] - e[i]) * g[i];
    xh[i] = (x[i] - mu) * rstd;
    s1 += dh[i];
    s2 += dh[i] * xh[i];
  }
  s1 = wave_sum(s1); s2 = wave_sum(s2);
  const float c1 = s1 * (1.f / F_DIM), c2 = s2 * (1.f / F_DIM);
  alignas(16) float outv[8];
#pragma unroll
  for (int i = 0; i < 8; ++i) outv[i] = rstd * (dh[i] - c1 - xh[i] * c2);
  *(float4*)(dp + (size_t)t * F_DIM + f0) = *(float4*)&outv[0];
  *(float4*)(dp + (size_t)t * F_DIM + f1) = *(float4*)&outv[4];
}

// ---------------- column sum with atomics -------------------------------------
__global__ __launch_bounds__(256) void colsum_kernel(
    const float* __restrict__ X, float* __restrict__ out)
{
  const int f = blockIdx.x * 256 + threadIdx.x;
  const int t0 = blockIdx.y * 128;
  float s = 0.f;
  for (int r = 0; r < 128; ++r) s += X[(size_t)(t0 + r) * F_DIM + f];
  atomicAdd(out + f, s);
}

// ---------------- sdot[t] = dot(v[t,:], gbp) ----------------------------------
__global__ __launch_bounds__(256) void sdot_kernel(
    const float* __restrict__ v, const float* __restrict__ gbp,
    float* __restrict__ sd)
{
  const int t = blockIdx.x * 4 + (threadIdx.x >> 6);
  const int lane = threadIdx.x & 63;
  const int f0 = lane * 4, f1 = 256 + lane * 4;
  const float* vr = v + (size_t)t * F_DIM;
  float4 a0 = *(const float4*)(vr + f0), a1 = *(const float4*)(vr + f1);
  float4 b0 = *(const float4*)(gbp + f0), b1 = *(const float4*)(gbp + f1);
  float s = a0.x*b0.x + a0.y*b0.y + a0.z*b0.z + a0.w*b0.w
          + a1.x*b1.x + a1.y*b1.y + a1.z*b1.z + a1.w*b1.w;
  s = wave_sum(s);
  if (lane == 0) sd[t] = s;
}

// ---------------- MFMA softmax stats: S^T = E·o^T, online m/z per token -------
// grid(NVC_S, T/64), block 256. wave w owns v rows [w*64,w*64+64) of each
// 256-vocab iter tile; per-wave online (m,z) over its vocab subset.
__global__ __launch_bounds__(256) void stats_mfma_kernel(
    const unsigned short* __restrict__ obf, const unsigned short* __restrict__ Ebf,
    const float* __restrict__ ob, float* __restrict__ mpart,
    float* __restrict__ zpart)
{
  __shared__ __align__(16) unsigned short Es[256 * 64];  // 256 v-rows x 64 k (XOR-swizzled granules)
  __shared__ __align__(16) unsigned short Os[64 * 64];   // 64 t-rows x 64 k
  const int tid = threadIdx.x;
  const int w = tid >> 6, lane = tid & 63;
  const int c15 = lane & 15, q = lane >> 4;
  const int t0 = blockIdx.y * 64;
  const int vbase = blockIdx.x * VCH_S;
  float mrun[4] = {-1e30f, -1e30f, -1e30f, -1e30f};
  float zrun[4] = {0.f, 0.f, 0.f, 0.f};
  for (int it = 0; it < VCH_S / 256; ++it) {
    const int v0 = vbase + it * 256;
    f32x4 acc[4][4];
#pragma unroll
    for (int mi = 0; mi < 4; ++mi)
#pragma unroll
      for (int nj = 0; nj < 4; ++nj) acc[mi][nj] = (f32x4){0.f, 0.f, 0.f, 0.f};
    for (int ks = 0; ks < 8; ++ks) {
      const int kb = ks * 64;
#pragma unroll
      for (int cc = 0; cc < 8; ++cc) {
        int gid = (w * 8 + cc) * 64 + lane;
        int row = gid >> 3, dg = (gid & 7) ^ (row & 7);
        gld16(Ebf + (size_t)(v0 + row) * F_DIM + kb + dg * 8, &Es[(w * 8 + cc) * 512]);
      }
#pragma unroll
      for (int cc = 0; cc < 2; ++cc) {
        int gid = (w * 2 + cc) * 64 + lane;
        int row = gid >> 3, dg = (gid & 7) ^ (row & 7);
        gld16(obf + (size_t)(t0 + row) * F_DIM + kb + dg * 8, &Os[(w * 2 + cc) * 512]);
      }
      __syncthreads();
#pragma unroll
      for (int kk = 0; kk < 2; ++kk) {
        bf16x8 af[4], bo[4];
#pragma unroll
        for (int mi = 0; mi < 4; ++mi) {
          int row = w * 64 + mi * 16 + c15;
          int g = (kk * 4 + q) ^ (row & 7);
          af[mi] = *(const bf16x8*)&Es[(row * 8 + g) * 8];
        }
#pragma unroll
        for (int nj = 0; nj < 4; ++nj) {
          int row = nj * 16 + c15;
          int g = (kk * 4 + q) ^ (row & 7);
          bo[nj] = *(const bf16x8*)&Os[(row * 8 + g) * 8];
        }
#pragma unroll
        for (int mi = 0; mi < 4; ++mi)
#pragma unroll
          for (int nj = 0; nj < 4; ++nj)
            acc[mi][nj] = __builtin_amdgcn_mfma_f32_16x16x32_bf16(af[mi], bo[nj], acc[mi][nj], 0, 0, 0);
      }
      __syncthreads();
    }
    // epilogue: +ob, online (m,z) per token column
    float obv[4][4];
#pragma unroll
    for (int mi = 0; mi < 4; ++mi)
#pragma unroll
      for (int r = 0; r < 4; ++r) obv[mi][r] = ob[v0 + w * 64 + mi * 16 + q * 4 + r];
#pragma unroll
    for (int nj = 0; nj < 4; ++nj) {
      float mx = -1e30f;
#pragma unroll
      for (int mi = 0; mi < 4; ++mi)
#pragma unroll
        for (int r = 0; r < 4; ++r) mx = fmaxf(mx, acc[mi][nj][r] + obv[mi][r]);
      mx = fmaxf(mx, __shfl_xor(mx, 16));
      mx = fmaxf(mx, __shfl_xor(mx, 32));
      const float mnew = fmaxf(mrun[nj], mx);
      float sv = 0.f;
#pragma unroll
      for (int mi = 0; mi < 4; ++mi)
#pragma unroll
        for (int r = 0; r < 4; ++r) sv += __expf(acc[mi][nj][r] + obv[mi][r] - mnew);
      sv += __shfl_xor(sv, 16);
      sv += __shfl_xor(sv, 32);
      zrun[nj] = zrun[nj] * __expf(mrun[nj] - mnew) + sv;
      mrun[nj] = mnew;
    }
  }
  if (lane < 16) {
    const int cc = blockIdx.x * 4 + w;
#pragma unroll
    for (int nj = 0; nj < 4; ++nj) {
      const int t = t0 + nj * 16 + lane;
      mpart[(size_t)t * NPART + cc] = mrun[nj];
      zpart[(size_t)t * NPART + cc] = zrun[nj];
    }
  }
}

// ---------------- combine partial stats ---------------------------------------
__global__ void combine_kernel(const float* __restrict__ mpart,
                               const float* __restrict__ zpart,
                               float* __restrict__ m, float* __restrict__ z)
{
  const int t = blockIdx.x * 256 + threadIdx.x;
  if (t >= T_TOK) return;
  float mm = -1e30f;
  for (int c = 0; c < NPART; ++c) mm = fmaxf(mm, mpart[(size_t)t * NPART + c]);
  float zz = 0.f;
  for (int c = 0; c < NPART; ++c)
    zz += zpart[(size_t)t * NPART + c] * __expf(mpart[(size_t)t * NPART + c] - mm);
  m[t] = mm; z[t] = zz;
}

// ---------------- MFMA dO += softmax(o·E^T+ob) @ E (flash-style, 2-pass) ------
// grid(NVC_P, T/64), block 256 (4 waves). Per 64-vocab iter: phase A computes
// S^T (wave w owns 16 v-rows x 64 t), P=exp(S-m)/z -> LDS (A-layout);
// phase B: dO[64t x 512f] += P @ Et, wave w owns 64 f per 256-f half.
__global__ __launch_bounds__(256) void pe_accum_kernel(
    const unsigned short* __restrict__ obf, const unsigned short* __restrict__ Ebf,
    const unsigned short* __restrict__ Etbf, const float* __restrict__ ob,
    const float* __restrict__ ms, const float* __restrict__ zs,
    float* __restrict__ dO)
{
  __shared__ __align__(16) unsigned short Es2[64 * 64];   // E slab 64v x 64k
  __shared__ __align__(16) unsigned short Os2[64 * 64];   // o slab 64t x 64k
  __shared__ __align__(16) unsigned short Ps[64 * 64];    // P 64t x 64v (bf16)
  __shared__ __align__(16) unsigned short Ets[256 * 64];  // Et half 256f x 64v
  const int tid = threadIdx.x;
  const int w = tid >> 6, lane = tid & 63;
  const int c15 = lane & 15, q = lane >> 4;
  const int t0 = blockIdx.y * 64;
  const int vbase = blockIdx.x * VCH_P;
  float mreg[4], zrreg[4];
#pragma unroll
  for (int nj = 0; nj < 4; ++nj) {
    const int t = t0 + nj * 16 + c15;
    mreg[nj] = ms[t]; zrreg[nj] = 1.f / zs[t];
  }
  f32x4 pacc[4][8];
#pragma unroll
  for (int mi = 0; mi < 4; ++mi)
#pragma unroll
    for (int fj = 0; fj < 8; ++fj) pacc[mi][fj] = (f32x4){0.f, 0.f, 0.f, 0.f};
  for (int it = 0; it < VCH_P / 64; ++it) {
    const int v0 = vbase + it * 64;
    f32x4 sacc[4];
#pragma unroll
    for (int nj = 0; nj < 4; ++nj) sacc[nj] = (f32x4){0.f, 0.f, 0.f, 0.f};
    for (int ks = 0; ks < 8; ++ks) {
      const int kb = ks * 64;
#pragma unroll
      for (int cc = 0; cc < 2; ++cc) {
        int gid = (w * 2 + cc) * 64 + lane;
        int row = gid >> 3, dg = (gid & 7) ^ (row & 7);
        gld16(Ebf + (size_t)(v0 + row) * F_DIM + kb + dg * 8, &Es2[(w * 2 + cc) * 512]);
      }
#pragma unroll
      for (int cc = 0; cc < 2; ++cc) {
        int gid = (w * 2 + cc) * 64 + lane;
        int row = gid >> 3, dg = (gid & 7) ^ (row & 7);
        gld16(obf + (size_t)(t0 + row) * F_DIM + kb + dg * 8, &Os2[(w * 2 + cc) * 512]);
      }
      __syncthreads();
#pragma unroll
      for (int kk = 0; kk < 2; ++kk) {
        bf16x8 ae;
        {
          int row = w * 16 + c15;
          int g = (kk * 4 + q) ^ (row & 7);
          ae = *(const bf16x8*)&Es2[(row * 8 + g) * 8];
        }
#pragma unroll
        for (int nj = 0; nj < 4; ++nj) {
          int row = nj * 16 + c15;
          int g = (kk * 4 + q) ^ (row & 7);
          bf16x8 bo = *(const bf16x8*)&Os2[(row * 8 + g) * 8];
          sacc[nj] = __builtin_amdgcn_mfma_f32_16x16x32_bf16(ae, bo, sacc[nj], 0, 0, 0);
        }
      }
      __syncthreads();
    }
    // P = exp(S + ob - m) / z, write to LDS in A-operand layout (bf16)
    float obv[4];
#pragma unroll
    for (int r = 0; r < 4; ++r) obv[r] = ob[v0 + w * 16 + q * 4 + r];
    const int vl = w * 16 + q * 4;
#pragma unroll
    for (int nj = 0; nj < 4; ++nj) {
      const float p0 = __expf(sacc[nj][0] + obv[0] - mreg[nj]) * zrreg[nj];
      const float p1 = __expf(sacc[nj][1] + obv[1] - mreg[nj]) * zrreg[nj];
      const float p2 = __expf(sacc[nj][2] + obv[2] - mreg[nj]) * zrreg[nj];
      const float p3 = __expf(sacc[nj][3] + obv[3] - mreg[nj]) * zrreg[nj];
      const unsigned int lo = (unsigned int)f2bf(p0) | ((unsigned int)f2bf(p1) << 16);
      const unsigned int hi = (unsigned int)f2bf(p2) | ((unsigned int)f2bf(p3) << 16);
      const int trow = nj * 16 + c15;
      const int g = (vl >> 3) ^ (trow & 7);
      const int slot = (trow * 8 + g) * 8 + (vl & 7);
      *(uint2*)&Ps[slot] = make_uint2(lo, hi);
    }
    __syncthreads();
    // phase B: pacc += P @ Et, f split in two 256-halves
#pragma unroll
    for (int fh = 0; fh < 2; ++fh) {
#pragma unroll
      for (int cc = 0; cc < 8; ++cc) {
        int gid = (w * 8 + cc) * 64 + lane;
        int row = gid >> 3, dg = (gid & 7) ^ (row & 7);
        gld16(Etbf + (size_t)(fh * 256 + row) * V_DIM + v0 + dg * 8, &Ets[(w * 8 + cc) * 512]);
      }
      __syncthreads();
#pragma unroll
      for (int kk = 0; kk < 2; ++kk) {
        bf16x8 ap[4];
#pragma unroll
        for (int mi = 0; mi < 4; ++mi) {
          int row = mi * 16 + c15;
          int g = (kk * 4 + q) ^ (row & 7);
          ap[mi] = *(const bf16x8*)&Ps[(row * 8 + g) * 8];
        }
#pragma unroll
        for (int nj = 0; nj < 4; ++nj) {
          int row = w * 64 + nj * 16 + c15;
          int g = (kk * 4 + q) ^ (row & 7);
          bf16x8 be = *(const bf16x8*)&Ets[(row * 8 + g) * 8];
#pragma unroll
          for (int mi = 0; mi < 4; ++mi)
            pacc[mi][fh * 4 + nj] =
                __builtin_amdgcn_mfma_f32_16x16x32_bf16(ap[mi], be, pacc[mi][fh * 4 + nj], 0, 0, 0);
        }
      }
      __syncthreads();
    }
  }
#pragma unroll
  for (int mi = 0; mi < 4; ++mi)
#pragma unroll
    for (int fj = 0; fj < 8; ++fj) {
      const int f = (fj >> 2) * 256 + w * 64 + (fj & 3) * 16 + c15;
#pragma unroll
      for (int r = 0; r < 4; ++r) {
        const int t = t0 + mi * 16 + q * 4 + r;
        atomicAdd(&dO[(size_t)t * F_DIM + f], pacc[mi][fj][r]);
      }
    }
}

// ---------------- fast loss: m + log z - (logit at label) ---------------------
__global__ __launch_bounds__(256) void fast_loss_kernel(
    const float* __restrict__ of, const float* __restrict__ E,
    const float* __restrict__ ob, const int* __restrict__ labels,
    const float* __restrict__ mf, const float* __restrict__ zf,
    float* __restrict__ out)
{
  const int t = blockIdx.x * 4 + (threadIdx.x >> 6);
  const int lane = threadIdx.x & 63;
  const int f0 = lane * 4, f1 = 256 + lane * 4;
  const int lab = labels[t];
  const float* orow = of + (size_t)t * F_DIM;
  const float* er = E + (size_t)lab * F_DIM;
  float4 a0 = *(const float4*)(orow + f0), a1 = *(const float4*)(orow + f1);
  float4 b0 = *(const float4*)(er + f0),   b1 = *(const float4*)(er + f1);
  float s = a0.x*b0.x + a0.y*b0.y + a0.z*b0.z + a0.w*b0.w
          + a1.x*b1.x + a1.y*b1.y + a1.z*b1.z + a1.w*b1.w;
  s = wave_sum(s);
  if (lane == 0) out[t] = mf[t] + logf(zf[t]) - (s + ob[lab]);
}

// ==============================================================================
extern "C" void kernel_launch(void* const* d_in, const int* in_sizes, int n_in,
                              void* d_out, int out_size, void* d_ws, size_t ws_size,
                              hipStream_t stream)
{
  const float* h      = (const float*)d_in[0];
  const float* E      = (const float*)d_in[1];
  const float* ob     = (const float*)d_in[2];
  const int*   labels = (const int*)d_in[3];
  const float* Wh     = (const float*)d_in[4];
  const float* bh     = (const float*)d_in[5];
  const float* hb     = (const float*)d_in[6];
  const float* Wp     = (const float*)d_in[7];
  const float* bp     = (const float*)d_in[8];
  const float* gamma  = (const float*)d_in[9];
  const float* beta   = (const float*)d_in[10];
  const float* stepW  = (const float*)d_in[11];
  const float* stepb  = (const float*)d_in[12];

  float* out_loss = (float*)d_out;                 // [2048]
  float* out_gWh  = out_loss + T_TOK;              // [512,1024]
  float* out_ghb  = out_gWh + F_DIM * H_DIM;       // [512]
  float* out_gWp  = out_ghb + F_DIM;               // [512,512]
  float* out_gbp  = out_gWp + F_DIM * F_DIM;       // [512]

  float* ws = (float*)d_ws;
  const size_t TF = (size_t)T_TOK * F_DIM;
  float* v_   = ws;
  float* p_   = ws + TF;
  float* o_   = ws + 2 * TF;
  float* dO_  = ws + 3 * TF;
  float* dp_  = ws + 4 * TF;
  float* dv_  = ws + 5 * TF;
  float* u_   = ws + 6 * TF;
  float* tm_  = ws + 7 * TF;
  float* of_  = ws + 8 * TF;
  float* sm   = ws + 9 * TF;
  float* mu_    = sm;
  float* rstd_  = sm + 2048;
  float* ms_    = sm + 4096;
  float* zs_    = sm + 6144;
  float* mf_    = sm + 8192;
  float* zf_    = sm + 10240;
  float* sd_    = sm + 12288;
  float* mpart  = sm + 14336;
  float* zpart  = mpart + (size_t)T_TOK * NPART;
  unsigned short* obf  = (unsigned short*)(zpart + (size_t)T_TOK * NPART);
  unsigned short* ofbf = obf + TF;
  unsigned short* Ebf  = ofbf + TF;
  unsigned short* Etbf = Ebf + (size_t)V_DIM * F_DIM;

  // zero atomic accumulators
  zero_kernel<<<(int)((TF + 255) / 256), 256, 0, stream>>>(dO_, (int)TF);
  zero_kernel<<<2, 256, 0, stream>>>(out_ghb, F_DIM);
  zero_kernel<<<2, 256, 0, stream>>>(out_gbp, F_DIM);

  // E -> bf16 (row-major + transposed)
  convertE_kernel<<<dim3(V_DIM / 64, F_DIM / 64), 256, 0, stream>>>(E, Ebf, Etbf);

  // v = relu(h @ Wh^T + bh + hb)
  gemm_nt_kernel<<<dim3(F_DIM / 64, T_TOK / 64), 256, 0, stream>>>(
      h, nullptr, Wh, v_, T_TOK, F_DIM, H_DIM, bh, hb, 1);
  // p = v @ Wp^T + bp
  gemm_nt_kernel<<<dim3(8, 32), 256, 0, stream>>>(
      v_, nullptr, Wp, p_, T_TOK, F_DIM, F_DIM, bp, nullptr, 0);
  // o = LN(p)  (fp32 + bf16)
  ln_fwd_kernel<<<512, 256, 0, stream>>>(
      p_, nullptr, nullptr, nullptr, nullptr, gamma, beta, o_, obf, mu_, rstd_, 0);
  // slow softmax stats (MFMA)
  stats_mfma_kernel<<<dim3(NVC_S, T_TOK / 64), 256, 0, stream>>>(obf, Ebf, ob, mpart, zpart);
  combine_kernel<<<8, 256, 0, stream>>>(mpart, zpart, ms_, zs_);
  // dO = softmax @ E (MFMA, flash-style recompute)
  pe_accum_kernel<<<dim3(NVC_P, T_TOK / 64), 256, 0, stream>>>(
      obf, Ebf, Etbf, ob, ms_, zs_, dO_);
  // dp = LN backward(dO - E[label])
  ln_bwd_kernel<<<512, 256, 0, stream>>>(dO_, E, labels, gamma, p_, mu_, rstd_, dp_);
  // gbp = colsum(dp)
  colsum_kernel<<<dim3(2, 16), 256, 0, stream>>>(dp_, out_gbp);
  // gWp = dp^T @ v
  gemm_tn_kernel<<<dim3(8, 8), 256, 0, stream>>>(dp_, v_, out_gWp, F_DIM, F_DIM, T_TOK);
  // dv = (dp @ Wp) * (v > 0)
  gemm_nn_kernel<<<dim3(8, 32), 256, 0, stream>>>(dp_, Wp, dv_, T_TOK, F_DIM, F_DIM, v_);
  // ghb = colsum(dv)
  colsum_kernel<<<dim3(2, 16), 256, 0, stream>>>(dv_, out_ghb);
  // gWh = dv^T @ h
  gemm_tn_kernel<<<dim3(16, 8), 256, 0, stream>>>(dv_, h, out_gWh, F_DIM, H_DIM, T_TOK);
  // u = v @ gWp
  gemm_nn_kernel<<<dim3(8, 32), 256, 0, stream>>>(v_, out_gWp, u_, T_TOK, F_DIM, F_DIM, nullptr);
  // sdot = v . gbp
  sdot_kernel<<<512, 256, 0, stream>>>(v_, out_gbp, sd_);
  // tmat = (v*u) @ stepW^T
  gemm_nt_kernel<<<dim3(8, 32), 256, 0, stream>>>(
      v_, u_, stepW, tm_, T_TOK, F_DIM, F_DIM, nullptr, nullptr, 0);
  // o_fast = LN(p - v*(tmat + stepb*sdot))  (fp32 + bf16)
  ln_fwd_kernel<<<512, 256, 0, stream>>>(
      p_, v_, tm_, stepb, sd_, gamma, beta, of_, ofbf, nullptr, nullptr, 1);
  // fast softmax stats (MFMA)
  stats_mfma_kernel<<<dim3(NVC_S, T_TOK / 64), 256, 0, stream>>>(ofbf, Ebf, ob, mpart, zpart);
  combine_kernel<<<8, 256, 0, stream>>>(mpart, zpart, mf_, zf_);
  // fast_loss
  fast_loss_kernel<<<512, 256, 0, stream>>>(of_, E, ob, labels, mf_, zf_, out_loss);
}

// Round 3
// 1454.186 us; speedup vs baseline: 4.5074x; 1.0110x over previous
//
#include <hip/hip_runtime.h>
#include <cstddef>
#include <math.h>

#define T_TOK 2048
#define F_DIM 512
#define H_DIM 1024
#define V_DIM 32000
#define NVC_S 50
#define VCH_S 640
#define NVC_P 25
#define VCH_P 1280
#define NPART NVC_S
#define LN_EPS 1e-5f

typedef __attribute__((ext_vector_type(8))) short bf16x8;
typedef __attribute__((ext_vector_type(4))) float f32x4;

__device__ __forceinline__ unsigned short f2bf(float x) {
  unsigned int u = __float_as_uint(x);
  u += 0x7fffu + ((u >> 16) & 1u);
  return (unsigned short)(u >> 16);
}

// async global->LDS, 16B per lane; LDS dest = wave-uniform base + lane*16
__device__ __forceinline__ void gld16(const unsigned short* gsrc, unsigned short* ldst) {
  __builtin_amdgcn_global_load_lds(
      (const __attribute__((address_space(1))) unsigned int*)gsrc,
      (__attribute__((address_space(3))) unsigned int*)ldst, 16, 0, 0);
}

__device__ inline float wave_sum(float x) {
#pragma unroll
  for (int off = 32; off > 0; off >>= 1) x += __shfl_xor(x, off, 64);
  return x;
}

// ---------------- zero ----------------
__global__ void zero_kernel(float* __restrict__ p, int n) {
  int i = blockIdx.x * 256 + threadIdx.x;
  if (i < n) p[i] = 0.f;
}

// ---------------- convert E to bf16 (row-major) + bf16 transposed ------------
__global__ __launch_bounds__(256) void convertE_kernel(
    const float* __restrict__ E, unsigned short* __restrict__ Ebf,
    unsigned short* __restrict__ Etbf)
{
  __shared__ float tile[64][65];
  const int tid = threadIdx.x;
  const int v0 = blockIdx.x * 64, f0 = blockIdx.y * 64;
  const int r = tid >> 4, cq = (tid & 15) * 4;
#pragma unroll
  for (int ps = 0; ps < 4; ++ps) {
    const int row = ps * 16 + r;
    float4 x = *(const float4*)&E[(size_t)(v0 + row) * F_DIM + f0 + cq];
    tile[row][cq + 0] = x.x; tile[row][cq + 1] = x.y;
    tile[row][cq + 2] = x.z; tile[row][cq + 3] = x.w;
    ushort4 u; u.x = f2bf(x.x); u.y = f2bf(x.y); u.z = f2bf(x.z); u.w = f2bf(x.w);
    *(ushort4*)&Ebf[(size_t)(v0 + row) * F_DIM + f0 + cq] = u;
  }
  __syncthreads();
#pragma unroll
  for (int ps = 0; ps < 4; ++ps) {
    const int frow = ps * 16 + r;
    ushort4 u;
    u.x = f2bf(tile[cq + 0][frow]); u.y = f2bf(tile[cq + 1][frow]);
    u.z = f2bf(tile[cq + 2][frow]); u.w = f2bf(tile[cq + 3][frow]);
    *(ushort4*)&Etbf[(size_t)(f0 + frow) * V_DIM + v0 + cq] = u;
  }
}

// ---------------- GEMM NT: C[M,N] = (A ⊙ A2)[M,K] * B[N,K]^T (+bias,relu) ----
__global__ __launch_bounds__(256) void gemm_nt_kernel(
    const float* __restrict__ A, const float* __restrict__ A2,
    const float* __restrict__ B, float* __restrict__ C,
    int M, int N, int K,
    const float* __restrict__ bias1, const float* __restrict__ bias2, int relu)
{
  __shared__ float As[16][68];
  __shared__ float Bs[16][68];
  const int tid = threadIdx.x;
  const int m0 = blockIdx.y * 64, n0 = blockIdx.x * 64;
  const int ty = tid >> 4, tx = tid & 15;
  const int lrow = tid >> 2, lkq = (tid & 3) * 4;
  float acc[4][4] = {};
  for (int k0 = 0; k0 < K; k0 += 16) {
    float4 a4 = *(const float4*)(A + (size_t)(m0 + lrow) * K + k0 + lkq);
    if (A2) {
      float4 u4 = *(const float4*)(A2 + (size_t)(m0 + lrow) * K + k0 + lkq);
      a4.x *= u4.x; a4.y *= u4.y; a4.z *= u4.z; a4.w *= u4.w;
    }
    float4 b4 = *(const float4*)(B + (size_t)(n0 + lrow) * K + k0 + lkq);
    As[lkq+0][lrow] = a4.x; As[lkq+1][lrow] = a4.y; As[lkq+2][lrow] = a4.z; As[lkq+3][lrow] = a4.w;
    Bs[lkq+0][lrow] = b4.x; Bs[lkq+1][lrow] = b4.y; Bs[lkq+2][lrow] = b4.z; Bs[lkq+3][lrow] = b4.w;
    __syncthreads();
#pragma unroll
    for (int k = 0; k < 16; ++k) {
      float4 a = *(const float4*)&As[k][ty*4];
      float4 b = *(const float4*)&Bs[k][tx*4];
      float ar[4] = {a.x,a.y,a.z,a.w}, br[4] = {b.x,b.y,b.z,b.w};
#pragma unroll
      for (int i = 0; i < 4; ++i)
#pragma unroll
        for (int j = 0; j < 4; ++j) acc[i][j] = fmaf(ar[i], br[j], acc[i][j]);
    }
    __syncthreads();
  }
#pragma unroll
  for (int i = 0; i < 4; ++i) {
    const int m = m0 + ty*4 + i;
    float cr[4];
#pragma unroll
    for (int j = 0; j < 4; ++j) {
      const int n = n0 + tx*4 + j;
      float v = acc[i][j];
      if (bias1) v += bias1[n];
      if (bias2) v += bias2[n];
      if (relu) v = fmaxf(v, 0.f);
      cr[j] = v;
    }
    float4 c; c.x = cr[0]; c.y = cr[1]; c.z = cr[2]; c.w = cr[3];
    *(float4*)(C + (size_t)m * N + n0 + tx*4) = c;
  }
}

// ---------------- GEMM NN: C[M,N] = A[M,K] * B[K,N], optional relu-mask ------
__global__ __launch_bounds__(256) void gemm_nn_kernel(
    const float* __restrict__ A, const float* __restrict__ B,
    float* __restrict__ C, int M, int N, int K,
    const float* __restrict__ maskgt)
{
  __shared__ float As[16][68];
  __shared__ float Bs[16][68];
  const int tid = threadIdx.x;
  const int m0 = blockIdx.y * 64, n0 = blockIdx.x * 64;
  const int ty = tid >> 4, tx = tid & 15;
  const int arow = tid >> 2, akq = (tid & 3) * 4;
  const int brow = tid >> 4, bcq = (tid & 15) * 4;
  float acc[4][4] = {};
  for (int k0 = 0; k0 < K; k0 += 16) {
    float4 a4 = *(const float4*)(A + (size_t)(m0 + arow) * K + k0 + akq);
    float4 b4 = *(const float4*)(B + (size_t)(k0 + brow) * N + n0 + bcq);
    As[akq+0][arow] = a4.x; As[akq+1][arow] = a4.y; As[akq+2][arow] = a4.z; As[akq+3][arow] = a4.w;
    *(float4*)&Bs[brow][bcq] = b4;
    __syncthreads();
#pragma unroll
    for (int k = 0; k < 16; ++k) {
      float4 a = *(const float4*)&As[k][ty*4];
      float4 b = *(const float4*)&Bs[k][tx*4];
      float ar[4] = {a.x,a.y,a.z,a.w}, br[4] = {b.x,b.y,b.z,b.w};
#pragma unroll
      for (int i = 0; i < 4; ++i)
#pragma unroll
        for (int j = 0; j < 4; ++j) acc[i][j] = fmaf(ar[i], br[j], acc[i][j]);
    }
    __syncthreads();
  }
#pragma unroll
  for (int i = 0; i < 4; ++i) {
    const int m = m0 + ty*4 + i;
    float cr[4];
    float4 mk;
    if (maskgt) mk = *(const float4*)(maskgt + (size_t)m * N + n0 + tx*4);
#pragma unroll
    for (int j = 0; j < 4; ++j) cr[j] = acc[i][j];
    if (maskgt) {
      if (!(mk.x > 0.f)) cr[0] = 0.f;
      if (!(mk.y > 0.f)) cr[1] = 0.f;
      if (!(mk.z > 0.f)) cr[2] = 0.f;
      if (!(mk.w > 0.f)) cr[3] = 0.f;
    }
    float4 c; c.x = cr[0]; c.y = cr[1]; c.z = cr[2]; c.w = cr[3];
    *(float4*)(C + (size_t)m * N + n0 + tx*4) = c;
  }
}

// ---------------- GEMM TN: C[M,N] = A[K,M]^T * B[K,N] ------------------------
__global__ __launch_bounds__(256) void gemm_tn_kernel(
    const float* __restrict__ A, const float* __restrict__ B,
    float* __restrict__ C, int M, int N, int K)
{
  __shared__ float As[16][68];
  __shared__ float Bs[16][68];
  const int tid = threadIdx.x;
  const int m0 = blockIdx.y * 64, n0 = blockIdx.x * 64;
  const int ty = tid >> 4, tx = tid & 15;
  const int row = tid >> 4, cq = (tid & 15) * 4;
  float acc[4][4] = {};
  for (int k0 = 0; k0 < K; k0 += 16) {
    float4 a4 = *(const float4*)(A + (size_t)(k0 + row) * M + m0 + cq);
    float4 b4 = *(const float4*)(B + (size_t)(k0 + row) * N + n0 + cq);
    *(float4*)&As[row][cq] = a4;
    *(float4*)&Bs[row][cq] = b4;
    __syncthreads();
#pragma unroll
    for (int k = 0; k < 16; ++k) {
      float4 a = *(const float4*)&As[k][ty*4];
      float4 b = *(const float4*)&Bs[k][tx*4];
      float ar[4] = {a.x,a.y,a.z,a.w}, br[4] = {b.x,b.y,b.z,b.w};
#pragma unroll
      for (int i = 0; i < 4; ++i)
#pragma unroll
        for (int j = 0; j < 4; ++j) acc[i][j] = fmaf(ar[i], br[j], acc[i][j]);
    }
    __syncthreads();
  }
#pragma unroll
  for (int i = 0; i < 4; ++i) {
    const int m = m0 + ty*4 + i;
    float4 c; c.x = acc[i][0]; c.y = acc[i][1]; c.z = acc[i][2]; c.w = acc[i][3];
    *(float4*)(C + (size_t)m * N + n0 + tx*4) = c;
  }
}

// ---------------- LayerNorm forward (wave per token), emits fp32 + bf16 -------
__global__ __launch_bounds__(256) void ln_fwd_kernel(
    const float* __restrict__ p, const float* __restrict__ v,
    const float* __restrict__ tmat, const float* __restrict__ stepb,
    const float* __restrict__ sdot, const float* __restrict__ gamma,
    const float* __restrict__ beta, float* __restrict__ o,
    unsigned short* __restrict__ obf,
    float* __restrict__ mu_out, float* __restrict__ rstd_out, int fastmode)
{
  const int t = blockIdx.x * 4 + (threadIdx.x >> 6);
  const int lane = threadIdx.x & 63;
  const int f0 = lane * 4, f1 = 256 + lane * 4;
  const float* pr = p + (size_t)t * F_DIM;
  float4 x0 = *(const float4*)(pr + f0);
  float4 x1 = *(const float4*)(pr + f1);
  if (fastmode) {
    const float* vr = v + (size_t)t * F_DIM;
    const float* tr = tmat + (size_t)t * F_DIM;
    const float sdt = sdot[t];
    float4 v0 = *(const float4*)(vr + f0), v1 = *(const float4*)(vr + f1);
    float4 t0 = *(const float4*)(tr + f0), t1 = *(const float4*)(tr + f1);
    float4 s0 = *(const float4*)(stepb + f0), s1 = *(const float4*)(stepb + f1);
    x0.x -= v0.x * (t0.x + s0.x * sdt);
    x0.y -= v0.y * (t0.y + s0.y * sdt);
    x0.z -= v0.z * (t0.z + s0.z * sdt);
    x0.w -= v0.w * (t0.w + s0.w * sdt);
    x1.x -= v1.x * (t1.x + s1.x * sdt);
    x1.y -= v1.y * (t1.y + s1.y * sdt);
    x1.z -= v1.z * (t1.z + s1.z * sdt);
    x1.w -= v1.w * (t1.w + s1.w * sdt);
  }
  float s  = x0.x + x0.y + x0.z + x0.w + x1.x + x1.y + x1.z + x1.w;
  float ss = x0.x*x0.x + x0.y*x0.y + x0.z*x0.z + x0.w*x0.w
           + x1.x*x1.x + x1.y*x1.y + x1.z*x1.z + x1.w*x1.w;
  s = wave_sum(s); ss = wave_sum(ss);
  const float mu = s * (1.f / F_DIM);
  const float var = ss * (1.f / F_DIM) - mu * mu;
  const float rstd = rsqrtf(var + LN_EPS);
  float4 g0 = *(const float4*)(gamma + f0), g1 = *(const float4*)(gamma + f1);
  float4 b0 = *(const float4*)(beta + f0),  b1 = *(const float4*)(beta + f1);
  float4 y0, y1;
  y0.x = (x0.x - mu) * rstd * g0.x + b0.x;
  y0.y = (x0.y - mu) * rstd * g0.y + b0.y;
  y0.z = (x0.z - mu) * rstd * g0.z + b0.z;
  y0.w = (x0.w - mu) * rstd * g0.w + b0.w;
  y1.x = (x1.x - mu) * rstd * g1.x + b1.x;
  y1.y = (x1.y - mu) * rstd * g1.y + b1.y;
  y1.z = (x1.z - mu) * rstd * g1.z + b1.z;
  y1.w = (x1.w - mu) * rstd * g1.w + b1.w;
  *(float4*)(o + (size_t)t * F_DIM + f0) = y0;
  *(float4*)(o + (size_t)t * F_DIM + f1) = y1;
  ushort4 u0, u1;
  u0.x = f2bf(y0.x); u0.y = f2bf(y0.y); u0.z = f2bf(y0.z); u0.w = f2bf(y0.w);
  u1.x = f2bf(y1.x); u1.y = f2bf(y1.y); u1.z = f2bf(y1.z); u1.w = f2bf(y1.w);
  *(ushort4*)(obf + (size_t)t * F_DIM + f0) = u0;
  *(ushort4*)(obf + (size_t)t * F_DIM + f1) = u1;
  if (!fastmode && lane == 0) { mu_out[t] = mu; rstd_out[t] = rstd; }
}

// ---------------- LayerNorm backward (wave per token) -------------------------
__global__ __launch_bounds__(256) void ln_bwd_kernel(
    const float* __restrict__ dO, const float* __restrict__ E,
    const int* __restrict__ labels, const float* __restrict__ gamma,
    const float* __restrict__ p, const float* __restrict__ mu_,
    const float* __restrict__ rstd_, float* __restrict__ dp)
{
  const int t = blockIdx.x * 4 + (threadIdx.x >> 6);
  const int lane = threadIdx.x & 63;
  const int f0 = lane * 4, f1 = 256 + lane * 4;
  const int lab = labels[t];
  const float mu = mu_[t], rstd = rstd_[t];
  const float* dor = dO + (size_t)t * F_DIM;
  const float* er  = E + (size_t)lab * F_DIM;
  const float* pr  = p + (size_t)t * F_DIM;
  alignas(16) float d[8], e[8], g[8], x[8];
  *(float4*)&d[0] = *(const float4*)(dor + f0); *(float4*)&d[4] = *(const float4*)(dor + f1);
  *(float4*)&e[0] = *(const float4*)(er + f0);  *(float4*)&e[4] = *(const float4*)(er + f1);
  *(float4*)&g[0] = *(const float4*)(gamma + f0); *(float4*)&g[4] = *(const float4*)(gamma + f1);
  *(float4*)&x[0] = *(const float4*)(pr + f0);  *(float4*)&x[4] = *(const float4*)(pr + f1);
  float dh[8], xh[8];
  float s1 = 0.f, s2 = 0.f;
#pragma unroll
  for (int i = 0; i < 8; ++i) {
    dh[i] = (d[i] - e[i]) * g[i];
    xh[i] = (x[i] - mu) * rstd;
    s1 += dh[i];
    s2 += dh[i] * xh[i];
  }
  s1 = wave_sum(s1); s2 = wave_sum(s2);
  const float c1 = s1 * (1.f / F_DIM), c2 = s2 * (1.f / F_DIM);
  alignas(16) float outv[8];
#pragma unroll
  for (int i = 0; i < 8; ++i) outv[i] = rstd * (dh[i] - c1 - xh[i] * c2);
  *(float4*)(dp + (size_t)t * F_DIM + f0) = *(float4*)&outv[0];
  *(float4*)(dp + (size_t)t * F_DIM + f1) = *(float4*)&outv[4];
}

// ---------------- column sum with atomics -------------------------------------
__global__ __launch_bounds__(256) void colsum_kernel(
    const float* __restrict__ X, float* __restrict__ out)
{
  const int f = blockIdx.x * 256 + threadIdx.x;
  const int t0 = blockIdx.y * 128;
  float s = 0.f;
  for (int r = 0; r < 128; ++r) s += X[(size_t)(t0 + r) * F_DIM + f];
  atomicAdd(out + f, s);
}

// ---------------- sdot[t] = dot(v[t,:], gbp) ----------------------------------
__global__ __launch_bounds__(256) void sdot_kernel(
    const float* __restrict__ v, const float* __restrict__ gbp,
    float* __restrict__ sd)
{
  const int t = blockIdx.x * 4 + (threadIdx.x >> 6);
  const int lane = threadIdx.x & 63;
  const int f0 = lane * 4, f1 = 256 + lane * 4;
  const float* vr = v + (size_t)t * F_DIM;
  float4 a0 = *(const float4*)(vr + f0), a1 = *(const float4*)(vr + f1);
  float4 b0 = *(const float4*)(gbp + f0), b1 = *(const float4*)(gbp + f1);
  float s = a0.x*b0.x + a0.y*b0.y + a0.z*b0.z + a0.w*b0.w
          + a1.x*b1.x + a1.y*b1.y + a1.z*b1.z + a1.w*b1.w;
  s = wave_sum(s);
  if (lane == 0) sd[t] = s;
}

// ---------------- MFMA softmax stats (o-frags in registers) -------------------
// grid(NVC_S, T/128), block 256 (4 waves). Wave w owns 32 tokens (2 nj groups).
// Per 64-v iter: stage E tile 64v x 512k (64KB) once, 128 MFMA/wave between
// 2 barriers, online (m,z) epilogue in registers.
__global__ __launch_bounds__(256, 2) void stats_mfma_kernel(
    const unsigned short* __restrict__ obf, const unsigned short* __restrict__ Ebf,
    const float* __restrict__ ob, float* __restrict__ mpart,
    float* __restrict__ zpart)
{
  __shared__ __align__(16) unsigned short Es[64 * 512];  // 64v x 512k, XOR-swizzled granules
  const int tid = threadIdx.x;
  const int w = tid >> 6, lane = tid & 63;
  const int c15 = lane & 15, q = lane >> 4;
  const int t0 = blockIdx.y * 128;
  const int vbase = blockIdx.x * VCH_S;
  // o-fragments (B-operand): 2 token groups x 16 k-steps, direct from global
  bf16x8 of[2][16];
#pragma unroll
  for (int nj = 0; nj < 2; ++nj) {
    const unsigned short* orow = obf + (size_t)(t0 + w * 32 + nj * 16 + c15) * F_DIM;
#pragma unroll
    for (int s = 0; s < 16; ++s) of[nj][s] = *(const bf16x8*)(orow + s * 32 + q * 8);
  }
  float mrun[2] = {-1e30f, -1e30f}, zrun[2] = {0.f, 0.f};
  for (int it = 0; it < VCH_S / 64; ++it) {
    const int v0 = vbase + it * 64;
#pragma unroll
    for (int i = 0; i < 16; ++i) {
      const int slot = (w * 16 + i) * 64 + lane;
      const int row = slot >> 6, col = slot & 63;
      const int colsrc = (col & 56) | ((col & 7) ^ (row & 7));
      gld16(Ebf + (size_t)(v0 + row) * F_DIM + colsrc * 8, &Es[(w * 16 + i) * 512]);
    }
    __syncthreads();
    f32x4 acc[4][2];
#pragma unroll
    for (int mi = 0; mi < 4; ++mi)
#pragma unroll
      for (int nj = 0; nj < 2; ++nj) acc[mi][nj] = (f32x4){0.f, 0.f, 0.f, 0.f};
#pragma unroll
    for (int s = 0; s < 16; ++s) {
      bf16x8 af[4];
#pragma unroll
      for (int mi = 0; mi < 4; ++mi) {
        const int row = mi * 16 + c15;
        const int c = s * 4 + q;
        const int col = (c & 56) | ((c & 7) ^ (row & 7));
        af[mi] = *(const bf16x8*)&Es[row * 512 + col * 8];
      }
#pragma unroll
      for (int mi = 0; mi < 4; ++mi)
#pragma unroll
        for (int nj = 0; nj < 2; ++nj)
          acc[mi][nj] = __builtin_amdgcn_mfma_f32_16x16x32_bf16(af[mi], of[nj][s], acc[mi][nj], 0, 0, 0);
    }
    __syncthreads();
    // epilogue: online m/z per token (token = col = c15 lane; v across mi,q,r)
    float obv[4][4];
#pragma unroll
    for (int mi = 0; mi < 4; ++mi)
#pragma unroll
      for (int r = 0; r < 4; ++r) obv[mi][r] = ob[v0 + mi * 16 + q * 4 + r];
#pragma unroll
    for (int nj = 0; nj < 2; ++nj) {
      float mx = -1e30f;
#pragma unroll
      for (int mi = 0; mi < 4; ++mi)
#pragma unroll
        for (int r = 0; r < 4; ++r) mx = fmaxf(mx, acc[mi][nj][r] + obv[mi][r]);
      mx = fmaxf(mx, __shfl_xor(mx, 16));
      mx = fmaxf(mx, __shfl_xor(mx, 32));
      const float mnew = fmaxf(mrun[nj], mx);
      float sv = 0.f;
#pragma unroll
      for (int mi = 0; mi < 4; ++mi)
#pragma unroll
        for (int r = 0; r < 4; ++r) sv += __expf(acc[mi][nj][r] + obv[mi][r] - mnew);
      sv += __shfl_xor(sv, 16);
      sv += __shfl_xor(sv, 32);
      zrun[nj] = zrun[nj] * __expf(mrun[nj] - mnew) + sv;
      mrun[nj] = mnew;
    }
  }
  if (q == 0) {
#pragma unroll
    for (int nj = 0; nj < 2; ++nj) {
      const int t = t0 + w * 32 + nj * 16 + c15;
      mpart[(size_t)t * NPART + blockIdx.x] = mrun[nj];
      zpart[(size_t)t * NPART + blockIdx.x] = zrun[nj];
    }
  }
}

// ---------------- combine partial stats ---------------------------------------
__global__ void combine_kernel(const float* __restrict__ mpart,
                               const float* __restrict__ zpart,
                               float* __restrict__ m, float* __restrict__ z)
{
  const int t = blockIdx.x * 256 + threadIdx.x;
  if (t >= T_TOK) return;
  float mm = -1e30f;
  for (int c = 0; c < NPART; ++c) mm = fmaxf(mm, mpart[(size_t)t * NPART + c]);
  float zz = 0.f;
  for (int c = 0; c < NPART; ++c)
    zz += zpart[(size_t)t * NPART + c] * __expf(mpart[(size_t)t * NPART + c] - mm);
  m[t] = mm; z[t] = zz;
}

// ---------------- MFMA dO += softmax(o·E^T+ob) @ E ---------------------------
// grid(NVC_P, T/64), block 256 (4 waves). Wave w owns 16 tokens; o-frags in
// registers; dO[16t x 512f] accumulated in 128 VGPRs; P transposed through a
// per-wave LDS region (no block barrier). 8 barriers/iter.
__global__ __launch_bounds__(256, 2) void pe_accum_kernel(
    const unsigned short* __restrict__ obf, const unsigned short* __restrict__ Ebf,
    const unsigned short* __restrict__ Etbf, const float* __restrict__ ob,
    const float* __restrict__ ms, const float* __restrict__ zs,
    float* __restrict__ dO)
{
  __shared__ __align__(16) unsigned short Es[64 * 256];   // K-half: 64v x 256k (32KB)
  __shared__ __align__(16) unsigned short Ets[256 * 64];  // f-half: 256f x 64v (32KB)
  __shared__ __align__(16) unsigned short Ps[4 * 1024];   // per-wave P: 16t x 64v (2KB each)
  const int tid = threadIdx.x;
  const int w = tid >> 6, lane = tid & 63;
  const int c15 = lane & 15, q = lane >> 4;
  const int t0 = blockIdx.y * 64;
  const int vbase = blockIdx.x * VCH_P;
  const int tmy = t0 + w * 16 + c15;
  const float mreg = ms[tmy], zr = 1.f / zs[tmy];
  // o-fragments (B-operand) for the wave's 16 tokens
  bf16x8 of[16];
  {
    const unsigned short* orow = obf + (size_t)tmy * F_DIM;
#pragma unroll
    for (int s = 0; s < 16; ++s) of[s] = *(const bf16x8*)(orow + s * 32 + q * 8);
  }
  f32x4 pacc[32];
#pragma unroll
  for (int i = 0; i < 32; ++i) pacc[i] = (f32x4){0.f, 0.f, 0.f, 0.f};
  for (int it = 0; it < VCH_P / 64; ++it) {
    const int v0 = vbase + it * 64;
    f32x4 sacc[4];
#pragma unroll
    for (int mi = 0; mi < 4; ++mi) sacc[mi] = (f32x4){0.f, 0.f, 0.f, 0.f};
    // ---- phase A: S^T[64v x 16t]/wave over K=512 in two 256-k halves ----
#pragma unroll
    for (int half = 0; half < 2; ++half) {
#pragma unroll
      for (int i = 0; i < 8; ++i) {
        const int slot = (w * 8 + i) * 64 + lane;
        const int row = slot >> 5, col = slot & 31;
        const int colsrc = (col & 24) | ((col & 7) ^ (row & 7));
        gld16(Ebf + (size_t)(v0 + row) * F_DIM + half * 256 + colsrc * 8, &Es[(w * 8 + i) * 512]);
      }
      __syncthreads();
#pragma unroll
      for (int s = 0; s < 8; ++s) {
        bf16x8 af[4];
#pragma unroll
        for (int mi = 0; mi < 4; ++mi) {
          const int row = mi * 16 + c15;
          const int c = s * 4 + q;
          const int col = (c & 24) | ((c & 7) ^ (row & 7));
          af[mi] = *(const bf16x8*)&Es[row * 256 + col * 8];
        }
#pragma unroll
        for (int mi = 0; mi < 4; ++mi)
          sacc[mi] = __builtin_amdgcn_mfma_f32_16x16x32_bf16(af[mi], of[half * 8 + s], sacc[mi], 0, 0, 0);
      }
      __syncthreads();
    }
    // ---- P = exp(S + ob - m)/z -> per-wave LDS (A-operand layout, swizzled) ----
#pragma unroll
    for (int mi = 0; mi < 4; ++mi) {
      const int vb = v0 + mi * 16 + q * 4;
      const float p0 = __expf(sacc[mi][0] + ob[vb + 0] - mreg) * zr;
      const float p1 = __expf(sacc[mi][1] + ob[vb + 1] - mreg) * zr;
      const float p2 = __expf(sacc[mi][2] + ob[vb + 2] - mreg) * zr;
      const float p3 = __expf(sacc[mi][3] + ob[vb + 3] - mreg) * zr;
      const unsigned int lo = (unsigned int)f2bf(p0) | ((unsigned int)f2bf(p1) << 16);
      const unsigned int hi = (unsigned int)f2bf(p2) | ((unsigned int)f2bf(p3) << 16);
      const int g = mi * 2 + (q >> 1);
      const int col = g ^ (c15 & 7);
      *(uint2*)&Ps[w * 1024 + c15 * 64 + col * 8 + (q & 1) * 4] = make_uint2(lo, hi);
    }
    // ---- phase B: dO[16t x 512f]/wave += P @ Et, f in two 256 halves ----
#pragma unroll
    for (int fh = 0; fh < 2; ++fh) {
#pragma unroll
      for (int i = 0; i < 8; ++i) {
        const int gid = (w * 8 + i) * 64 + lane;
        const int row = gid >> 3;
        const int colsrc = (gid & 7) ^ (row & 7);
        gld16(Etbf + (size_t)(fh * 256 + row) * V_DIM + v0 + colsrc * 8, &Ets[(w * 8 + i) * 512]);
      }
      __syncthreads();
#pragma unroll
      for (int kk = 0; kk < 2; ++kk) {
        const bf16x8 ap = *(const bf16x8*)&Ps[w * 1024 + c15 * 64 + (((kk * 4 + q)) ^ (c15 & 7)) * 8];
#pragma unroll
        for (int nj = 0; nj < 16; ++nj) {
          const int row = nj * 16 + c15;
          const int col = (kk * 4 + q) ^ (row & 7);
          const bf16x8 be = *(const bf16x8*)&Ets[row * 64 + col * 8];
          pacc[fh * 16 + nj] =
              __builtin_amdgcn_mfma_f32_16x16x32_bf16(ap, be, pacc[fh * 16 + nj], 0, 0, 0);
        }
      }
      __syncthreads();
    }
  }
#pragma unroll
  for (int fh = 0; fh < 2; ++fh)
#pragma unroll
    for (int nj = 0; nj < 16; ++nj) {
      const int f = fh * 256 + nj * 16 + c15;
#pragma unroll
      for (int r = 0; r < 4; ++r) {
        const int t = t0 + w * 16 + q * 4 + r;
        atomicAdd(&dO[(size_t)t * F_DIM + f], pacc[fh * 16 + nj][r]);
      }
    }
}

// ---------------- fast loss: m + log z - (logit at label) ---------------------
__global__ __launch_bounds__(256) void fast_loss_kernel(
    const float* __restrict__ of, const float* __restrict__ E,
    const float* __restrict__ ob, const int* __restrict__ labels,
    const float* __restrict__ mf, const float* __restrict__ zf,
    float* __restrict__ out)
{
  const int t = blockIdx.x * 4 + (threadIdx.x >> 6);
  const int lane = threadIdx.x & 63;
  const int f0 = lane * 4, f1 = 256 + lane * 4;
  const int lab = labels[t];
  const float* orow = of + (size_t)t * F_DIM;
  const float* er = E + (size_t)lab * F_DIM;
  float4 a0 = *(const float4*)(orow + f0), a1 = *(const float4*)(orow + f1);
  float4 b0 = *(const float4*)(er + f0),   b1 = *(const float4*)(er + f1);
  float s = a0.x*b0.x + a0.y*b0.y + a0.z*b0.z + a0.w*b0.w
          + a1.x*b1.x + a1.y*b1.y + a1.z*b1.z + a1.w*b1.w;
  s = wave_sum(s);
  if (lane == 0) out[t] = mf[t] + logf(zf[t]) - (s + ob[lab]);
}

// ==============================================================================
extern "C" void kernel_launch(void* const* d_in, const int* in_sizes, int n_in,
                              void* d_out, int out_size, void* d_ws, size_t ws_size,
                              hipStream_t stream)
{
  const float* h      = (const float*)d_in[0];
  const float* E      = (const float*)d_in[1];
  const float* ob     = (const float*)d_in[2];
  const int*   labels = (const int*)d_in[3];
  const float* Wh     = (const float*)d_in[4];
  const float* bh     = (const float*)d_in[5];
  const float* hb     = (const float*)d_in[6];
  const float* Wp     = (const float*)d_in[7];
  const float* bp     = (const float*)d_in[8];
  const float* gamma  = (const float*)d_in[9];
  const float* beta   = (const float*)d_in[10];
  const float* stepW  = (const float*)d_in[11];
  const float* stepb  = (const float*)d_in[12];

  float* out_loss = (float*)d_out;                 // [2048]
  float* out_gWh  = out_loss + T_TOK;              // [512,1024]
  float* out_ghb  = out_gWh + F_DIM * H_DIM;       // [512]
  float* out_gWp  = out_ghb + F_DIM;               // [512,512]
  float* out_gbp  = out_gWp + F_DIM * F_DIM;       // [512]

  float* ws = (float*)d_ws;
  const size_t TF = (size_t)T_TOK * F_DIM;
  float* v_   = ws;
  float* p_   = ws + TF;
  float* o_   = ws + 2 * TF;
  float* dO_  = ws + 3 * TF;
  float* dp_  = ws + 4 * TF;
  float* dv_  = ws + 5 * TF;
  float* u_   = ws + 6 * TF;
  float* tm_  = ws + 7 * TF;
  float* of_  = ws + 8 * TF;
  float* sm   = ws + 9 * TF;
  float* mu_    = sm;
  float* rstd_  = sm + 2048;
  float* ms_    = sm + 4096;
  float* zs_    = sm + 6144;
  float* mf_    = sm + 8192;
  float* zf_    = sm + 10240;
  float* sd_    = sm + 12288;
  float* mpart  = sm + 14336;
  float* zpart  = mpart + (size_t)T_TOK * NPART;
  unsigned short* obf  = (unsigned short*)(zpart + (size_t)T_TOK * NPART);
  unsigned short* ofbf = obf + TF;
  unsigned short* Ebf  = ofbf + TF;
  unsigned short* Etbf = Ebf + (size_t)V_DIM * F_DIM;

  // zero atomic accumulators
  zero_kernel<<<(int)((TF + 255) / 256), 256, 0, stream>>>(dO_, (int)TF);
  zero_kernel<<<2, 256, 0, stream>>>(out_ghb, F_DIM);
  zero_kernel<<<2, 256, 0, stream>>>(out_gbp, F_DIM);

  // E -> bf16 (row-major + transposed)
  convertE_kernel<<<dim3(V_DIM / 64, F_DIM / 64), 256, 0, stream>>>(E, Ebf, Etbf);

  // v = relu(h @ Wh^T + bh + hb)
  gemm_nt_kernel<<<dim3(F_DIM / 64, T_TOK / 64), 256, 0, stream>>>(
      h, nullptr, Wh, v_, T_TOK, F_DIM, H_DIM, bh, hb, 1);
  // p = v @ Wp^T + bp
  gemm_nt_kernel<<<dim3(8, 32), 256, 0, stream>>>(
      v_, nullptr, Wp, p_, T_TOK, F_DIM, F_DIM, bp, nullptr, 0);
  // o = LN(p)  (fp32 + bf16)
  ln_fwd_kernel<<<512, 256, 0, stream>>>(
      p_, nullptr, nullptr, nullptr, nullptr, gamma, beta, o_, obf, mu_, rstd_, 0);
  // slow softmax stats (MFMA)
  stats_mfma_kernel<<<dim3(NVC_S, T_TOK / 128), 256, 0, stream>>>(obf, Ebf, ob, mpart, zpart);
  combine_kernel<<<8, 256, 0, stream>>>(mpart, zpart, ms_, zs_);
  // dO = softmax @ E (MFMA, flash-style recompute)
  pe_accum_kernel<<<dim3(NVC_P, T_TOK / 64), 256, 0, stream>>>(
      obf, Ebf, Etbf, ob, ms_, zs_, dO_);
  // dp = LN backward(dO - E[label])
  ln_bwd_kernel<<<512, 256, 0, stream>>>(dO_, E, labels, gamma, p_, mu_, rstd_, dp_);
  // gbp = colsum(dp)
  colsum_kernel<<<dim3(2, 16), 256, 0, stream>>>(dp_, out_gbp);
  // gWp = dp^T @ v
  gemm_tn_kernel<<<dim3(8, 8), 256, 0, stream>>>(dp_, v_, out_gWp, F_DIM, F_DIM, T_TOK);
  // dv = (dp @ Wp) * (v > 0)
  gemm_nn_kernel<<<dim3(8, 32), 256, 0, stream>>>(dp_, Wp, dv_, T_TOK, F_DIM, F_DIM, v_);
  // ghb = colsum(dv)
  colsum_kernel<<<dim3(2, 16), 256, 0, stream>>>(dv_, out_ghb);
  // gWh = dv^T @ h
  gemm_tn_kernel<<<dim3(16, 8), 256, 0, stream>>>(dv_, h, out_gWh, F_DIM, H_DIM, T_TOK);
  // u = v @ gWp
  gemm_nn_kernel<<<dim3(8, 32), 256, 0, stream>>>(v_, out_gWp, u_, T_TOK, F_DIM, F_DIM, nullptr);
  // sdot = v . gbp
  sdot_kernel<<<512, 256, 0, stream>>>(v_, out_gbp, sd_);
  // tmat = (v*u) @ stepW^T
  gemm_nt_kernel<<<dim3(8, 32), 256, 0, stream>>>(
      v_, u_, stepW, tm_, T_TOK, F_DIM, F_DIM, nullptr, nullptr, 0);
  // o_fast = LN(p - v*(tmat + stepb*sdot))  (fp32 + bf16)
  ln_fwd_kernel<<<512, 256, 0, stream>>>(
      p_, v_, tm_, stepb, sd_, gamma, beta, of_, ofbf, nullptr, nullptr, 1);
  // fast softmax stats (MFMA)
  stats_mfma_kernel<<<dim3(NVC_S, T_TOK / 128), 256, 0, stream>>>(ofbf, Ebf, ob, mpart, zpart);
  combine_kernel<<<8, 256, 0, stream>>>(mpart, zpart, mf_, zf_);
  // fast_loss
  fast_loss_kernel<<<512, 256, 0, stream>>>(of_, E, ob, labels, mf_, zf_, out_loss);
}

// Round 4
// 1036.519 us; speedup vs baseline: 6.3236x; 1.4030x over previous
//
#include <hip/hip_runtime.h>
#include <cstddef>
#include <math.h>

#define T_TOK 2048
#define F_DIM 512
#define H_DIM 1024
#define V_DIM 32000
#define NVC   25
#define VCH   1280
#define NPART NVC
#define NKC   10
#define KC    3200
#define LN_EPS 1e-5f

typedef __attribute__((ext_vector_type(8))) short bf16x8;
typedef __attribute__((ext_vector_type(4))) float f32x4;

__device__ __forceinline__ unsigned short f2bf(float x) {
  unsigned int u = __float_as_uint(x);
  u += 0x7fffu + ((u >> 16) & 1u);
  return (unsigned short)(u >> 16);
}

// async global->LDS, 16B per lane; LDS dest = wave-uniform base + lane*16
__device__ __forceinline__ void gld16(const unsigned short* gsrc, unsigned short* ldst) {
  __builtin_amdgcn_global_load_lds(
      (const __attribute__((address_space(1))) unsigned int*)gsrc,
      (__attribute__((address_space(3))) unsigned int*)ldst, 16, 0, 0);
}

__device__ inline float wave_sum(float x) {
#pragma unroll
  for (int off = 32; off > 0; off >>= 1) x += __shfl_xor(x, off, 64);
  return x;
}

// ---------------- zero ----------------
__global__ void zero_kernel(float* __restrict__ p, int n) {
  int i = blockIdx.x * 256 + threadIdx.x;
  if (i < n) p[i] = 0.f;
}

// ---------------- convert E to bf16 (row-major) + bf16 transposed ------------
__global__ __launch_bounds__(256) void convertE_kernel(
    const float* __restrict__ E, unsigned short* __restrict__ Ebf,
    unsigned short* __restrict__ Etbf)
{
  __shared__ float tile[64][65];
  const int tid = threadIdx.x;
  const int v0 = blockIdx.x * 64, f0 = blockIdx.y * 64;
  const int r = tid >> 4, cq = (tid & 15) * 4;
#pragma unroll
  for (int ps = 0; ps < 4; ++ps) {
    const int row = ps * 16 + r;
    float4 x = *(const float4*)&E[(size_t)(v0 + row) * F_DIM + f0 + cq];
    tile[row][cq + 0] = x.x; tile[row][cq + 1] = x.y;
    tile[row][cq + 2] = x.z; tile[row][cq + 3] = x.w;
    ushort4 u; u.x = f2bf(x.x); u.y = f2bf(x.y); u.z = f2bf(x.z); u.w = f2bf(x.w);
    *(ushort4*)&Ebf[(size_t)(v0 + row) * F_DIM + f0 + cq] = u;
  }
  __syncthreads();
#pragma unroll
  for (int ps = 0; ps < 4; ++ps) {
    const int frow = ps * 16 + r;
    ushort4 u;
    u.x = f2bf(tile[cq + 0][frow]); u.y = f2bf(tile[cq + 1][frow]);
    u.z = f2bf(tile[cq + 2][frow]); u.w = f2bf(tile[cq + 3][frow]);
    *(ushort4*)&Etbf[(size_t)(f0 + frow) * V_DIM + v0 + cq] = u;
  }
}

// ---------------- GEMM NT: C[M,N] = (A ⊙ A2)[M,K] * B[N,K]^T (+bias,relu) ----
__global__ __launch_bounds__(256) void gemm_nt_kernel(
    const float* __restrict__ A, const float* __restrict__ A2,
    const float* __restrict__ B, float* __restrict__ C,
    int M, int N, int K,
    const float* __restrict__ bias1, const float* __restrict__ bias2, int relu)
{
  __shared__ float As[16][68];
  __shared__ float Bs[16][68];
  const int tid = threadIdx.x;
  const int m0 = blockIdx.y * 64, n0 = blockIdx.x * 64;
  const int ty = tid >> 4, tx = tid & 15;
  const int lrow = tid >> 2, lkq = (tid & 3) * 4;
  float acc[4][4] = {};
  for (int k0 = 0; k0 < K; k0 += 16) {
    float4 a4 = *(const float4*)(A + (size_t)(m0 + lrow) * K + k0 + lkq);
    if (A2) {
      float4 u4 = *(const float4*)(A2 + (size_t)(m0 + lrow) * K + k0 + lkq);
      a4.x *= u4.x; a4.y *= u4.y; a4.z *= u4.z; a4.w *= u4.w;
    }
    float4 b4 = *(const float4*)(B + (size_t)(n0 + lrow) * K + k0 + lkq);
    As[lkq+0][lrow] = a4.x; As[lkq+1][lrow] = a4.y; As[lkq+2][lrow] = a4.z; As[lkq+3][lrow] = a4.w;
    Bs[lkq+0][lrow] = b4.x; Bs[lkq+1][lrow] = b4.y; Bs[lkq+2][lrow] = b4.z; Bs[lkq+3][lrow] = b4.w;
    __syncthreads();
#pragma unroll
    for (int k = 0; k < 16; ++k) {
      float4 a = *(const float4*)&As[k][ty*4];
      float4 b = *(const float4*)&Bs[k][tx*4];
      float ar[4] = {a.x,a.y,a.z,a.w}, br[4] = {b.x,b.y,b.z,b.w};
#pragma unroll
      for (int i = 0; i < 4; ++i)
#pragma unroll
        for (int j = 0; j < 4; ++j) acc[i][j] = fmaf(ar[i], br[j], acc[i][j]);
    }
    __syncthreads();
  }
#pragma unroll
  for (int i = 0; i < 4; ++i) {
    const int m = m0 + ty*4 + i;
    float cr[4];
#pragma unroll
    for (int j = 0; j < 4; ++j) {
      const int n = n0 + tx*4 + j;
      float v = acc[i][j];
      if (bias1) v += bias1[n];
      if (bias2) v += bias2[n];
      if (relu) v = fmaxf(v, 0.f);
      cr[j] = v;
    }
    float4 c; c.x = cr[0]; c.y = cr[1]; c.z = cr[2]; c.w = cr[3];
    *(float4*)(C + (size_t)m * N + n0 + tx*4) = c;
  }
}

// ---------------- GEMM NN: C[M,N] = A[M,K] * B[K,N], optional relu-mask ------
__global__ __launch_bounds__(256) void gemm_nn_kernel(
    const float* __restrict__ A, const float* __restrict__ B,
    float* __restrict__ C, int M, int N, int K,
    const float* __restrict__ maskgt)
{
  __shared__ float As[16][68];
  __shared__ float Bs[16][68];
  const int tid = threadIdx.x;
  const int m0 = blockIdx.y * 64, n0 = blockIdx.x * 64;
  const int ty = tid >> 4, tx = tid & 15;
  const int arow = tid >> 2, akq = (tid & 3) * 4;
  const int brow = tid >> 4, bcq = (tid & 15) * 4;
  float acc[4][4] = {};
  for (int k0 = 0; k0 < K; k0 += 16) {
    float4 a4 = *(const float4*)(A + (size_t)(m0 + arow) * K + k0 + akq);
    float4 b4 = *(const float4*)(B + (size_t)(k0 + brow) * N + n0 + bcq);
    As[akq+0][arow] = a4.x; As[akq+1][arow] = a4.y; As[akq+2][arow] = a4.z; As[akq+3][arow] = a4.w;
    *(float4*)&Bs[brow][bcq] = b4;
    __syncthreads();
#pragma unroll
    for (int k = 0; k < 16; ++k) {
      float4 a = *(const float4*)&As[k][ty*4];
      float4 b = *(const float4*)&Bs[k][tx*4];
      float ar[4] = {a.x,a.y,a.z,a.w}, br[4] = {b.x,b.y,b.z,b.w};
#pragma unroll
      for (int i = 0; i < 4; ++i)
#pragma unroll
        for (int j = 0; j < 4; ++j) acc[i][j] = fmaf(ar[i], br[j], acc[i][j]);
    }
    __syncthreads();
  }
#pragma unroll
  for (int i = 0; i < 4; ++i) {
    const int m = m0 + ty*4 + i;
    float cr[4];
    float4 mk;
    if (maskgt) mk = *(const float4*)(maskgt + (size_t)m * N + n0 + tx*4);
#pragma unroll
    for (int j = 0; j < 4; ++j) cr[j] = acc[i][j];
    if (maskgt) {
      if (!(mk.x > 0.f)) cr[0] = 0.f;
      if (!(mk.y > 0.f)) cr[1] = 0.f;
      if (!(mk.z > 0.f)) cr[2] = 0.f;
      if (!(mk.w > 0.f)) cr[3] = 0.f;
    }
    float4 c; c.x = cr[0]; c.y = cr[1]; c.z = cr[2]; c.w = cr[3];
    *(float4*)(C + (size_t)m * N + n0 + tx*4) = c;
  }
}

// ---------------- GEMM TN: C[M,N] = A[K,M]^T * B[K,N] ------------------------
__global__ __launch_bounds__(256) void gemm_tn_kernel(
    const float* __restrict__ A, const float* __restrict__ B,
    float* __restrict__ C, int M, int N, int K)
{
  __shared__ float As[16][68];
  __shared__ float Bs[16][68];
  const int tid = threadIdx.x;
  const int m0 = blockIdx.y * 64, n0 = blockIdx.x * 64;
  const int ty = tid >> 4, tx = tid & 15;
  const int row = tid >> 4, cq = (tid & 15) * 4;
  float acc[4][4] = {};
  for (int k0 = 0; k0 < K; k0 += 16) {
    float4 a4 = *(const float4*)(A + (size_t)(k0 + row) * M + m0 + cq);
    float4 b4 = *(const float4*)(B + (size_t)(k0 + row) * N + n0 + cq);
    *(float4*)&As[row][cq] = a4;
    *(float4*)&Bs[row][cq] = b4;
    __syncthreads();
#pragma unroll
    for (int k = 0; k < 16; ++k) {
      float4 a = *(const float4*)&As[k][ty*4];
      float4 b = *(const float4*)&Bs[k][tx*4];
      float ar[4] = {a.x,a.y,a.z,a.w}, br[4] = {b.x,b.y,b.z,b.w};
#pragma unroll
      for (int i = 0; i < 4; ++i)
#pragma unroll
        for (int j = 0; j < 4; ++j) acc[i][j] = fmaf(ar[i], br[j], acc[i][j]);
    }
    __syncthreads();
  }
#pragma unroll
  for (int i = 0; i < 4; ++i) {
    const int m = m0 + ty*4 + i;
    float4 c; c.x = acc[i][0]; c.y = acc[i][1]; c.z = acc[i][2]; c.w = acc[i][3];
    *(float4*)(C + (size_t)m * N + n0 + tx*4) = c;
  }
}

// ---------------- LayerNorm forward (wave per token), emits fp32 + bf16 -------
__global__ __launch_bounds__(256) void ln_fwd_kernel(
    const float* __restrict__ p, const float* __restrict__ v,
    const float* __restrict__ tmat, const float* __restrict__ stepb,
    const float* __restrict__ sdot, const float* __restrict__ gamma,
    const float* __restrict__ beta, float* __restrict__ o,
    unsigned short* __restrict__ obf,
    float* __restrict__ mu_out, float* __restrict__ rstd_out, int fastmode)
{
  const int t = blockIdx.x * 4 + (threadIdx.x >> 6);
  const int lane = threadIdx.x & 63;
  const int f0 = lane * 4, f1 = 256 + lane * 4;
  const float* pr = p + (size_t)t * F_DIM;
  float4 x0 = *(const float4*)(pr + f0);
  float4 x1 = *(const float4*)(pr + f1);
  if (fastmode) {
    const float* vr = v + (size_t)t * F_DIM;
    const float* tr = tmat + (size_t)t * F_DIM;
    const float sdt = sdot[t];
    float4 v0 = *(const float4*)(vr + f0), v1 = *(const float4*)(vr + f1);
    float4 t0 = *(const float4*)(tr + f0), t1 = *(const float4*)(tr + f1);
    float4 s0 = *(const float4*)(stepb + f0), s1 = *(const float4*)(stepb + f1);
    x0.x -= v0.x * (t0.x + s0.x * sdt);
    x0.y -= v0.y * (t0.y + s0.y * sdt);
    x0.z -= v0.z * (t0.z + s0.z * sdt);
    x0.w -= v0.w * (t0.w + s0.w * sdt);
    x1.x -= v1.x * (t1.x + s1.x * sdt);
    x1.y -= v1.y * (t1.y + s1.y * sdt);
    x1.z -= v1.z * (t1.z + s1.z * sdt);
    x1.w -= v1.w * (t1.w + s1.w * sdt);
  }
  float s  = x0.x + x0.y + x0.z + x0.w + x1.x + x1.y + x1.z + x1.w;
  float ss = x0.x*x0.x + x0.y*x0.y + x0.z*x0.z + x0.w*x0.w
           + x1.x*x1.x + x1.y*x1.y + x1.z*x1.z + x1.w*x1.w;
  s = wave_sum(s); ss = wave_sum(ss);
  const float mu = s * (1.f / F_DIM);
  const float var = ss * (1.f / F_DIM) - mu * mu;
  const float rstd = rsqrtf(var + LN_EPS);
  float4 g0 = *(const float4*)(gamma + f0), g1 = *(const float4*)(gamma + f1);
  float4 b0 = *(const float4*)(beta + f0),  b1 = *(const float4*)(beta + f1);
  float4 y0, y1;
  y0.x = (x0.x - mu) * rstd * g0.x + b0.x;
  y0.y = (x0.y - mu) * rstd * g0.y + b0.y;
  y0.z = (x0.z - mu) * rstd * g0.z + b0.z;
  y0.w = (x0.w - mu) * rstd * g0.w + b0.w;
  y1.x = (x1.x - mu) * rstd * g1.x + b1.x;
  y1.y = (x1.y - mu) * rstd * g1.y + b1.y;
  y1.z = (x1.z - mu) * rstd * g1.z + b1.z;
  y1.w = (x1.w - mu) * rstd * g1.w + b1.w;
  *(float4*)(o + (size_t)t * F_DIM + f0) = y0;
  *(float4*)(o + (size_t)t * F_DIM + f1) = y1;
  ushort4 u0, u1;
  u0.x = f2bf(y0.x); u0.y = f2bf(y0.y); u0.z = f2bf(y0.z); u0.w = f2bf(y0.w);
  u1.x = f2bf(y1.x); u1.y = f2bf(y1.y); u1.z = f2bf(y1.z); u1.w = f2bf(y1.w);
  *(ushort4*)(obf + (size_t)t * F_DIM + f0) = u0;
  *(ushort4*)(obf + (size_t)t * F_DIM + f1) = u1;
  if (!fastmode && lane == 0) { mu_out[t] = mu; rstd_out[t] = rstd; }
}

// ---------------- LayerNorm backward (wave per token) -------------------------
__global__ __launch_bounds__(256) void ln_bwd_kernel(
    const float* __restrict__ dO, const float* __restrict__ E,
    const int* __restrict__ labels, const float* __restrict__ gamma,
    const float* __restrict__ p, const float* __restrict__ mu_,
    const float* __restrict__ rstd_, float* __restrict__ dp)
{
  const int t = blockIdx.x * 4 + (threadIdx.x >> 6);
  const int lane = threadIdx.x & 63;
  const int f0 = lane * 4, f1 = 256 + lane * 4;
  const int lab = labels[t];
  const float mu = mu_[t], rstd = rstd_[t];
  const float* dor = dO + (size_t)t * F_DIM;
  const float* er  = E + (size_t)lab * F_DIM;
  const float* pr  = p + (size_t)t * F_DIM;
  alignas(16) float d[8], e[8], g[8], x[8];
  *(float4*)&d[0] = *(const float4*)(dor + f0); *(float4*)&d[4] = *(const float4*)(dor + f1);
  *(float4*)&e[0] = *(const float4*)(er + f0);  *(float4*)&e[4] = *(const float4*)(er + f1);
  *(float4*)&g[0] = *(const float4*)(gamma + f0); *(float4*)&g[4] = *(const float4*)(gamma + f1);
  *(float4*)&x[0] = *(const float4*)(pr + f0);  *(float4*)&x[4] = *(const float4*)(pr + f1);
  float dh[8], xh[8];
  float s1 = 0.f, s2 = 0.f;
#pragma unroll
  for (int i = 0; i < 8; ++i) {
    dh[i] = (d[i] - e[i]) * g[i];
    xh[i] = (x[i] - mu) * rstd;
    s1 += dh[i];
    s2 += dh[i] * xh[i];
  }
  s1 = wave_sum(s1); s2 = wave_sum(s2);
  const float c1 = s1 * (1.f / F_DIM), c2 = s2 * (1.f / F_DIM);
  alignas(16) float outv[8];
#pragma unroll
  for (int i = 0; i < 8; ++i) outv[i] = rstd * (dh[i] - c1 - xh[i] * c2);
  *(float4*)(dp + (size_t)t * F_DIM + f0) = *(float4*)&outv[0];
  *(float4*)(dp + (size_t)t * F_DIM + f1) = *(float4*)&outv[4];
}

// ---------------- column sum with atomics -------------------------------------
__global__ __launch_bounds__(256) void colsum_kernel(
    const float* __restrict__ X, float* __restrict__ out)
{
  const int f = blockIdx.x * 256 + threadIdx.x;
  const int t0 = blockIdx.y * 128;
  float s = 0.f;
  for (int r = 0; r < 128; ++r) s += X[(size_t)(t0 + r) * F_DIM + f];
  atomicAdd(out + f, s);
}

// ---------------- sdot[t] = dot(v[t,:], gbp) ----------------------------------
__global__ __launch_bounds__(256) void sdot_kernel(
    const float* __restrict__ v, const float* __restrict__ gbp,
    float* __restrict__ sd)
{
  const int t = blockIdx.x * 4 + (threadIdx.x >> 6);
  const int lane = threadIdx.x & 63;
  const int f0 = lane * 4, f1 = 256 + lane * 4;
  const float* vr = v + (size_t)t * F_DIM;
  float4 a0 = *(const float4*)(vr + f0), a1 = *(const float4*)(vr + f1);
  float4 b0 = *(const float4*)(gbp + f0), b1 = *(const float4*)(gbp + f1);
  float s = a0.x*b0.x + a0.y*b0.y + a0.z*b0.z + a0.w*b0.w
          + a1.x*b1.x + a1.y*b1.y + a1.z*b1.z + a1.w*b1.w;
  s = wave_sum(s);
  if (lane == 0) sd[t] = s;
}

// ---------------- MFMA softmax stats ------------------------------------------
// grid(T/64, NVC) — token dim FASTEST so co-scheduled blocks share one E
// window per XCD L2. Wave owns 16 tokens (of[16] in regs, 64 VGPR); per 32-v
// iter: stage E 32v x 512k (32KB, XOR-swizzled), 32 MFMA/wave, online m/z.
// 4 blocks/CU for barrier-drain TLP.
__global__ __launch_bounds__(256, 4) void stats_mfma_kernel(
    const unsigned short* __restrict__ obf, const unsigned short* __restrict__ Ebf,
    const float* __restrict__ ob, float* __restrict__ mpart,
    float* __restrict__ zpart)
{
  __shared__ __align__(16) unsigned short Es[32 * 512];
  const int tid = threadIdx.x;
  const int w = tid >> 6, lane = tid & 63;
  const int c15 = lane & 15, q = lane >> 4;
  const int t0 = blockIdx.x * 64;
  const int vbase = blockIdx.y * VCH;
  const int tok = t0 + w * 16 + c15;
  bf16x8 of[16];
  {
    const unsigned short* orow = obf + (size_t)tok * F_DIM;
#pragma unroll
    for (int s = 0; s < 16; ++s) of[s] = *(const bf16x8*)(orow + s * 32 + q * 8);
  }
  float mrun = -1e30f, zrun = 0.f;
  for (int it = 0; it < VCH / 32; ++it) {
    const int v0 = vbase + it * 32;
#pragma unroll
    for (int i = 0; i < 8; ++i) {
      const int gid = (w * 8 + i) * 64 + lane;
      const int row = gid >> 6, col = gid & 63;
      const int colsrc = (col & 56) | ((col & 7) ^ (row & 7));
      gld16(Ebf + (size_t)(v0 + row) * F_DIM + colsrc * 8, &Es[(w * 8 + i) * 64 * 8]);
    }
    __syncthreads();
    f32x4 acc[2];
    acc[0] = (f32x4){0.f, 0.f, 0.f, 0.f};
    acc[1] = (f32x4){0.f, 0.f, 0.f, 0.f};
#pragma unroll
    for (int s = 0; s < 16; ++s) {
      bf16x8 af[2];
#pragma unroll
      for (int mi = 0; mi < 2; ++mi) {
        const int row = mi * 16 + c15;
        const int c = s * 4 + q;
        const int col = (c & 56) | ((c & 7) ^ (row & 7));
        af[mi] = *(const bf16x8*)&Es[(row * 64 + col) * 8];
      }
      acc[0] = __builtin_amdgcn_mfma_f32_16x16x32_bf16(af[0], of[s], acc[0], 0, 0, 0);
      acc[1] = __builtin_amdgcn_mfma_f32_16x16x32_bf16(af[1], of[s], acc[1], 0, 0, 0);
    }
    __syncthreads();
    float obv[2][4];
#pragma unroll
    for (int mi = 0; mi < 2; ++mi)
#pragma unroll
      for (int r = 0; r < 4; ++r) obv[mi][r] = ob[v0 + mi * 16 + q * 4 + r];
    float mx = -1e30f;
#pragma unroll
    for (int mi = 0; mi < 2; ++mi)
#pragma unroll
      for (int r = 0; r < 4; ++r) mx = fmaxf(mx, acc[mi][r] + obv[mi][r]);
    mx = fmaxf(mx, __shfl_xor(mx, 16));
    mx = fmaxf(mx, __shfl_xor(mx, 32));
    const float mnew = fmaxf(mrun, mx);
    float sv = 0.f;
#pragma unroll
    for (int mi = 0; mi < 2; ++mi)
#pragma unroll
      for (int r = 0; r < 4; ++r) sv += __expf(acc[mi][r] + obv[mi][r] - mnew);
    sv += __shfl_xor(sv, 16);
    sv += __shfl_xor(sv, 32);
    zrun = zrun * __expf(mrun - mnew) + sv;
    mrun = mnew;
  }
  if (q == 0) {
    mpart[(size_t)tok * NPART + blockIdx.y] = mrun;
    zpart[(size_t)tok * NPART + blockIdx.y] = zrun;
  }
}

// ---------------- combine partial stats ---------------------------------------
__global__ void combine_kernel(const float* __restrict__ mpart,
                               const float* __restrict__ zpart,
                               float* __restrict__ m, float* __restrict__ z)
{
  const int t = blockIdx.x * 256 + threadIdx.x;
  if (t >= T_TOK) return;
  float mm = -1e30f;
  for (int c = 0; c < NPART; ++c) mm = fmaxf(mm, mpart[(size_t)t * NPART + c]);
  float zz = 0.f;
  for (int c = 0; c < NPART; ++c)
    zz += zpart[(size_t)t * NPART + c] * __expf(mpart[(size_t)t * NPART + c] - mm);
  m[t] = mm; z[t] = zz;
}

// ---------------- P = softmax(o·E^T + ob) materialized as bf16 ----------------
// Same skeleton as stats; epilogue writes P[t][v] (coalesced ushort4).
__global__ __launch_bounds__(256, 4) void p_write_kernel(
    const unsigned short* __restrict__ obf, const unsigned short* __restrict__ Ebf,
    const float* __restrict__ ob, const float* __restrict__ ms,
    const float* __restrict__ zs, unsigned short* __restrict__ P)
{
  __shared__ __align__(16) unsigned short Es[32 * 512];
  const int tid = threadIdx.x;
  const int w = tid >> 6, lane = tid & 63;
  const int c15 = lane & 15, q = lane >> 4;
  const int t0 = blockIdx.x * 64;
  const int vbase = blockIdx.y * VCH;
  const int tok = t0 + w * 16 + c15;
  const float mreg = ms[tok], zr = 1.f / zs[tok];
  bf16x8 of[16];
  {
    const unsigned short* orow = obf + (size_t)tok * F_DIM;
#pragma unroll
    for (int s = 0; s < 16; ++s) of[s] = *(const bf16x8*)(orow + s * 32 + q * 8);
  }
  for (int it = 0; it < VCH / 32; ++it) {
    const int v0 = vbase + it * 32;
#pragma unroll
    for (int i = 0; i < 8; ++i) {
      const int gid = (w * 8 + i) * 64 + lane;
      const int row = gid >> 6, col = gid & 63;
      const int colsrc = (col & 56) | ((col & 7) ^ (row & 7));
      gld16(Ebf + (size_t)(v0 + row) * F_DIM + colsrc * 8, &Es[(w * 8 + i) * 64 * 8]);
    }
    __syncthreads();
    f32x4 acc[2];
    acc[0] = (f32x4){0.f, 0.f, 0.f, 0.f};
    acc[1] = (f32x4){0.f, 0.f, 0.f, 0.f};
#pragma unroll
    for (int s = 0; s < 16; ++s) {
      bf16x8 af[2];
#pragma unroll
      for (int mi = 0; mi < 2; ++mi) {
        const int row = mi * 16 + c15;
        const int c = s * 4 + q;
        const int col = (c & 56) | ((c & 7) ^ (row & 7));
        af[mi] = *(const bf16x8*)&Es[(row * 64 + col) * 8];
      }
      acc[0] = __builtin_amdgcn_mfma_f32_16x16x32_bf16(af[0], of[s], acc[0], 0, 0, 0);
      acc[1] = __builtin_amdgcn_mfma_f32_16x16x32_bf16(af[1], of[s], acc[1], 0, 0, 0);
    }
    __syncthreads();
#pragma unroll
    for (int mi = 0; mi < 2; ++mi) {
      const int vb = v0 + mi * 16 + q * 4;
      ushort4 u;
      u.x = f2bf(__expf(acc[mi][0] + ob[vb + 0] - mreg) * zr);
      u.y = f2bf(__expf(acc[mi][1] + ob[vb + 1] - mreg) * zr);
      u.z = f2bf(__expf(acc[mi][2] + ob[vb + 2] - mreg) * zr);
      u.w = f2bf(__expf(acc[mi][3] + ob[vb + 3] - mreg) * zr);
      *(ushort4*)&P[(size_t)tok * V_DIM + vb] = u;
    }
  }
}

// ---------------- dO = P @ Et^T (NT bf16 GEMM, split-K, fp32 atomics) ---------
// M=2048(t) N=512(f) K=32000(v). 128x128x64 tile, 4 waves of 64x64.
__global__ __launch_bounds__(256, 3) void gemm_pe_kernel(
    const unsigned short* __restrict__ P, const unsigned short* __restrict__ Etbf,
    float* __restrict__ dO)
{
  __shared__ __align__(16) unsigned short As[128 * 64];
  __shared__ __align__(16) unsigned short Bs[128 * 64];
  const int tid = threadIdx.x;
  const int w = tid >> 6, lane = tid & 63;
  const int c15 = lane & 15, q = lane >> 4;
  const int n0 = blockIdx.x * 128, m0 = blockIdx.y * 128;
  const int kbase = blockIdx.z * KC;
  const int mw = (w & 1) * 64, nw = (w >> 1) * 64;
  f32x4 acc[4][4];
#pragma unroll
  for (int mi = 0; mi < 4; ++mi)
#pragma unroll
    for (int nj = 0; nj < 4; ++nj) acc[mi][nj] = (f32x4){0.f, 0.f, 0.f, 0.f};
  for (int it = 0; it < KC / 64; ++it) {
    const int kb = kbase + it * 64;
#pragma unroll
    for (int i = 0; i < 4; ++i) {
      const int gid = (w * 4 + i) * 64 + lane;
      const int row = gid >> 3, col = gid & 7;
      const int colsrc = col ^ (row & 7);
      gld16(P + (size_t)(m0 + row) * V_DIM + kb + colsrc * 8, &As[(w * 4 + i) * 64 * 8]);
    }
#pragma unroll
    for (int i = 0; i < 4; ++i) {
      const int gid = (w * 4 + i) * 64 + lane;
      const int row = gid >> 3, col = gid & 7;
      const int colsrc = col ^ (row & 7);
      gld16(Etbf + (size_t)(n0 + row) * V_DIM + kb + colsrc * 8, &Bs[(w * 4 + i) * 64 * 8]);
    }
    __syncthreads();
#pragma unroll
    for (int kk = 0; kk < 2; ++kk) {
      bf16x8 af[4], bfr[4];
#pragma unroll
      for (int mi = 0; mi < 4; ++mi) {
        const int row = mw + mi * 16 + c15;
        const int g = (kk * 4 + q) ^ (row & 7);
        af[mi] = *(const bf16x8*)&As[(row * 8 + g) * 8];
      }
#pragma unroll
      for (int nj = 0; nj < 4; ++nj) {
        const int row = nw + nj * 16 + c15;
        const int g = (kk * 4 + q) ^ (row & 7);
        bfr[nj] = *(const bf16x8*)&Bs[(row * 8 + g) * 8];
      }
#pragma unroll
      for (int mi = 0; mi < 4; ++mi)
#pragma unroll
        for (int nj = 0; nj < 4; ++nj)
          acc[mi][nj] = __builtin_amdgcn_mfma_f32_16x16x32_bf16(af[mi], bfr[nj], acc[mi][nj], 0, 0, 0);
    }
    __syncthreads();
  }
#pragma unroll
  for (int mi = 0; mi < 4; ++mi)
#pragma unroll
    for (int nj = 0; nj < 4; ++nj) {
      const int f = n0 + nw + nj * 16 + c15;
#pragma unroll
      for (int r = 0; r < 4; ++r) {
        const int t = m0 + mw + mi * 16 + q * 4 + r;
        atomicAdd(&dO[(size_t)t * F_DIM + f], acc[mi][nj][r]);
      }
    }
}

// ---------------- fast loss: m + log z - (logit at label) ---------------------
__global__ __launch_bounds__(256) void fast_loss_kernel(
    const float* __restrict__ of, const float* __restrict__ E,
    const float* __restrict__ ob, const int* __restrict__ labels,
    const float* __restrict__ mf, const float* __restrict__ zf,
    float* __restrict__ out)
{
  const int t = blockIdx.x * 4 + (threadIdx.x >> 6);
  const int lane = threadIdx.x & 63;
  const int f0 = lane * 4, f1 = 256 + lane * 4;
  const int lab = labels[t];
  const float* orow = of + (size_t)t * F_DIM;
  const float* er = E + (size_t)lab * F_DIM;
  float4 a0 = *(const float4*)(orow + f0), a1 = *(const float4*)(orow + f1);
  float4 b0 = *(const float4*)(er + f0),   b1 = *(const float4*)(er + f1);
  float s = a0.x*b0.x + a0.y*b0.y + a0.z*b0.z + a0.w*b0.w
          + a1.x*b1.x + a1.y*b1.y + a1.z*b1.z + a1.w*b1.w;
  s = wave_sum(s);
  if (lane == 0) out[t] = mf[t] + logf(zf[t]) - (s + ob[lab]);
}

// ==============================================================================
extern "C" void kernel_launch(void* const* d_in, const int* in_sizes, int n_in,
                              void* d_out, int out_size, void* d_ws, size_t ws_size,
                              hipStream_t stream)
{
  const float* h      = (const float*)d_in[0];
  const float* E      = (const float*)d_in[1];
  const float* ob     = (const float*)d_in[2];
  const int*   labels = (const int*)d_in[3];
  const float* Wh     = (const float*)d_in[4];
  const float* bh     = (const float*)d_in[5];
  const float* hb     = (const float*)d_in[6];
  const float* Wp     = (const float*)d_in[7];
  const float* bp     = (const float*)d_in[8];
  const float* gamma  = (const float*)d_in[9];
  const float* beta   = (const float*)d_in[10];
  const float* stepW  = (const float*)d_in[11];
  const float* stepb  = (const float*)d_in[12];

  float* out_loss = (float*)d_out;                 // [2048]
  float* out_gWh  = out_loss + T_TOK;              // [512,1024]
  float* out_ghb  = out_gWh + F_DIM * H_DIM;       // [512]
  float* out_gWp  = out_ghb + F_DIM;               // [512,512]
  float* out_gbp  = out_gWp + F_DIM * F_DIM;       // [512]

  float* ws = (float*)d_ws;
  const size_t TF = (size_t)T_TOK * F_DIM;
  float* v_   = ws;
  float* p_   = ws + TF;
  float* o_   = ws + 2 * TF;
  float* dO_  = ws + 3 * TF;
  float* dp_  = ws + 4 * TF;
  float* dv_  = ws + 5 * TF;
  float* u_   = ws + 6 * TF;
  float* tm_  = ws + 7 * TF;
  float* of_  = ws + 8 * TF;
  float* sm   = ws + 9 * TF;
  float* mu_    = sm;
  float* rstd_  = sm + 2048;
  float* ms_    = sm + 4096;
  float* zs_    = sm + 6144;
  float* mf_    = sm + 8192;
  float* zf_    = sm + 10240;
  float* sd_    = sm + 12288;
  float* mpart  = sm + 14336;
  float* zpart  = mpart + (size_t)T_TOK * NPART;
  unsigned short* obf  = (unsigned short*)(zpart + (size_t)T_TOK * NPART);
  unsigned short* ofbf = obf + TF;
  unsigned short* Ebf  = ofbf + TF;
  unsigned short* Etbf = Ebf + (size_t)V_DIM * F_DIM;
  unsigned short* Pbuf = Etbf + (size_t)V_DIM * F_DIM;   // [2048, 32000] bf16

  // zero atomic accumulators
  zero_kernel<<<(int)((TF + 255) / 256), 256, 0, stream>>>(dO_, (int)TF);
  zero_kernel<<<2, 256, 0, stream>>>(out_ghb, F_DIM);
  zero_kernel<<<2, 256, 0, stream>>>(out_gbp, F_DIM);

  // E -> bf16 (row-major + transposed)
  convertE_kernel<<<dim3(V_DIM / 64, F_DIM / 64), 256, 0, stream>>>(E, Ebf, Etbf);

  // v = relu(h @ Wh^T + bh + hb)
  gemm_nt_kernel<<<dim3(F_DIM / 64, T_TOK / 64), 256, 0, stream>>>(
      h, nullptr, Wh, v_, T_TOK, F_DIM, H_DIM, bh, hb, 1);
  // p = v @ Wp^T + bp
  gemm_nt_kernel<<<dim3(8, 32), 256, 0, stream>>>(
      v_, nullptr, Wp, p_, T_TOK, F_DIM, F_DIM, bp, nullptr, 0);
  // o = LN(p)  (fp32 + bf16)
  ln_fwd_kernel<<<512, 256, 0, stream>>>(
      p_, nullptr, nullptr, nullptr, nullptr, gamma, beta, o_, obf, mu_, rstd_, 0);
  // slow softmax stats (MFMA)
  stats_mfma_kernel<<<dim3(T_TOK / 64, NVC), 256, 0, stream>>>(obf, Ebf, ob, mpart, zpart);
  combine_kernel<<<8, 256, 0, stream>>>(mpart, zpart, ms_, zs_);
  // P = softmax(logits) materialized bf16
  p_write_kernel<<<dim3(T_TOK / 64, NVC), 256, 0, stream>>>(obf, Ebf, ob, ms_, zs_, Pbuf);
  // dO = P @ E (bf16 GEMM, split-K atomics)
  gemm_pe_kernel<<<dim3(F_DIM / 128, T_TOK / 128, NKC), 256, 0, stream>>>(Pbuf, Etbf, dO_);
  // dp = LN backward(dO - E[label])
  ln_bwd_kernel<<<512, 256, 0, stream>>>(dO_, E, labels, gamma, p_, mu_, rstd_, dp_);
  // gbp = colsum(dp)
  colsum_kernel<<<dim3(2, 16), 256, 0, stream>>>(dp_, out_gbp);
  // gWp = dp^T @ v
  gemm_tn_kernel<<<dim3(8, 8), 256, 0, stream>>>(dp_, v_, out_gWp, F_DIM, F_DIM, T_TOK);
  // dv = (dp @ Wp) * (v > 0)
  gemm_nn_kernel<<<dim3(8, 32), 256, 0, stream>>>(dp_, Wp, dv_, T_TOK, F_DIM, F_DIM, v_);
  // ghb = colsum(dv)
  colsum_kernel<<<dim3(2, 16), 256, 0, stream>>>(dv_, out_ghb);
  // gWh = dv^T @ h
  gemm_tn_kernel<<<dim3(16, 8), 256, 0, stream>>>(dv_, h, out_gWh, F_DIM, H_DIM, T_TOK);
  // u = v @ gWp
  gemm_nn_kernel<<<dim3(8, 32), 256, 0, stream>>>(v_, out_gWp, u_, T_TOK, F_DIM, F_DIM, nullptr);
  // sdot = v . gbp
  sdot_kernel<<<512, 256, 0, stream>>>(v_, out_gbp, sd_);
  // tmat = (v*u) @ stepW^T
  gemm_nt_kernel<<<dim3(8, 32), 256, 0, stream>>>(
      v_, u_, stepW, tm_, T_TOK, F_DIM, F_DIM, nullptr, nullptr, 0);
  // o_fast = LN(p - v*(tmat + stepb*sdot))  (fp32 + bf16)
  ln_fwd_kernel<<<512, 256, 0, stream>>>(
      p_, v_, tm_, stepb, sd_, gamma, beta, of_, ofbf, nullptr, nullptr, 1);
  // fast softmax stats (MFMA)
  stats_mfma_kernel<<<dim3(T_TOK / 64, NVC), 256, 0, stream>>>(ofbf, Ebf, ob, mpart, zpart);
  combine_kernel<<<8, 256, 0, stream>>>(mpart, zpart, mf_, zf_);
  // fast_loss
  fast_loss_kernel<<<512, 256, 0, stream>>>(of_, E, ob, labels, mf_, zf_, out_loss);
}

// Round 5
// 887.321 us; speedup vs baseline: 7.3869x; 1.1681x over previous
//
#include <hip/hip_runtime.h>
#include <cstddef>
#include <math.h>

#define T_TOK 2048
#define F_DIM 512
#define H_DIM 1024
#define V_DIM 32000
#define NKC   10
#define KC    3200
#define LN_EPS 1e-5f
#define SHIFT 20.0f

typedef __attribute__((ext_vector_type(8))) short bf16x8;
typedef __attribute__((ext_vector_type(4))) float f32x4;

__device__ __forceinline__ unsigned short f2bf(float x) {
  unsigned int u = __float_as_uint(x);
  u += 0x7fffu + ((u >> 16) & 1u);
  return (unsigned short)(u >> 16);
}

// async global->LDS, 16B per lane; LDS dest = wave-uniform base + lane*16
__device__ __forceinline__ void gld16(const unsigned short* gsrc, unsigned short* ldst) {
  __builtin_amdgcn_global_load_lds(
      (const __attribute__((address_space(1))) unsigned int*)gsrc,
      (__attribute__((address_space(3))) unsigned int*)ldst, 16, 0, 0);
}

__device__ inline float wave_sum(float x) {
#pragma unroll
  for (int off = 32; off > 0; off >>= 1) x += __shfl_xor(x, off, 64);
  return x;
}

// ---------------- zero ----------------
__global__ void zero_kernel(float* __restrict__ p, int n) {
  int i = blockIdx.x * 256 + threadIdx.x;
  if (i < n) p[i] = 0.f;
}

// ---------------- convert E to bf16 (row-major) + bf16 transposed ------------
__global__ __launch_bounds__(256) void convertE_kernel(
    const float* __restrict__ E, unsigned short* __restrict__ Ebf,
    unsigned short* __restrict__ Etbf)
{
  __shared__ float tile[64][65];
  const int tid = threadIdx.x;
  const int v0 = blockIdx.x * 64, f0 = blockIdx.y * 64;
  const int r = tid >> 4, cq = (tid & 15) * 4;
#pragma unroll
  for (int ps = 0; ps < 4; ++ps) {
    const int row = ps * 16 + r;
    float4 x = *(const float4*)&E[(size_t)(v0 + row) * F_DIM + f0 + cq];
    tile[row][cq + 0] = x.x; tile[row][cq + 1] = x.y;
    tile[row][cq + 2] = x.z; tile[row][cq + 3] = x.w;
    ushort4 u; u.x = f2bf(x.x); u.y = f2bf(x.y); u.z = f2bf(x.z); u.w = f2bf(x.w);
    *(ushort4*)&Ebf[(size_t)(v0 + row) * F_DIM + f0 + cq] = u;
  }
  __syncthreads();
#pragma unroll
  for (int ps = 0; ps < 4; ++ps) {
    const int frow = ps * 16 + r;
    ushort4 u;
    u.x = f2bf(tile[cq + 0][frow]); u.y = f2bf(tile[cq + 1][frow]);
    u.z = f2bf(tile[cq + 2][frow]); u.w = f2bf(tile[cq + 3][frow]);
    *(ushort4*)&Etbf[(size_t)(f0 + frow) * V_DIM + v0 + cq] = u;
  }
}

// ---------------- GEMM NT: C[M,N] = (A ⊙ A2)[M,K] * B[N,K]^T (+bias,relu) ----
__global__ __launch_bounds__(256) void gemm_nt_kernel(
    const float* __restrict__ A, const float* __restrict__ A2,
    const float* __restrict__ B, float* __restrict__ C,
    int M, int N, int K,
    const float* __restrict__ bias1, const float* __restrict__ bias2, int relu)
{
  __shared__ float As[16][68];
  __shared__ float Bs[16][68];
  const int tid = threadIdx.x;
  const int m0 = blockIdx.y * 64, n0 = blockIdx.x * 64;
  const int ty = tid >> 4, tx = tid & 15;
  const int lrow = tid >> 2, lkq = (tid & 3) * 4;
  float acc[4][4] = {};
  for (int k0 = 0; k0 < K; k0 += 16) {
    float4 a4 = *(const float4*)(A + (size_t)(m0 + lrow) * K + k0 + lkq);
    if (A2) {
      float4 u4 = *(const float4*)(A2 + (size_t)(m0 + lrow) * K + k0 + lkq);
      a4.x *= u4.x; a4.y *= u4.y; a4.z *= u4.z; a4.w *= u4.w;
    }
    float4 b4 = *(const float4*)(B + (size_t)(n0 + lrow) * K + k0 + lkq);
    As[lkq+0][lrow] = a4.x; As[lkq+1][lrow] = a4.y; As[lkq+2][lrow] = a4.z; As[lkq+3][lrow] = a4.w;
    Bs[lkq+0][lrow] = b4.x; Bs[lkq+1][lrow] = b4.y; Bs[lkq+2][lrow] = b4.z; Bs[lkq+3][lrow] = b4.w;
    __syncthreads();
#pragma unroll
    for (int k = 0; k < 16; ++k) {
      float4 a = *(const float4*)&As[k][ty*4];
      float4 b = *(const float4*)&Bs[k][tx*4];
      float ar[4] = {a.x,a.y,a.z,a.w}, br[4] = {b.x,b.y,b.z,b.w};
#pragma unroll
      for (int i = 0; i < 4; ++i)
#pragma unroll
        for (int j = 0; j < 4; ++j) acc[i][j] = fmaf(ar[i], br[j], acc[i][j]);
    }
    __syncthreads();
  }
#pragma unroll
  for (int i = 0; i < 4; ++i) {
    const int m = m0 + ty*4 + i;
    float cr[4];
#pragma unroll
    for (int j = 0; j < 4; ++j) {
      const int n = n0 + tx*4 + j;
      float v = acc[i][j];
      if (bias1) v += bias1[n];
      if (bias2) v += bias2[n];
      if (relu) v = fmaxf(v, 0.f);
      cr[j] = v;
    }
    float4 c; c.x = cr[0]; c.y = cr[1]; c.z = cr[2]; c.w = cr[3];
    *(float4*)(C + (size_t)m * N + n0 + tx*4) = c;
  }
}

// ---------------- GEMM NN: C[M,N] = A[M,K] * B[K,N], optional relu-mask ------
__global__ __launch_bounds__(256) void gemm_nn_kernel(
    const float* __restrict__ A, const float* __restrict__ B,
    float* __restrict__ C, int M, int N, int K,
    const float* __restrict__ maskgt)
{
  __shared__ float As[16][68];
  __shared__ float Bs[16][68];
  const int tid = threadIdx.x;
  const int m0 = blockIdx.y * 64, n0 = blockIdx.x * 64;
  const int ty = tid >> 4, tx = tid & 15;
  const int arow = tid >> 2, akq = (tid & 3) * 4;
  const int brow = tid >> 4, bcq = (tid & 15) * 4;
  float acc[4][4] = {};
  for (int k0 = 0; k0 < K; k0 += 16) {
    float4 a4 = *(const float4*)(A + (size_t)(m0 + arow) * K + k0 + akq);
    float4 b4 = *(const float4*)(B + (size_t)(k0 + brow) * N + n0 + bcq);
    As[akq+0][arow] = a4.x; As[akq+1][arow] = a4.y; As[akq+2][arow] = a4.z; As[akq+3][arow] = a4.w;
    *(float4*)&Bs[brow][bcq] = b4;
    __syncthreads();
#pragma unroll
    for (int k = 0; k < 16; ++k) {
      float4 a = *(const float4*)&As[k][ty*4];
      float4 b = *(const float4*)&Bs[k][tx*4];
      float ar[4] = {a.x,a.y,a.z,a.w}, br[4] = {b.x,b.y,b.z,b.w};
#pragma unroll
      for (int i = 0; i < 4; ++i)
#pragma unroll
        for (int j = 0; j < 4; ++j) acc[i][j] = fmaf(ar[i], br[j], acc[i][j]);
    }
    __syncthreads();
  }
#pragma unroll
  for (int i = 0; i < 4; ++i) {
    const int m = m0 + ty*4 + i;
    float cr[4];
    float4 mk;
    if (maskgt) mk = *(const float4*)(maskgt + (size_t)m * N + n0 + tx*4);
#pragma unroll
    for (int j = 0; j < 4; ++j) cr[j] = acc[i][j];
    if (maskgt) {
      if (!(mk.x > 0.f)) cr[0] = 0.f;
      if (!(mk.y > 0.f)) cr[1] = 0.f;
      if (!(mk.z > 0.f)) cr[2] = 0.f;
      if (!(mk.w > 0.f)) cr[3] = 0.f;
    }
    float4 c; c.x = cr[0]; c.y = cr[1]; c.z = cr[2]; c.w = cr[3];
    *(float4*)(C + (size_t)m * N + n0 + tx*4) = c;
  }
}

// ---------------- GEMM TN: C[M,N] = A[K,M]^T * B[K,N] ------------------------
__global__ __launch_bounds__(256) void gemm_tn_kernel(
    const float* __restrict__ A, const float* __restrict__ B,
    float* __restrict__ C, int M, int N, int K)
{
  __shared__ float As[16][68];
  __shared__ float Bs[16][68];
  const int tid = threadIdx.x;
  const int m0 = blockIdx.y * 64, n0 = blockIdx.x * 64;
  const int ty = tid >> 4, tx = tid & 15;
  const int row = tid >> 4, cq = (tid & 15) * 4;
  float acc[4][4] = {};
  for (int k0 = 0; k0 < K; k0 += 16) {
    float4 a4 = *(const float4*)(A + (size_t)(k0 + row) * M + m0 + cq);
    float4 b4 = *(const float4*)(B + (size_t)(k0 + row) * N + n0 + cq);
    *(float4*)&As[row][cq] = a4;
    *(float4*)&Bs[row][cq] = b4;
    __syncthreads();
#pragma unroll
    for (int k = 0; k < 16; ++k) {
      float4 a = *(const float4*)&As[k][ty*4];
      float4 b = *(const float4*)&Bs[k][tx*4];
      float ar[4] = {a.x,a.y,a.z,a.w}, br[4] = {b.x,b.y,b.z,b.w};
#pragma unroll
      for (int i = 0; i < 4; ++i)
#pragma unroll
        for (int j = 0; j < 4; ++j) acc[i][j] = fmaf(ar[i], br[j], acc[i][j]);
    }
    __syncthreads();
  }
#pragma unroll
  for (int i = 0; i < 4; ++i) {
    const int m = m0 + ty*4 + i;
    float4 c; c.x = acc[i][0]; c.y = acc[i][1]; c.z = acc[i][2]; c.w = acc[i][3];
    *(float4*)(C + (size_t)m * N + n0 + tx*4) = c;
  }
}

// ---------------- LayerNorm forward (wave per token), emits fp32 + bf16 -------
__global__ __launch_bounds__(256) void ln_fwd_kernel(
    const float* __restrict__ p, const float* __restrict__ v,
    const float* __restrict__ tmat, const float* __restrict__ stepb,
    const float* __restrict__ sdot, const float* __restrict__ gamma,
    const float* __restrict__ beta, float* __restrict__ o,
    unsigned short* __restrict__ obf,
    float* __restrict__ mu_out, float* __restrict__ rstd_out, int fastmode)
{
  const int t = blockIdx.x * 4 + (threadIdx.x >> 6);
  const int lane = threadIdx.x & 63;
  const int f0 = lane * 4, f1 = 256 + lane * 4;
  const float* pr = p + (size_t)t * F_DIM;
  float4 x0 = *(const float4*)(pr + f0);
  float4 x1 = *(const float4*)(pr + f1);
  if (fastmode) {
    const float* vr = v + (size_t)t * F_DIM;
    const float* tr = tmat + (size_t)t * F_DIM;
    const float sdt = sdot[t];
    float4 v0 = *(const float4*)(vr + f0), v1 = *(const float4*)(vr + f1);
    float4 t0 = *(const float4*)(tr + f0), t1 = *(const float4*)(tr + f1);
    float4 s0 = *(const float4*)(stepb + f0), s1 = *(const float4*)(stepb + f1);
    x0.x -= v0.x * (t0.x + s0.x * sdt);
    x0.y -= v0.y * (t0.y + s0.y * sdt);
    x0.z -= v0.z * (t0.z + s0.z * sdt);
    x0.w -= v0.w * (t0.w + s0.w * sdt);
    x1.x -= v1.x * (t1.x + s1.x * sdt);
    x1.y -= v1.y * (t1.y + s1.y * sdt);
    x1.z -= v1.z * (t1.z + s1.z * sdt);
    x1.w -= v1.w * (t1.w + s1.w * sdt);
  }
  float s  = x0.x + x0.y + x0.z + x0.w + x1.x + x1.y + x1.z + x1.w;
  float ss = x0.x*x0.x + x0.y*x0.y + x0.z*x0.z + x0.w*x0.w
           + x1.x*x1.x + x1.y*x1.y + x1.z*x1.z + x1.w*x1.w;
  s = wave_sum(s); ss = wave_sum(ss);
  const float mu = s * (1.f / F_DIM);
  const float var = ss * (1.f / F_DIM) - mu * mu;
  const float rstd = rsqrtf(var + LN_EPS);
  float4 g0 = *(const float4*)(gamma + f0), g1 = *(const float4*)(gamma + f1);
  float4 b0 = *(const float4*)(beta + f0),  b1 = *(const float4*)(beta + f1);
  float4 y0, y1;
  y0.x = (x0.x - mu) * rstd * g0.x + b0.x;
  y0.y = (x0.y - mu) * rstd * g0.y + b0.y;
  y0.z = (x0.z - mu) * rstd * g0.z + b0.z;
  y0.w = (x0.w - mu) * rstd * g0.w + b0.w;
  y1.x = (x1.x - mu) * rstd * g1.x + b1.x;
  y1.y = (x1.y - mu) * rstd * g1.y + b1.y;
  y1.z = (x1.z - mu) * rstd * g1.z + b1.z;
  y1.w = (x1.w - mu) * rstd * g1.w + b1.w;
  *(float4*)(o + (size_t)t * F_DIM + f0) = y0;
  *(float4*)(o + (size_t)t * F_DIM + f1) = y1;
  ushort4 u0, u1;
  u0.x = f2bf(y0.x); u0.y = f2bf(y0.y); u0.z = f2bf(y0.z); u0.w = f2bf(y0.w);
  u1.x = f2bf(y1.x); u1.y = f2bf(y1.y); u1.z = f2bf(y1.z); u1.w = f2bf(y1.w);
  *(ushort4*)(obf + (size_t)t * F_DIM + f0) = u0;
  *(ushort4*)(obf + (size_t)t * F_DIM + f1) = u1;
  if (!fastmode && lane == 0) { mu_out[t] = mu; rstd_out[t] = rstd; }
}

// ---------------- LayerNorm backward (wave per token) -------------------------
// dO = U/z - E[label]; dp = rstd*(dh - mean(dh) - xhat*mean(dh*xhat))
__global__ __launch_bounds__(256) void ln_bwd_kernel(
    const float* __restrict__ U, const float* __restrict__ z_,
    const float* __restrict__ E,
    const int* __restrict__ labels, const float* __restrict__ gamma,
    const float* __restrict__ p, const float* __restrict__ mu_,
    const float* __restrict__ rstd_, float* __restrict__ dp)
{
  const int t = blockIdx.x * 4 + (threadIdx.x >> 6);
  const int lane = threadIdx.x & 63;
  const int f0 = lane * 4, f1 = 256 + lane * 4;
  const int lab = labels[t];
  const float mu = mu_[t], rstd = rstd_[t];
  const float zr = 1.f / z_[t];
  const float* dor = U + (size_t)t * F_DIM;
  const float* er  = E + (size_t)lab * F_DIM;
  const float* pr  = p + (size_t)t * F_DIM;
  alignas(16) float d[8], e[8], g[8], x[8];
  *(float4*)&d[0] = *(const float4*)(dor + f0); *(float4*)&d[4] = *(const float4*)(dor + f1);
  *(float4*)&e[0] = *(const float4*)(er + f0);  *(float4*)&e[4] = *(const float4*)(er + f1);
  *(float4*)&g[0] = *(const float4*)(gamma + f0); *(float4*)&g[4] = *(const float4*)(gamma + f1);
  *(float4*)&x[0] = *(const float4*)(pr + f0);  *(float4*)&x[4] = *(const float4*)(pr + f1);
  float dh[8], xh[8];
  float s1 = 0.f, s2 = 0.f;
#pragma unroll
  for (int i = 0; i < 8; ++i) {
    dh[i] = (d[i] * zr - e[i]) * g[i];
    xh[i] = (x[i] - mu) * rstd;
    s1 += dh[i];
    s2 += dh[i] * xh[i];
  }
  s1 = wave_sum(s1); s2 = wave_sum(s2);
  const float c1 = s1 * (1.f / F_DIM), c2 = s2 * (1.f / F_DIM);
  alignas(16) float outv[8];
#pragma unroll
  for (int i = 0; i < 8; ++i) outv[i] = rstd * (dh[i] - c1 - xh[i] * c2);
  *(float4*)(dp + (size_t)t * F_DIM + f0) = *(float4*)&outv[0];
  *(float4*)(dp + (size_t)t * F_DIM + f1) = *(float4*)&outv[4];
}

// ---------------- column sum with atomics -------------------------------------
__global__ __launch_bounds__(256) void colsum_kernel(
    const float* __restrict__ X, float* __restrict__ out)
{
  const int f = blockIdx.x * 256 + threadIdx.x;
  const int t0 = blockIdx.y * 128;
  float s = 0.f;
  for (int r = 0; r < 128; ++r) s += X[(size_t)(t0 + r) * F_DIM + f];
  atomicAdd(out + f, s);
}

// ---------------- sdot[t] = dot(v[t,:], gbp) ----------------------------------
__global__ __launch_bounds__(256) void sdot_kernel(
    const float* __restrict__ v, const float* __restrict__ gbp,
    float* __restrict__ sd)
{
  const int t = blockIdx.x * 4 + (threadIdx.x >> 6);
  const int lane = threadIdx.x & 63;
  const int f0 = lane * 4, f1 = 256 + lane * 4;
  const float* vr = v + (size_t)t * F_DIM;
  float4 a0 = *(const float4*)(vr + f0), a1 = *(const float4*)(vr + f1);
  float4 b0 = *(const float4*)(gbp + f0), b1 = *(const float4*)(gbp + f1);
  float s = a0.x*b0.x + a0.y*b0.y + a0.z*b0.z + a0.w*b0.w
          + a1.x*b1.x + a1.y*b1.y + a1.z*b1.z + a1.w*b1.w;
  s = wave_sum(s);
  if (lane == 0) sd[t] = s;
}

// ---------------- expS = exp(o·E^T + ob - SHIFT); z[t] += rowsum --------------
// m97-style 128x128x(BK=64) NT GEMM. 4 waves: wave w covers v-half (w&1)*64,
// t-half (w>>1)*64; 4x4 fragment grid (16 ds_read_b128 : 32 MFMA per slab).
// LayerNorm bounds |logit| <= ~30, so fixed SHIFT replaces per-row max.
// expS==null: z-only pass (fast path).
__global__ __launch_bounds__(256, 3) void expsum_kernel(
    const unsigned short* __restrict__ obf, const unsigned short* __restrict__ Ebf,
    const float* __restrict__ ob, unsigned short* __restrict__ expS,
    float* __restrict__ z)
{
  __shared__ __align__(16) unsigned short Es[128 * 64];  // E slab (vocab rows)
  __shared__ __align__(16) unsigned short Os[128 * 64];  // o slab (token rows)
  const int tid = threadIdx.x;
  const int w = tid >> 6, lane = tid & 63;
  const int c15 = lane & 15, q = lane >> 4;
  const int t0 = blockIdx.x * 128, v0 = blockIdx.y * 128;
  const int vw = v0 + (w & 1) * 64, tw = t0 + (w >> 1) * 64;
  f32x4 acc[4][4];
#pragma unroll
  for (int mi = 0; mi < 4; ++mi)
#pragma unroll
    for (int nj = 0; nj < 4; ++nj) acc[mi][nj] = (f32x4){0.f, 0.f, 0.f, 0.f};
  for (int it = 0; it < F_DIM / 64; ++it) {
    const int kb = it * 64;
#pragma unroll
    for (int i = 0; i < 4; ++i) {
      const int gid = (w * 4 + i) * 64 + lane;
      const int row = gid >> 3, col3 = gid & 7;
      const int colsrc = col3 ^ (row & 7);
      gld16(Ebf + (size_t)(v0 + row) * F_DIM + kb + colsrc * 8, &Es[(w * 4 + i) * 512]);
      gld16(obf + (size_t)(t0 + row) * F_DIM + kb + colsrc * 8, &Os[(w * 4 + i) * 512]);
    }
    __syncthreads();
#pragma unroll
    for (int kk = 0; kk < 2; ++kk) {
      const int g = (kk * 4 + q) ^ (c15 & 7);
      bf16x8 af[4], bfr[4];
#pragma unroll
      for (int mi = 0; mi < 4; ++mi) {
        const int row = (w & 1) * 64 + mi * 16 + c15;
        af[mi] = *(const bf16x8*)&Es[(row * 8 + g) * 8];
      }
#pragma unroll
      for (int nj = 0; nj < 4; ++nj) {
        const int row = (w >> 1) * 64 + nj * 16 + c15;
        bfr[nj] = *(const bf16x8*)&Os[(row * 8 + g) * 8];
      }
#pragma unroll
      for (int mi = 0; mi < 4; ++mi)
#pragma unroll
        for (int nj = 0; nj < 4; ++nj)
          acc[mi][nj] = __builtin_amdgcn_mfma_f32_16x16x32_bf16(af[mi], bfr[nj], acc[mi][nj], 0, 0, 0);
    }
    __syncthreads();
  }
  // epilogue: e = exp(S + ob - SHIFT); optional bf16 store; z rowsum atomics
  float obv[4][4];
#pragma unroll
  for (int mi = 0; mi < 4; ++mi)
    *(float4*)obv[mi] = *(const float4*)&ob[vw + mi * 16 + q * 4];
#pragma unroll
  for (int nj = 0; nj < 4; ++nj) {
    const int t = tw + nj * 16 + c15;
    float zsum = 0.f;
#pragma unroll
    for (int mi = 0; mi < 4; ++mi) {
      float e0 = __expf(acc[mi][nj][0] + obv[mi][0] - SHIFT);
      float e1 = __expf(acc[mi][nj][1] + obv[mi][1] - SHIFT);
      float e2 = __expf(acc[mi][nj][2] + obv[mi][2] - SHIFT);
      float e3 = __expf(acc[mi][nj][3] + obv[mi][3] - SHIFT);
      zsum += e0 + e1 + e2 + e3;
      if (expS) {
        ushort4 u; u.x = f2bf(e0); u.y = f2bf(e1); u.z = f2bf(e2); u.w = f2bf(e3);
        *(ushort4*)&expS[(size_t)t * V_DIM + vw + mi * 16 + q * 4] = u;
      }
    }
    zsum += __shfl_xor(zsum, 16);
    zsum += __shfl_xor(zsum, 32);
    if (q == 0) atomicAdd(&z[t], zsum);
  }
}

// ---------------- U = expS @ Et^T (NT bf16 GEMM, split-K, fp32 atomics) -------
// M=2048(t) N=512(f) K=32000(v). 128x128x64 tile, 4 waves of 64x64.
__global__ __launch_bounds__(256, 3) void gemm_pe_kernel(
    const unsigned short* __restrict__ P, const unsigned short* __restrict__ Etbf,
    float* __restrict__ dO)
{
  __shared__ __align__(16) unsigned short As[128 * 64];
  __shared__ __align__(16) unsigned short Bs[128 * 64];
  const int tid = threadIdx.x;
  const int w = tid >> 6, lane = tid & 63;
  const int c15 = lane & 15, q = lane >> 4;
  const int n0 = blockIdx.x * 128, m0 = blockIdx.y * 128;
  const int kbase = blockIdx.z * KC;
  const int mw = (w & 1) * 64, nw = (w >> 1) * 64;
  f32x4 acc[4][4];
#pragma unroll
  for (int mi = 0; mi < 4; ++mi)
#pragma unroll
    for (int nj = 0; nj < 4; ++nj) acc[mi][nj] = (f32x4){0.f, 0.f, 0.f, 0.f};
  for (int it = 0; it < KC / 64; ++it) {
    const int kb = kbase + it * 64;
#pragma unroll
    for (int i = 0; i < 4; ++i) {
      const int gid = (w * 4 + i) * 64 + lane;
      const int row = gid >> 3, col = gid & 7;
      const int colsrc = col ^ (row & 7);
      gld16(P + (size_t)(m0 + row) * V_DIM + kb + colsrc * 8, &As[(w * 4 + i) * 512]);
      gld16(Etbf + (size_t)(n0 + row) * V_DIM + kb + colsrc * 8, &Bs[(w * 4 + i) * 512]);
    }
    __syncthreads();
#pragma unroll
    for (int kk = 0; kk < 2; ++kk) {
      const int g = (kk * 4 + q) ^ (c15 & 7);
      bf16x8 af[4], bfr[4];
#pragma unroll
      for (int mi = 0; mi < 4; ++mi) {
        const int row = mw + mi * 16 + c15;
        af[mi] = *(const bf16x8*)&As[(row * 8 + g) * 8];
      }
#pragma unroll
      for (int nj = 0; nj < 4; ++nj) {
        const int row = nw + nj * 16 + c15;
        bfr[nj] = *(const bf16x8*)&Bs[(row * 8 + g) * 8];
      }
#pragma unroll
      for (int mi = 0; mi < 4; ++mi)
#pragma unroll
        for (int nj = 0; nj < 4; ++nj)
          acc[mi][nj] = __builtin_amdgcn_mfma_f32_16x16x32_bf16(af[mi], bfr[nj], acc[mi][nj], 0, 0, 0);
    }
    __syncthreads();
  }
#pragma unroll
  for (int mi = 0; mi < 4; ++mi)
#pragma unroll
    for (int nj = 0; nj < 4; ++nj) {
      const int f = n0 + nw + nj * 16 + c15;
#pragma unroll
      for (int r = 0; r < 4; ++r) {
        const int t = m0 + mw + mi * 16 + q * 4 + r;
        atomicAdd(&dO[(size_t)t * F_DIM + f], acc[mi][nj][r]);
      }
    }
}

// ---------------- fast loss: SHIFT + log z - (logit at label) -----------------
__global__ __launch_bounds__(256) void fast_loss_kernel(
    const float* __restrict__ of, const float* __restrict__ E,
    const float* __restrict__ ob, const int* __restrict__ labels,
    const float* __restrict__ zf,
    float* __restrict__ out)
{
  const int t = blockIdx.x * 4 + (threadIdx.x >> 6);
  const int lane = threadIdx.x & 63;
  const int f0 = lane * 4, f1 = 256 + lane * 4;
  const int lab = labels[t];
  const float* orow = of + (size_t)t * F_DIM;
  const float* er = E + (size_t)lab * F_DIM;
  float4 a0 = *(const float4*)(orow + f0), a1 = *(const float4*)(orow + f1);
  float4 b0 = *(const float4*)(er + f0),   b1 = *(const float4*)(er + f1);
  float s = a0.x*b0.x + a0.y*b0.y + a0.z*b0.z + a0.w*b0.w
          + a1.x*b1.x + a1.y*b1.y + a1.z*b1.z + a1.w*b1.w;
  s = wave_sum(s);
  if (lane == 0) out[t] = SHIFT + logf(zf[t]) - (s + ob[lab]);
}

// ==============================================================================
extern "C" void kernel_launch(void* const* d_in, const int* in_sizes, int n_in,
                              void* d_out, int out_size, void* d_ws, size_t ws_size,
                              hipStream_t stream)
{
  const float* h      = (const float*)d_in[0];
  const float* E      = (const float*)d_in[1];
  const float* ob     = (const float*)d_in[2];
  const int*   labels = (const int*)d_in[3];
  const float* Wh     = (const float*)d_in[4];
  const float* bh     = (const float*)d_in[5];
  const float* hb     = (const float*)d_in[6];
  const float* Wp     = (const float*)d_in[7];
  const float* bp     = (const float*)d_in[8];
  const float* gamma  = (const float*)d_in[9];
  const float* beta   = (const float*)d_in[10];
  const float* stepW  = (const float*)d_in[11];
  const float* stepb  = (const float*)d_in[12];

  float* out_loss = (float*)d_out;                 // [2048]
  float* out_gWh  = out_loss + T_TOK;              // [512,1024]
  float* out_ghb  = out_gWh + F_DIM * H_DIM;       // [512]
  float* out_gWp  = out_ghb + F_DIM;               // [512,512]
  float* out_gbp  = out_gWp + F_DIM * F_DIM;       // [512]

  float* ws = (float*)d_ws;
  const size_t TF = (size_t)T_TOK * F_DIM;
  float* v_   = ws;
  float* p_   = ws + TF;
  float* o_   = ws + 2 * TF;
  float* dO_  = ws + 3 * TF;   // U = expS @ E (pre 1/z scale)
  float* dp_  = ws + 4 * TF;
  float* dv_  = ws + 5 * TF;
  float* u_   = ws + 6 * TF;
  float* tm_  = ws + 7 * TF;
  float* of_  = ws + 8 * TF;
  float* sm   = ws + 9 * TF;
  float* mu_    = sm;
  float* rstd_  = sm + 2048;
  float* zs_    = sm + 4096;
  float* zf_    = sm + 6144;
  float* sd_    = sm + 8192;
  unsigned short* obf  = (unsigned short*)(sm + 10240);
  unsigned short* ofbf = obf + TF;
  unsigned short* Ebf  = ofbf + TF;
  unsigned short* Etbf = Ebf + (size_t)V_DIM * F_DIM;
  unsigned short* Pbuf = Etbf + (size_t)V_DIM * F_DIM;   // expS [2048, 32000] bf16

  // zero atomic accumulators
  zero_kernel<<<(int)((TF + 255) / 256), 256, 0, stream>>>(dO_, (int)TF);
  zero_kernel<<<8, 256, 0, stream>>>(zs_, T_TOK);
  zero_kernel<<<8, 256, 0, stream>>>(zf_, T_TOK);
  zero_kernel<<<2, 256, 0, stream>>>(out_ghb, F_DIM);
  zero_kernel<<<2, 256, 0, stream>>>(out_gbp, F_DIM);

  // E -> bf16 (row-major + transposed)
  convertE_kernel<<<dim3(V_DIM / 64, F_DIM / 64), 256, 0, stream>>>(E, Ebf, Etbf);

  // v = relu(h @ Wh^T + bh + hb)
  gemm_nt_kernel<<<dim3(F_DIM / 64, T_TOK / 64), 256, 0, stream>>>(
      h, nullptr, Wh, v_, T_TOK, F_DIM, H_DIM, bh, hb, 1);
  // p = v @ Wp^T + bp
  gemm_nt_kernel<<<dim3(8, 32), 256, 0, stream>>>(
      v_, nullptr, Wp, p_, T_TOK, F_DIM, F_DIM, bp, nullptr, 0);
  // o = LN(p)  (fp32 + bf16)
  ln_fwd_kernel<<<512, 256, 0, stream>>>(
      p_, nullptr, nullptr, nullptr, nullptr, gamma, beta, o_, obf, mu_, rstd_, 0);
  // expS + z (slow path)
  expsum_kernel<<<dim3(T_TOK / 128, V_DIM / 128), 256, 0, stream>>>(
      obf, Ebf, ob, Pbuf, zs_);
  // U = expS @ E (bf16 GEMM, split-K atomics)
  gemm_pe_kernel<<<dim3(F_DIM / 128, T_TOK / 128, NKC), 256, 0, stream>>>(Pbuf, Etbf, dO_);
  // dp = LN backward(U/z - E[label])
  ln_bwd_kernel<<<512, 256, 0, stream>>>(dO_, zs_, E, labels, gamma, p_, mu_, rstd_, dp_);
  // gbp = colsum(dp)
  colsum_kernel<<<dim3(2, 16), 256, 0, stream>>>(dp_, out_gbp);
  // gWp = dp^T @ v
  gemm_tn_kernel<<<dim3(8, 8), 256, 0, stream>>>(dp_, v_, out_gWp, F_DIM, F_DIM, T_TOK);
  // dv = (dp @ Wp) * (v > 0)
  gemm_nn_kernel<<<dim3(8, 32), 256, 0, stream>>>(dp_, Wp, dv_, T_TOK, F_DIM, F_DIM, v_);
  // ghb = colsum(dv)
  colsum_kernel<<<dim3(2, 16), 256, 0, stream>>>(dv_, out_ghb);
  // gWh = dv^T @ h
  gemm_tn_kernel<<<dim3(16, 8), 256, 0, stream>>>(dv_, h, out_gWh, F_DIM, H_DIM, T_TOK);
  // u = v @ gWp
  gemm_nn_kernel<<<dim3(8, 32), 256, 0, stream>>>(v_, out_gWp, u_, T_TOK, F_DIM, F_DIM, nullptr);
  // sdot = v . gbp
  sdot_kernel<<<512, 256, 0, stream>>>(v_, out_gbp, sd_);
  // tmat = (v*u) @ stepW^T
  gemm_nt_kernel<<<dim3(8, 32), 256, 0, stream>>>(
      v_, u_, stepW, tm_, T_TOK, F_DIM, F_DIM, nullptr, nullptr, 0);
  // o_fast = LN(p - v*(tmat + stepb*sdot))  (fp32 + bf16)
  ln_fwd_kernel<<<512, 256, 0, stream>>>(
      p_, v_, tm_, stepb, sd_, gamma, beta, of_, ofbf, nullptr, nullptr, 1);
  // fast path: z only
  expsum_kernel<<<dim3(T_TOK / 128, V_DIM / 128), 256, 0, stream>>>(
      ofbf, Ebf, ob, nullptr, zf_);
  // fast_loss
  fast_loss_kernel<<<512, 256, 0, stream>>>(of_, E, ob, labels, zf_, out_loss);
}

// Round 9
// 831.578 us; speedup vs baseline: 7.8821x; 1.0670x over previous
//
#include <hip/hip_runtime.h>
#include <cstddef>
#include <math.h>

#define T_TOK 2048
#define F_DIM 512
#define H_DIM 1024
#define V_DIM 32000
#define VHALF 16000
#define NKC   10
#define KC    1600
#define LN_EPS 1e-5f
#define SHIFT 20.0f

typedef __attribute__((ext_vector_type(8))) short bf16x8;
typedef __attribute__((ext_vector_type(4))) float f32x4;

__device__ __forceinline__ unsigned short f2bf(float x) {
  unsigned int u = __float_as_uint(x);
  u += 0x7fffu + ((u >> 16) & 1u);
  return (unsigned short)(u >> 16);
}

// async global->LDS, 16B per lane; LDS dest = wave-uniform base + lane*16
__device__ __forceinline__ void gld16(const unsigned short* gsrc, unsigned short* ldst) {
  __builtin_amdgcn_global_load_lds(
      (const __attribute__((address_space(1))) unsigned int*)gsrc,
      (__attribute__((address_space(3))) unsigned int*)ldst, 16, 0, 0);
}

__device__ inline float wave_sum(float x) {
#pragma unroll
  for (int off = 32; off > 0; off >>= 1) x += __shfl_xor(x, off, 64);
  return x;
}

// ---------------- zero ----------------
__global__ void zero_kernel(float* __restrict__ p, int n) {
  int i = blockIdx.x * 256 + threadIdx.x;
  if (i < n) p[i] = 0.f;
}

// ---------------- fp32 [R,C] -> bf16 [C,R] (transpose) ------------------------
__global__ __launch_bounds__(256) void convT_kernel(
    const float* __restrict__ in, unsigned short* __restrict__ out, int R, int C) {
  __shared__ unsigned short tile[64][65];
  const int r0 = blockIdx.x * 64, c0 = blockIdx.y * 64;
  const int rr = threadIdx.x >> 4, cc4 = (threadIdx.x & 15) * 4;
#pragma unroll
  for (int ps = 0; ps < 4; ++ps) {
    const int row = ps * 16 + rr;
    float4 x = *(const float4*)&in[(size_t)(r0 + row) * C + c0 + cc4];
    tile[row][cc4 + 0] = f2bf(x.x); tile[row][cc4 + 1] = f2bf(x.y);
    tile[row][cc4 + 2] = f2bf(x.z); tile[row][cc4 + 3] = f2bf(x.w);
  }
  __syncthreads();
#pragma unroll
  for (int ps = 0; ps < 4; ++ps) {
    const int orow = ps * 16 + rr;
    ushort4 u;
    u.x = tile[cc4 + 0][orow]; u.y = tile[cc4 + 1][orow];
    u.z = tile[cc4 + 2][orow]; u.w = tile[cc4 + 3][orow];
    *(ushort4*)&out[(size_t)(c0 + orow) * R + r0 + cc4] = u;
  }
}

// ---------------- convert E to bf16 (row-major) + bf16 transposed ------------
__global__ __launch_bounds__(256) void convertE_kernel(
    const float* __restrict__ E, unsigned short* __restrict__ Ebf,
    unsigned short* __restrict__ Etbf)
{
  __shared__ float tile[64][65];
  const int tid = threadIdx.x;
  const int v0 = blockIdx.x * 64, f0 = blockIdx.y * 64;
  const int r = tid >> 4, cq = (tid & 15) * 4;
#pragma unroll
  for (int ps = 0; ps < 4; ++ps) {
    const int row = ps * 16 + r;
    float4 x = *(const float4*)&E[(size_t)(v0 + row) * F_DIM + f0 + cq];
    tile[row][cq + 0] = x.x; tile[row][cq + 1] = x.y;
    tile[row][cq + 2] = x.z; tile[row][cq + 3] = x.w;
    ushort4 u; u.x = f2bf(x.x); u.y = f2bf(x.y); u.z = f2bf(x.z); u.w = f2bf(x.w);
    *(ushort4*)&Ebf[(size_t)(v0 + row) * F_DIM + f0 + cq] = u;
  }
  __syncthreads();
#pragma unroll
  for (int ps = 0; ps < 4; ++ps) {
    const int frow = ps * 16 + r;
    ushort4 u;
    u.x = f2bf(tile[cq + 0][frow]); u.y = f2bf(tile[cq + 1][frow]);
    u.z = f2bf(tile[cq + 2][frow]); u.w = f2bf(tile[cq + 3][frow]);
    *(ushort4*)&Etbf[(size_t)(f0 + frow) * V_DIM + v0 + cq] = u;
  }
}

// ---------------- generic bf16 NT GEMM: C[M,N] = A[M,K] * B[N,K]^T ------------
// Used only OUTSIDE the c_t precision chain (dv, gWh).
__global__ __launch_bounds__(256, 2) void gemm_bf_nt_kernel(
    const unsigned short* __restrict__ A, const unsigned short* __restrict__ B,
    int M, int N, int K,
    const float* __restrict__ maskv,
    float* __restrict__ outf, int atomic_f)
{
  __shared__ __align__(16) unsigned short As[128 * 64];
  __shared__ __align__(16) unsigned short Bs[128 * 64];
  const int tid = threadIdx.x;
  const int w = tid >> 6, lane = tid & 63;
  const int c15 = lane & 15, q = lane >> 4;
  const int n0 = blockIdx.x * 128, m0 = blockIdx.y * 128;
  const int kc = K / gridDim.z;
  const int kbase = blockIdx.z * kc;
  const int mw = (w & 1) * 64, nw = (w >> 1) * 64;
  f32x4 acc[4][4];
#pragma unroll
  for (int mi = 0; mi < 4; ++mi)
#pragma unroll
    for (int nj = 0; nj < 4; ++nj) acc[mi][nj] = (f32x4){0.f, 0.f, 0.f, 0.f};
  for (int it = 0; it < kc / 64; ++it) {
    const int kb = kbase + it * 64;
#pragma unroll
    for (int i = 0; i < 4; ++i) {
      const int gid = (w * 4 + i) * 64 + lane;
      const int row = gid >> 3, col = gid & 7;
      const int colsrc = col ^ (row & 7);
      gld16(A + (size_t)(m0 + row) * K + kb + colsrc * 8, &As[(w * 4 + i) * 512]);
      gld16(B + (size_t)(n0 + row) * K + kb + colsrc * 8, &Bs[(w * 4 + i) * 512]);
    }
    __syncthreads();
#pragma unroll
    for (int kk = 0; kk < 2; ++kk) {
      const int g = (kk * 4 + q) ^ (c15 & 7);
      bf16x8 af[4], bfr[4];
#pragma unroll
      for (int mi = 0; mi < 4; ++mi) {
        const int row = mw + mi * 16 + c15;
        af[mi] = *(const bf16x8*)&As[(row * 8 + g) * 8];
      }
#pragma unroll
      for (int nj = 0; nj < 4; ++nj) {
        const int row = nw + nj * 16 + c15;
        bfr[nj] = *(const bf16x8*)&Bs[(row * 8 + g) * 8];
      }
#pragma unroll
      for (int mi = 0; mi < 4; ++mi)
#pragma unroll
        for (int nj = 0; nj < 4; ++nj)
          acc[mi][nj] = __builtin_amdgcn_mfma_f32_16x16x32_bf16(af[mi], bfr[nj], acc[mi][nj], 0, 0, 0);
    }
    __syncthreads();
  }
#pragma unroll
  for (int mi = 0; mi < 4; ++mi)
#pragma unroll
    for (int nj = 0; nj < 4; ++nj) {
      const int n = n0 + nw + nj * 16 + c15;
#pragma unroll
      for (int r = 0; r < 4; ++r) {
        const int m = m0 + mw + mi * 16 + q * 4 + r;
        const size_t idx = (size_t)m * N + n;
        float v = acc[mi][nj][r];
        if (maskv && !(maskv[idx] > 0.f)) v = 0.f;
        if (atomic_f) atomicAdd(outf + idx, v); else outf[idx] = v;
      }
    }
}

// ---------------- fp32 GEMM NT: C[M,N] = (A ⊙ A2)[M,K] * B[N,K]^T (+bias,relu)
// Precision-critical chain: v, p, tmat (feeds the c_t per-token scalar).
__global__ __launch_bounds__(256) void gemm_nt_kernel(
    const float* __restrict__ A, const float* __restrict__ A2,
    const float* __restrict__ B, float* __restrict__ C,
    int M, int N, int K,
    const float* __restrict__ bias1, const float* __restrict__ bias2, int relu)
{
  __shared__ float As[16][68];
  __shared__ float Bs[16][68];
  const int tid = threadIdx.x;
  const int m0 = blockIdx.y * 64, n0 = blockIdx.x * 64;
  const int ty = tid >> 4, tx = tid & 15;
  const int lrow = tid >> 2, lkq = (tid & 3) * 4;
  float acc[4][4] = {};
  for (int k0 = 0; k0 < K; k0 += 16) {
    float4 a4 = *(const float4*)(A + (size_t)(m0 + lrow) * K + k0 + lkq);
    if (A2) {
      float4 u4 = *(const float4*)(A2 + (size_t)(m0 + lrow) * K + k0 + lkq);
      a4.x *= u4.x; a4.y *= u4.y; a4.z *= u4.z; a4.w *= u4.w;
    }
    float4 b4 = *(const float4*)(B + (size_t)(n0 + lrow) * K + k0 + lkq);
    As[lkq+0][lrow] = a4.x; As[lkq+1][lrow] = a4.y; As[lkq+2][lrow] = a4.z; As[lkq+3][lrow] = a4.w;
    Bs[lkq+0][lrow] = b4.x; Bs[lkq+1][lrow] = b4.y; Bs[lkq+2][lrow] = b4.z; Bs[lkq+3][lrow] = b4.w;
    __syncthreads();
#pragma unroll
    for (int k = 0; k < 16; ++k) {
      float4 a = *(const float4*)&As[k][ty*4];
      float4 b = *(const float4*)&Bs[k][tx*4];
      float ar[4] = {a.x,a.y,a.z,a.w}, br[4] = {b.x,b.y,b.z,b.w};
#pragma unroll
      for (int i = 0; i < 4; ++i)
#pragma unroll
        for (int j = 0; j < 4; ++j) acc[i][j] = fmaf(ar[i], br[j], acc[i][j]);
    }
    __syncthreads();
  }
#pragma unroll
  for (int i = 0; i < 4; ++i) {
    const int m = m0 + ty*4 + i;
    float cr[4];
#pragma unroll
    for (int j = 0; j < 4; ++j) {
      const int n = n0 + tx*4 + j;
      float v = acc[i][j];
      if (bias1) v += bias1[n];
      if (bias2) v += bias2[n];
      if (relu) v = fmaxf(v, 0.f);
      cr[j] = v;
    }
    float4 c; c.x = cr[0]; c.y = cr[1]; c.z = cr[2]; c.w = cr[3];
    *(float4*)(C + (size_t)m * N + n0 + tx*4) = c;
  }
}

// ---------------- fp32 GEMM NN: C[M,N] = A[M,K] * B[K,N] ----------------------
// Precision-critical (u = v @ gWp).
__global__ __launch_bounds__(256) void gemm_nn_kernel(
    const float* __restrict__ A, const float* __restrict__ B,
    float* __restrict__ C, int M, int N, int K)
{
  __shared__ float As[16][68];
  __shared__ float Bs[16][68];
  const int tid = threadIdx.x;
  const int m0 = blockIdx.y * 64, n0 = blockIdx.x * 64;
  const int ty = tid >> 4, tx = tid & 15;
  const int arow = tid >> 2, akq = (tid & 3) * 4;
  const int brow = tid >> 4, bcq = (tid & 15) * 4;
  float acc[4][4] = {};
  for (int k0 = 0; k0 < K; k0 += 16) {
    float4 a4 = *(const float4*)(A + (size_t)(m0 + arow) * K + k0 + akq);
    float4 b4 = *(const float4*)(B + (size_t)(k0 + brow) * N + n0 + bcq);
    As[akq+0][arow] = a4.x; As[akq+1][arow] = a4.y; As[akq+2][arow] = a4.z; As[akq+3][arow] = a4.w;
    *(float4*)&Bs[brow][bcq] = b4;
    __syncthreads();
#pragma unroll
    for (int k = 0; k < 16; ++k) {
      float4 a = *(const float4*)&As[k][ty*4];
      float4 b = *(const float4*)&Bs[k][tx*4];
      float ar[4] = {a.x,a.y,a.z,a.w}, br[4] = {b.x,b.y,b.z,b.w};
#pragma unroll
      for (int i = 0; i < 4; ++i)
#pragma unroll
        for (int j = 0; j < 4; ++j) acc[i][j] = fmaf(ar[i], br[j], acc[i][j]);
    }
    __syncthreads();
  }
#pragma unroll
  for (int i = 0; i < 4; ++i) {
    const int m = m0 + ty*4 + i;
    float4 c; c.x = acc[i][0]; c.y = acc[i][1]; c.z = acc[i][2]; c.w = acc[i][3];
    *(float4*)(C + (size_t)m * N + n0 + tx*4) = c;
  }
}

// ---------------- fp32 GEMM TN: C[M,N] = A[K,M]^T * B[K,N] --------------------
// Precision-critical (gWp = dp^T @ v).
__global__ __launch_bounds__(256) void gemm_tn_kernel(
    const float* __restrict__ A, const float* __restrict__ B,
    float* __restrict__ C, int M, int N, int K)
{
  __shared__ float As[16][68];
  __shared__ float Bs[16][68];
  const int tid = threadIdx.x;
  const int m0 = blockIdx.y * 64, n0 = blockIdx.x * 64;
  const int ty = tid >> 4, tx = tid & 15;
  const int row = tid >> 4, cq = (tid & 15) * 4;
  float acc[4][4] = {};
  for (int k0 = 0; k0 < K; k0 += 16) {
    float4 a4 = *(const float4*)(A + (size_t)(k0 + row) * M + m0 + cq);
    float4 b4 = *(const float4*)(B + (size_t)(k0 + row) * N + n0 + cq);
    *(float4*)&As[row][cq] = a4;
    *(float4*)&Bs[row][cq] = b4;
    __syncthreads();
#pragma unroll
    for (int k = 0; k < 16; ++k) {
      float4 a = *(const float4*)&As[k][ty*4];
      float4 b = *(const float4*)&Bs[k][tx*4];
      float ar[4] = {a.x,a.y,a.z,a.w}, br[4] = {b.x,b.y,b.z,b.w};
#pragma unroll
      for (int i = 0; i < 4; ++i)
#pragma unroll
        for (int j = 0; j < 4; ++j) acc[i][j] = fmaf(ar[i], br[j], acc[i][j]);
    }
    __syncthreads();
  }
#pragma unroll
  for (int i = 0; i < 4; ++i) {
    const int m = m0 + ty*4 + i;
    float4 c; c.x = acc[i][0]; c.y = acc[i][1]; c.z = acc[i][2]; c.w = acc[i][3];
    *(float4*)(C + (size_t)m * N + n0 + tx*4) = c;
  }
}

// ---------------- LayerNorm forward (wave per token) --------------------------
__global__ __launch_bounds__(256) void ln_fwd_kernel(
    const float* __restrict__ p, const float* __restrict__ v,
    const float* __restrict__ tmat, const float* __restrict__ stepb,
    const float* __restrict__ sdot, const float* __restrict__ gamma,
    const float* __restrict__ beta, float* __restrict__ o,
    unsigned short* __restrict__ obf,
    float* __restrict__ mu_out, float* __restrict__ rstd_out, int fastmode)
{
  const int t = blockIdx.x * 4 + (threadIdx.x >> 6);
  const int lane = threadIdx.x & 63;
  const int f0 = lane * 4, f1 = 256 + lane * 4;
  const float* pr = p + (size_t)t * F_DIM;
  float4 x0 = *(const float4*)(pr + f0);
  float4 x1 = *(const float4*)(pr + f1);
  if (fastmode) {
    const float* vr = v + (size_t)t * F_DIM;
    const float* tr = tmat + (size_t)t * F_DIM;
    const float sdt = sdot[t];
    float4 v0 = *(const float4*)(vr + f0), v1 = *(const float4*)(vr + f1);
    float4 t0 = *(const float4*)(tr + f0), t1 = *(const float4*)(tr + f1);
    float4 s0 = *(const float4*)(stepb + f0), s1 = *(const float4*)(stepb + f1);
    x0.x -= v0.x * (t0.x + s0.x * sdt);
    x0.y -= v0.y * (t0.y + s0.y * sdt);
    x0.z -= v0.z * (t0.z + s0.z * sdt);
    x0.w -= v0.w * (t0.w + s0.w * sdt);
    x1.x -= v1.x * (t1.x + s1.x * sdt);
    x1.y -= v1.y * (t1.y + s1.y * sdt);
    x1.z -= v1.z * (t1.z + s1.z * sdt);
    x1.w -= v1.w * (t1.w + s1.w * sdt);
  }
  float s  = x0.x + x0.y + x0.z + x0.w + x1.x + x1.y + x1.z + x1.w;
  float ss = x0.x*x0.x + x0.y*x0.y + x0.z*x0.z + x0.w*x0.w
           + x1.x*x1.x + x1.y*x1.y + x1.z*x1.z + x1.w*x1.w;
  s = wave_sum(s); ss = wave_sum(ss);
  const float mu = s * (1.f / F_DIM);
  const float var = ss * (1.f / F_DIM) - mu * mu;
  const float rstd = rsqrtf(var + LN_EPS);
  float4 g0 = *(const float4*)(gamma + f0), g1 = *(const float4*)(gamma + f1);
  float4 b0 = *(const float4*)(beta + f0),  b1 = *(const float4*)(beta + f1);
  float4 y0, y1;
  y0.x = (x0.x - mu) * rstd * g0.x + b0.x;
  y0.y = (x0.y - mu) * rstd * g0.y + b0.y;
  y0.z = (x0.z - mu) * rstd * g0.z + b0.z;
  y0.w = (x0.w - mu) * rstd * g0.w + b0.w;
  y1.x = (x1.x - mu) * rstd * g1.x + b1.x;
  y1.y = (x1.y - mu) * rstd * g1.y + b1.y;
  y1.z = (x1.z - mu) * rstd * g1.z + b1.z;
  y1.w = (x1.w - mu) * rstd * g1.w + b1.w;
  if (o) {
    *(float4*)(o + (size_t)t * F_DIM + f0) = y0;
    *(float4*)(o + (size_t)t * F_DIM + f1) = y1;
  }
  ushort4 u0, u1;
  u0.x = f2bf(y0.x); u0.y = f2bf(y0.y); u0.z = f2bf(y0.z); u0.w = f2bf(y0.w);
  u1.x = f2bf(y1.x); u1.y = f2bf(y1.y); u1.z = f2bf(y1.z); u1.w = f2bf(y1.w);
  *(ushort4*)(obf + (size_t)t * F_DIM + f0) = u0;
  *(ushort4*)(obf + (size_t)t * F_DIM + f1) = u1;
  if (!fastmode && lane == 0) { mu_out[t] = mu; rstd_out[t] = rstd; }
}

// ---------------- LayerNorm backward (wave per token) -------------------------
__global__ __launch_bounds__(256) void ln_bwd_kernel(
    const float* __restrict__ U, const float* __restrict__ z_,
    const float* __restrict__ E,
    const int* __restrict__ labels, const float* __restrict__ gamma,
    const float* __restrict__ p, const float* __restrict__ mu_,
    const float* __restrict__ rstd_, float* __restrict__ dp,
    unsigned short* __restrict__ dpbf)
{
  const int t = blockIdx.x * 4 + (threadIdx.x >> 6);
  const int lane = threadIdx.x & 63;
  const int f0 = lane * 4, f1 = 256 + lane * 4;
  const int lab = labels[t];
  const float mu = mu_[t], rstd = rstd_[t];
  const float zr = 1.f / z_[t];
  const float* dor = U + (size_t)t * F_DIM;
  const float* er  = E + (size_t)lab * F_DIM;
  const float* pr  = p + (size_t)t * F_DIM;
  alignas(16) float d[8], e[8], g[8], x[8];
  *(float4*)&d[0] = *(const float4*)(dor + f0); *(float4*)&d[4] = *(const float4*)(dor + f1);
  *(float4*)&e[0] = *(const float4*)(er + f0);  *(float4*)&e[4] = *(const float4*)(er + f1);
  *(float4*)&g[0] = *(const float4*)(gamma + f0); *(float4*)&g[4] = *(const float4*)(gamma + f1);
  *(float4*)&x[0] = *(const float4*)(pr + f0);  *(float4*)&x[4] = *(const float4*)(pr + f1);
  float dh[8], xh[8];
  float s1 = 0.f, s2 = 0.f;
#pragma unroll
  for (int i = 0; i < 8; ++i) {
    dh[i] = (d[i] * zr - e[i]) * g[i];
    xh[i] = (x[i] - mu) * rstd;
    s1 += dh[i];
    s2 += dh[i] * xh[i];
  }
  s1 = wave_sum(s1); s2 = wave_sum(s2);
  const float c1 = s1 * (1.f / F_DIM), c2 = s2 * (1.f / F_DIM);
  alignas(16) float outv[8];
#pragma unroll
  for (int i = 0; i < 8; ++i) outv[i] = rstd * (dh[i] - c1 - xh[i] * c2);
  *(float4*)(dp + (size_t)t * F_DIM + f0) = *(float4*)&outv[0];
  *(float4*)(dp + (size_t)t * F_DIM + f1) = *(float4*)&outv[4];
  ushort4 u0, u1;
  u0.x = f2bf(outv[0]); u0.y = f2bf(outv[1]); u0.z = f2bf(outv[2]); u0.w = f2bf(outv[3]);
  u1.x = f2bf(outv[4]); u1.y = f2bf(outv[5]); u1.z = f2bf(outv[6]); u1.w = f2bf(outv[7]);
  *(ushort4*)(dpbf + (size_t)t * F_DIM + f0) = u0;
  *(ushort4*)(dpbf + (size_t)t * F_DIM + f1) = u1;
}

// ---------------- column sum with atomics -------------------------------------
__global__ __launch_bounds__(256) void colsum_kernel(
    const float* __restrict__ X, float* __restrict__ out)
{
  const int f = blockIdx.x * 256 + threadIdx.x;
  const int t0 = blockIdx.y * 128;
  float s = 0.f;
  for (int r = 0; r < 128; ++r) s += X[(size_t)(t0 + r) * F_DIM + f];
  atomicAdd(out + f, s);
}

// ---------------- sdot[t] = dot(v[t,:], gbp) ----------------------------------
__global__ __launch_bounds__(256) void sdot_kernel(
    const float* __restrict__ v, const float* __restrict__ gbp,
    float* __restrict__ sd)
{
  const int t = blockIdx.x * 4 + (threadIdx.x >> 6);
  const int lane = threadIdx.x & 63;
  const int f0 = lane * 4, f1 = 256 + lane * 4;
  const float* vr = v + (size_t)t * F_DIM;
  float4 a0 = *(const float4*)(vr + f0), a1 = *(const float4*)(vr + f1);
  float4 b0 = *(const float4*)(gbp + f0), b1 = *(const float4*)(gbp + f1);
  float s = a0.x*b0.x + a0.y*b0.y + a0.z*b0.z + a0.w*b0.w
          + a1.x*b1.x + a1.y*b1.y + a1.z*b1.z + a1.w*b1.w;
  s = wave_sum(s);
  if (lane == 0) sd[t] = s;
}

// ---------------- expS = exp(o·E^T + ob - SHIFT); z[t] += rowsum --------------
__global__ __launch_bounds__(256, 2) void expsum_kernel(
    const unsigned short* __restrict__ obf, const unsigned short* __restrict__ Ebf,
    const float* __restrict__ ob, unsigned short* __restrict__ expS,
    float* __restrict__ z, int vbase)
{
  __shared__ __align__(16) unsigned short Es[128 * 64];
  __shared__ __align__(16) unsigned short Os[128 * 64];
  const int tid = threadIdx.x;
  const int w = tid >> 6, lane = tid & 63;
  const int c15 = lane & 15, q = lane >> 4;
  const int t0 = blockIdx.x * 128, v0 = vbase + blockIdx.y * 128;
  const int vw = v0 + (w & 1) * 64, tw = t0 + (w >> 1) * 64;
  f32x4 acc[4][4];
#pragma unroll
  for (int mi = 0; mi < 4; ++mi)
#pragma unroll
    for (int nj = 0; nj < 4; ++nj) acc[mi][nj] = (f32x4){0.f, 0.f, 0.f, 0.f};
  for (int it = 0; it < F_DIM / 64; ++it) {
    const int kb = it * 64;
#pragma unroll
    for (int i = 0; i < 4; ++i) {
      const int gid = (w * 4 + i) * 64 + lane;
      const int row = gid >> 3, col3 = gid & 7;
      const int colsrc = col3 ^ (row & 7);
      gld16(Ebf + (size_t)(v0 + row) * F_DIM + kb + colsrc * 8, &Es[(w * 4 + i) * 512]);
      gld16(obf + (size_t)(t0 + row) * F_DIM + kb + colsrc * 8, &Os[(w * 4 + i) * 512]);
    }
    __syncthreads();
#pragma unroll
    for (int kk = 0; kk < 2; ++kk) {
      const int g = (kk * 4 + q) ^ (c15 & 7);
      bf16x8 af[4], bfr[4];
#pragma unroll
      for (int mi = 0; mi < 4; ++mi) {
        const int row = (w & 1) * 64 + mi * 16 + c15;
        af[mi] = *(const bf16x8*)&Es[(row * 8 + g) * 8];
      }
#pragma unroll
      for (int nj = 0; nj < 4; ++nj) {
        const int row = (w >> 1) * 64 + nj * 16 + c15;
        bfr[nj] = *(const bf16x8*)&Os[(row * 8 + g) * 8];
      }
#pragma unroll
      for (int mi = 0; mi < 4; ++mi)
#pragma unroll
        for (int nj = 0; nj < 4; ++nj)
          acc[mi][nj] = __builtin_amdgcn_mfma_f32_16x16x32_bf16(af[mi], bfr[nj], acc[mi][nj], 0, 0, 0);
    }
    __syncthreads();
  }
  float obv[4][4];
#pragma unroll
  for (int mi = 0; mi < 4; ++mi)
    *(float4*)obv[mi] = *(const float4*)&ob[vw + mi * 16 + q * 4];
#pragma unroll
  for (int nj = 0; nj < 4; ++nj) {
    const int t = tw + nj * 16 + c15;
    float zsum = 0.f;
#pragma unroll
    for (int mi = 0; mi < 4; ++mi) {
      float e0 = __expf(acc[mi][nj][0] + obv[mi][0] - SHIFT);
      float e1 = __expf(acc[mi][nj][1] + obv[mi][1] - SHIFT);
      float e2 = __expf(acc[mi][nj][2] + obv[mi][2] - SHIFT);
      float e3 = __expf(acc[mi][nj][3] + obv[mi][3] - SHIFT);
      zsum += e0 + e1 + e2 + e3;
      if (expS) {
        const int vloc = vw - vbase + mi * 16 + q * 4;
        ushort4 u; u.x = f2bf(e0); u.y = f2bf(e1); u.z = f2bf(e2); u.w = f2bf(e3);
        *(ushort4*)&expS[(size_t)t * VHALF + vloc] = u;
      }
    }
    zsum += __shfl_xor(zsum, 16);
    zsum += __shfl_xor(zsum, 32);
    if (q == 0) atomicAdd(&z[t], zsum);
  }
}

// ---------------- U += expS(half) @ E(half) (NT bf16 GEMM, split-K atomics) ---
__global__ __launch_bounds__(256, 2) void gemm_pe_kernel(
    const unsigned short* __restrict__ P, const unsigned short* __restrict__ Etbf,
    float* __restrict__ dO, int vbase)
{
  __shared__ __align__(16) unsigned short As[128 * 64];
  __shared__ __align__(16) unsigned short Bs[128 * 64];
  const int tid = threadIdx.x;
  const int w = tid >> 6, lane = tid & 63;
  const int c15 = lane & 15, q = lane >> 4;
  const int n0 = blockIdx.x * 128, m0 = blockIdx.y * 128;
  const int klbase = blockIdx.z * KC;
  const int mw = (w & 1) * 64, nw = (w >> 1) * 64;
  f32x4 acc[4][4];
#pragma unroll
  for (int mi = 0; mi < 4; ++mi)
#pragma unroll
    for (int nj = 0; nj < 4; ++nj) acc[mi][nj] = (f32x4){0.f, 0.f, 0.f, 0.f};
  for (int it = 0; it < KC / 64; ++it) {
    const int kl = klbase + it * 64;
#pragma unroll
    for (int i = 0; i < 4; ++i) {
      const int gid = (w * 4 + i) * 64 + lane;
      const int row = gid >> 3, col = gid & 7;
      const int colsrc = col ^ (row & 7);
      gld16(P + (size_t)(m0 + row) * VHALF + kl + colsrc * 8, &As[(w * 4 + i) * 512]);
      gld16(Etbf + (size_t)(n0 + row) * V_DIM + vbase + kl + colsrc * 8, &Bs[(w * 4 + i) * 512]);
    }
    __syncthreads();
#pragma unroll
    for (int kk = 0; kk < 2; ++kk) {
      const int g = (kk * 4 + q) ^ (c15 & 7);
      bf16x8 af[4], bfr[4];
#pragma unroll
      for (int mi = 0; mi < 4; ++mi) {
        const int row = mw + mi * 16 + c15;
        af[mi] = *(const bf16x8*)&As[(row * 8 + g) * 8];
      }
#pragma unroll
      for (int nj = 0; nj < 4; ++nj) {
        const int row = nw + nj * 16 + c15;
        bfr[nj] = *(const bf16x8*)&Bs[(row * 8 + g) * 8];
      }
#pragma unroll
      for (int mi = 0; mi < 4; ++mi)
#pragma unroll
        for (int nj = 0; nj < 4; ++nj)
          acc[mi][nj] = __builtin_amdgcn_mfma_f32_16x16x32_bf16(af[mi], bfr[nj], acc[mi][nj], 0, 0, 0);
    }
    __syncthreads();
  }
#pragma unroll
  for (int mi = 0; mi < 4; ++mi)
#pragma unroll
    for (int nj = 0; nj < 4; ++nj) {
      const int f = n0 + nw + nj * 16 + c15;
#pragma unroll
      for (int r = 0; r < 4; ++r) {
        const int t = m0 + mw + mi * 16 + q * 4 + r;
        atomicAdd(&dO[(size_t)t * F_DIM + f], acc[mi][nj][r]);
      }
    }
}

// ---------------- fast loss: SHIFT + log z - (logit at label) -----------------
__global__ __launch_bounds__(256) void fast_loss_kernel(
    const float* __restrict__ of, const float* __restrict__ E,
    const float* __restrict__ ob, const int* __restrict__ labels,
    const float* __restrict__ zf,
    float* __restrict__ out)
{
  const int t = blockIdx.x * 4 + (threadIdx.x >> 6);
  const int lane = threadIdx.x & 63;
  const int f0 = lane * 4, f1 = 256 + lane * 4;
  const int lab = labels[t];
  const float* orow = of + (size_t)t * F_DIM;
  const float* er = E + (size_t)lab * F_DIM;
  float4 a0 = *(const float4*)(orow + f0), a1 = *(const float4*)(orow + f1);
  float4 b0 = *(const float4*)(er + f0),   b1 = *(const float4*)(er + f1);
  float s = a0.x*b0.x + a0.y*b0.y + a0.z*b0.z + a0.w*b0.w
          + a1.x*b1.x + a1.y*b1.y + a1.z*b1.z + a1.w*b1.w;
  s = wave_sum(s);
  if (lane == 0) out[t] = SHIFT + logf(zf[t]) - (s + ob[lab]);
}

// ==============================================================================
extern "C" void kernel_launch(void* const* d_in, const int* in_sizes, int n_in,
                              void* d_out, int out_size, void* d_ws, size_t ws_size,
                              hipStream_t stream)
{
  const float* h      = (const float*)d_in[0];
  const float* E      = (const float*)d_in[1];
  const float* ob     = (const float*)d_in[2];
  const int*   labels = (const int*)d_in[3];
  const float* Wh     = (const float*)d_in[4];
  const float* bh     = (const float*)d_in[5];
  const float* hb     = (const float*)d_in[6];
  const float* Wp     = (const float*)d_in[7];
  const float* bp     = (const float*)d_in[8];
  const float* gamma  = (const float*)d_in[9];
  const float* beta   = (const float*)d_in[10];
  const float* stepW  = (const float*)d_in[11];
  const float* stepb  = (const float*)d_in[12];

  float* out_loss = (float*)d_out;                 // [2048]
  float* out_gWh  = out_loss + T_TOK;              // [512,1024]
  float* out_ghb  = out_gWh + F_DIM * H_DIM;       // [512]
  float* out_gWp  = out_ghb + F_DIM;               // [512,512]
  float* out_gbp  = out_gWp + F_DIM * F_DIM;       // [512]

  float* ws = (float*)d_ws;
  const size_t TF = (size_t)T_TOK * F_DIM;
  float* v_   = ws;
  float* p_   = ws + TF;
  float* dO_  = ws + 2 * TF;   // U = expS @ E (pre 1/z scale)
  float* dp_  = ws + 3 * TF;
  float* dv_  = ws + 4 * TF;
  float* u_   = ws + 5 * TF;
  float* tm_  = ws + 6 * TF;
  float* of_  = ws + 7 * TF;
  float* sm   = ws + 8 * TF;
  float* mu_    = sm;
  float* rstd_  = sm + 2048;
  float* zs_    = sm + 4096;
  float* zf_    = sm + 6144;
  float* sd_    = sm + 8192;
  unsigned short* obf   = (unsigned short*)(sm + 10240);
  unsigned short* ofbf  = obf + TF;
  unsigned short* dpbf  = ofbf + TF;
  unsigned short* dvTbf = dpbf + TF;
  unsigned short* hbfT  = dvTbf + TF;                      // [1024,2048]
  unsigned short* WpTbf = hbfT + (size_t)T_TOK * H_DIM;    // [512,512]
  unsigned short* Ebf   = WpTbf + (size_t)F_DIM * F_DIM;
  unsigned short* Etbf  = Ebf + (size_t)V_DIM * F_DIM;
  unsigned short* Pbuf  = Etbf + (size_t)V_DIM * F_DIM;    // expS [2048, VHALF]

  // zero atomic accumulators
  zero_kernel<<<(int)((TF + 255) / 256), 256, 0, stream>>>(dO_, (int)TF);
  zero_kernel<<<8, 256, 0, stream>>>(zs_, T_TOK);
  zero_kernel<<<8, 256, 0, stream>>>(zf_, T_TOK);
  zero_kernel<<<2, 256, 0, stream>>>(out_ghb, F_DIM);
  zero_kernel<<<2, 256, 0, stream>>>(out_gbp, F_DIM);
  zero_kernel<<<F_DIM * H_DIM / 256, 256, 0, stream>>>(out_gWh, F_DIM * H_DIM);

  // conversions
  convertE_kernel<<<dim3(V_DIM / 64, F_DIM / 64), 256, 0, stream>>>(E, Ebf, Etbf);
  convT_kernel<<<dim3(T_TOK / 64, H_DIM / 64), 256, 0, stream>>>(h, hbfT, T_TOK, H_DIM);
  convT_kernel<<<dim3(F_DIM / 64, F_DIM / 64), 256, 0, stream>>>(Wp, WpTbf, F_DIM, F_DIM);

  // v = relu(h @ Wh^T + bh + hb)  (fp32 — v feeds the c_t chain)
  gemm_nt_kernel<<<dim3(F_DIM / 64, T_TOK / 64), 256, 0, stream>>>(
      h, nullptr, Wh, v_, T_TOK, F_DIM, H_DIM, bh, hb, 1);
  // p = v @ Wp^T + bp  (fp32 — feeds LN fast input directly)
  gemm_nt_kernel<<<dim3(8, 32), 256, 0, stream>>>(
      v_, nullptr, Wp, p_, T_TOK, F_DIM, F_DIM, bp, nullptr, 0);
  // o = LN(p)  (bf16 only)
  ln_fwd_kernel<<<512, 256, 0, stream>>>(
      p_, nullptr, nullptr, nullptr, nullptr, gamma, beta, nullptr, obf, mu_, rstd_, 0);
  // vocab halves: expS + z, then U accumulation
  expsum_kernel<<<dim3(T_TOK / 128, VHALF / 128), 256, 0, stream>>>(
      obf, Ebf, ob, Pbuf, zs_, 0);
  gemm_pe_kernel<<<dim3(F_DIM / 128, T_TOK / 128, NKC), 256, 0, stream>>>(Pbuf, Etbf, dO_, 0);
  expsum_kernel<<<dim3(T_TOK / 128, VHALF / 128), 256, 0, stream>>>(
      obf, Ebf, ob, Pbuf, zs_, VHALF);
  gemm_pe_kernel<<<dim3(F_DIM / 128, T_TOK / 128, NKC), 256, 0, stream>>>(Pbuf, Etbf, dO_, VHALF);
  // dp = LN backward(U/z - E[label])  -> dp fp32 + dpbf
  ln_bwd_kernel<<<512, 256, 0, stream>>>(dO_, zs_, E, labels, gamma, p_, mu_, rstd_, dp_, dpbf);
  // gbp = colsum(dp)  (fp32)
  colsum_kernel<<<dim3(2, 16), 256, 0, stream>>>(dp_, out_gbp);
  // gWp = dp^T @ v  (fp32 — c_t chain)
  gemm_tn_kernel<<<dim3(8, 8), 256, 0, stream>>>(dp_, v_, out_gWp, F_DIM, F_DIM, T_TOK);
  // dv = (dp @ Wp) * (v > 0)  (bf16 ok: feeds only gWh/ghb)
  gemm_bf_nt_kernel<<<dim3(4, 16, 1), 256, 0, stream>>>(
      dpbf, WpTbf, T_TOK, F_DIM, F_DIM, v_, dv_, 0);
  // ghb = colsum(dv)
  colsum_kernel<<<dim3(2, 16), 256, 0, stream>>>(dv_, out_ghb);
  convT_kernel<<<dim3(T_TOK / 64, F_DIM / 64), 256, 0, stream>>>(dv_, dvTbf, T_TOK, F_DIM);
  // gWh = dv^T @ h  (bf16, split-K=4, atomic)
  gemm_bf_nt_kernel<<<dim3(8, 4, 4), 256, 0, stream>>>(
      dvTbf, hbfT, F_DIM, H_DIM, T_TOK, nullptr, out_gWh, 1);
  // u = v @ gWp  (fp32 — c_t chain)
  gemm_nn_kernel<<<dim3(8, 32), 256, 0, stream>>>(v_, out_gWp, u_, T_TOK, F_DIM, F_DIM);
  // sdot = v . gbp  (fp32)
  sdot_kernel<<<512, 256, 0, stream>>>(v_, out_gbp, sd_);
  // tmat = (v*u) @ stepW^T  (fp32 — c_t chain)
  gemm_nt_kernel<<<dim3(8, 32), 256, 0, stream>>>(
      v_, u_, stepW, tm_, T_TOK, F_DIM, F_DIM, nullptr, nullptr, 0);
  // o_fast = LN(p - v*(tmat + stepb*sdot))
  ln_fwd_kernel<<<512, 256, 0, stream>>>(
      p_, v_, tm_, stepb, sd_, gamma, beta, of_, ofbf, nullptr, nullptr, 1);
  // fast path: z only (full vocab in one launch)
  expsum_kernel<<<dim3(T_TOK / 128, V_DIM / 128), 256, 0, stream>>>(
      ofbf, Ebf, ob, nullptr, zf_, 0);
  // fast_loss
  fast_loss_kernel<<<512, 256, 0, stream>>>(of_, E, ob, labels, zf_, out_loss);
}